// Round 7
// baseline (858.595 us; speedup 1.0000x reference)
//
#include <hip/hip_runtime.h>

#define DIM   1024
#define HEADS 16
#define HD    64
#define BB    2
#define SS    2048
#define LLL   2048
#define LOG2E 1.4426950408889634f

typedef __bf16 bf16x8 __attribute__((ext_vector_type(8)));
typedef __bf16 bf16x4v __attribute__((ext_vector_type(4)));
typedef float  f32x4  __attribute__((ext_vector_type(4)));
typedef short  s16x4  __attribute__((ext_vector_type(4)));
typedef short  s16x8  __attribute__((ext_vector_type(8)));
typedef unsigned short u16;

static __device__ __forceinline__ u16 f2b(float x) {
  unsigned u = __float_as_uint(x);
  u += 0x7fffu + ((u >> 16) & 1u);
  return (u16)(u >> 16);
}
static __device__ __forceinline__ float b2f(u16 u) {
  return __uint_as_float(((unsigned)u) << 16);
}
static __device__ __forceinline__ f32x4 mfma32(bf16x8 a, bf16x8 b, f32x4 c) {
  return __builtin_amdgcn_mfma_f32_16x16x32_bf16(a, b, c, 0, 0, 0);
}
static __device__ __forceinline__ f32x4 mfma16(s16x4 a, s16x4 b, f32x4 c) {
#if __has_builtin(__builtin_amdgcn_mfma_f32_16x16x16bf16_1k)
  return __builtin_amdgcn_mfma_f32_16x16x16bf16_1k(a, b, c, 0, 0, 0);
#else
  asm volatile("v_mfma_f32_16x16x16_bf16 %0, %1, %2, %0" : "+v"(c) : "v"(a), "v"(b));
  return c;
#endif
}

// ---------------- f32 -> bf16 convert ----------------
__global__ void cvt_f32_bf16(const float* __restrict__ src, u16* __restrict__ dst, int n4) {
  int i = blockIdx.x * blockDim.x + threadIdx.x;
  if (i >= n4) return;
  float4 f = ((const float4*)src)[i];
  ushort4 o;
  o.x = f2b(f.x); o.y = f2b(f.y); o.z = f2b(f.z); o.w = f2b(f.w);
  ((ushort4*)dst)[i] = o;
}

// ---------------- mask -> bitmask ----------------
__global__ void mask_pack(const int* __restrict__ mask, unsigned* __restrict__ mbits) {
  int i = blockIdx.x * blockDim.x + threadIdx.x;
  const int* src = mask + (size_t)i * 32;
  unsigned bm = 0;
#pragma unroll
  for (int j = 0; j < 8; ++j) {
    int4 m = ((const int4*)src)[j];
    bm |= (m.x != 0 ? 1u : 0u) << (j * 4 + 0);
    bm |= (m.y != 0 ? 1u : 0u) << (j * 4 + 1);
    bm |= (m.z != 0 ? 1u : 0u) << (j * 4 + 2);
    bm |= (m.w != 0 ? 1u : 0u) << (j * 4 + 3);
  }
  mbits[i] = bm;
}

// ---------------- K (f32) -> fragment-packed bf16 tiles, PRESCALED by 0.125*log2(e) ----------------
__global__ __launch_bounds__(256) void pack_k(const float* __restrict__ k0,
                                              const float* __restrict__ k1,
                                              u16* __restrict__ Kfrag) {
  const float SCK = 0.125f * LOG2E;
  const int w = threadIdx.x >> 6, l = threadIdx.x & 63, g = l >> 4, li = l & 15;
  const int lt = blockIdx.x * 4 + w, h = blockIdx.y, z = blockIdx.z;
  const int lay = z >> 1, b = z & 1;
  const float* src = (lay ? k1 : k0) + (size_t)b * LLL * DIM;
  u16* dst = Kfrag + ((((size_t)z * HEADS + h) * 32 + lt) * 8) * 512;
#pragma unroll
  for (int c = 0; c < 8; ++c) {
    int mt = c >> 1, kk = c & 1;
    const float* p = &src[(size_t)(lt * 64 + mt * 16 + li) * DIM + h * 64 + kk * 32 + g * 8];
    float4 f0 = *(const float4*)p;
    float4 f1 = *(const float4*)(p + 4);
    u16 u[8] = {f2b(f0.x * SCK), f2b(f0.y * SCK), f2b(f0.z * SCK), f2b(f0.w * SCK),
                f2b(f1.x * SCK), f2b(f1.y * SCK), f2b(f1.z * SCK), f2b(f1.w * SCK)};
    *(uint4*)&dst[c * 512 + l * 8] = *(uint4*)u;
  }
}

// ---------------- V (f32) -> fragment-packed bf16 tiles (transposed) ----------------
__global__ __launch_bounds__(256) void pack_v(const float* __restrict__ v0,
                                              const float* __restrict__ v1,
                                              u16* __restrict__ Vfrag) {
  __shared__ u16 T[64][72];  // T[l][d]
  const int lt = blockIdx.x, h = blockIdx.y, z = blockIdx.z;
  const int lay = z >> 1, b = z & 1;
  const float* v = (lay ? v1 : v0) + (size_t)b * LLL * DIM;
  const int t = threadIdx.x;
  {
    int r = t >> 2, c16 = (t & 3) * 16;
    const float* src = &v[(size_t)(lt * 64 + r) * DIM + h * 64 + c16];
#pragma unroll
    for (int i = 0; i < 4; ++i) {
      float4 f = *(const float4*)&src[i * 4];
      T[r][c16 + i * 4 + 0] = f2b(f.x);
      T[r][c16 + i * 4 + 1] = f2b(f.y);
      T[r][c16 + i * 4 + 2] = f2b(f.z);
      T[r][c16 + i * 4 + 3] = f2b(f.w);
    }
  }
  __syncthreads();
  u16* dst = Vfrag + ((((size_t)z * HEADS + h) * 32 + lt) * 8) * 512;
  {
    int lane = t & 63, g = lane >> 4, li = lane & 15;
#pragma unroll
    for (int cc = 0; cc < 2; ++cc) {
      int c = (t >> 6) + cc * 4;
      int mt = c >> 1, p = c & 1;
      u16 u[8];
#pragma unroll
      for (int j = 0; j < 4; ++j) u[j] = T[mt * 16 + 4 * g + j][p * 32 + li];
#pragma unroll
      for (int j = 0; j < 4; ++j) u[4 + j] = T[mt * 16 + 4 * g + j][p * 32 + 16 + li];
      *(uint4*)&dst[c * 512 + lane * 8] = *(uint4*)u;
    }
  }
}

// ---------------- bf16 NT GEMM, 128x64 tile. MODE 1: f32 row-major out; MODE 2: Q-fragment out
template<int MODE>
__global__ __launch_bounds__(256) void gemm_nt(const u16* __restrict__ A,
                                               const u16* __restrict__ Bt,
                                               const float* __restrict__ bias,
                                               void* __restrict__ Cv,
                                               int M, int N, int K) {
  __shared__ u16 As[128][64];
  __shared__ u16 Bs[64][64];
  const int t = threadIdx.x;
  const int w = t >> 6, l = t & 63, g = l >> 4, li = l & 15;
  const int m0 = blockIdx.y * 128, n0 = blockIdx.x * 64;
  f32x4 acc[2][4] = {};
  for (int kt = 0; kt < K; kt += 64) {
#pragma unroll
    for (int s = 0; s < 4; ++s) {
      int slot = t + s * 256;
      int r = slot >> 3, c8 = (slot & 7) * 8;
      *(uint4*)&As[r][c8 ^ ((r & 7) << 3)] = *(const uint4*)&A[(size_t)(m0 + r) * K + kt + c8];
    }
#pragma unroll
    for (int s = 0; s < 2; ++s) {
      int slot = t + s * 256;
      int r = slot >> 3, c8 = (slot & 7) * 8;
      *(uint4*)&Bs[r][c8 ^ ((r & 7) << 3)] = *(const uint4*)&Bt[(size_t)(n0 + r) * K + kt + c8];
    }
    __syncthreads();
#pragma unroll
    for (int kk = 0; kk < 2; ++kk) {
      bf16x8 a[2], bfr[4];
#pragma unroll
      for (int mi = 0; mi < 2; ++mi) {
        int ra = w * 32 + mi * 16 + li;
        a[mi] = *(const bf16x8*)&As[ra][(kk * 32 + g * 8) ^ ((ra & 7) << 3)];
      }
#pragma unroll
      for (int ni = 0; ni < 4; ++ni) {
        int rb = ni * 16 + li;
        bfr[ni] = *(const bf16x8*)&Bs[rb][(kk * 32 + g * 8) ^ ((rb & 7) << 3)];
      }
#pragma unroll
      for (int mi = 0; mi < 2; ++mi)
#pragma unroll
        for (int ni = 0; ni < 4; ++ni)
          acc[mi][ni] = mfma32(a[mi], bfr[ni], acc[mi][ni]);
    }
    __syncthreads();
  }
#pragma unroll
  for (int mi = 0; mi < 2; ++mi)
#pragma unroll
    for (int ni = 0; ni < 4; ++ni)
#pragma unroll
      for (int v = 0; v < 4; ++v) {
        int rr = m0 + w * 32 + mi * 16 + g * 4 + v;
        int cc = n0 + ni * 16 + li;
        float val = acc[mi][ni][v] + bias[cc];
        if (MODE == 1) {
          ((float*)Cv)[(size_t)rr * N + cc] = val;
        } else {
          // Qfrag[b][h][qt][c=n*2+kk][lane(gp,liq)][8]
          int b = rr >> 11, q = rr & 2047;
          int qt = q >> 5, n = (q >> 4) & 1, liq = q & 15;
          int h = (cc >> 6) & 15, kk2 = (cc >> 5) & 1, gp = (cc >> 3) & 3, j = cc & 7;
          size_t base = ((((size_t)b * HEADS + h) * 64 + qt) * 4 + n * 2 + kk2) * 512;
          ((u16*)Cv)[base + (size_t)(gp * 16 + liq) * 8 + j] = f2b(val);
        }
      }
}

// ---------------- attn_pv: 32 q-rows/wave, L-split across a 2-wave pair ----------------
// db layout: [z][q][h] = l2d = log2(1/denominator)
template<int MASKED>
static __device__ __forceinline__ void attn_pv_body(int z, int h, int qt, int half, int l,
                                                    const u16* __restrict__ Qfrag,
                                                    const u16* __restrict__ Kfrag,
                                                    const u16* __restrict__ Vfrag,
                                                    const unsigned* __restrict__ mbits,
                                                    u16* __restrict__ out01,
                                                    float* __restrict__ db,
                                                    float* __restrict__ X) {
  const int g = l >> 4, li = l & 15;
  const int b = z & 1;
  const u16* kfh = Kfrag + (size_t)(z * HEADS + h) * (32 * 8 * 512);
  const u16* vfh = Vfrag + (size_t)(z * HEADS + h) * (32 * 8 * 512);
  const u16* qfh = Qfrag + (((size_t)(b * HEADS + h) * 64 + qt) * 4) * 512;

  bf16x8 qf[2][2];
#pragma unroll
  for (int n = 0; n < 2; ++n)
#pragma unroll
    for (int kk = 0; kk < 2; ++kk)
      qf[n][kk] = *(const bf16x8*)&qfh[(n * 2 + kk) * 512 + l * 8];

  const unsigned* mrow0 = MASKED ? mbits + (size_t)(qt * 32 + li) * (LLL / 32) : nullptr;
  const unsigned* mrow1 = MASKED ? mrow0 + 16 * (LLL / 32) : nullptr;
  const int shb = 4 * g;

  f32x4 racc4[2] = {};
  f32x4 oacc[4][2] = {};  // [dt][n], unnormalized
  const int lt0 = half * 16;
  for (int lt = lt0; lt < lt0 + 16; ++lt) {
    unsigned mw[2][2];
    if (MASKED) {
      mw[0][0] = mrow0[lt * 2]; mw[0][1] = mrow0[lt * 2 + 1];
      mw[1][0] = mrow1[lt * 2]; mw[1][1] = mrow1[lt * 2 + 1];
    }
    const u16* kfl = kfh + (size_t)lt * 4096 + l * 8;
    const u16* vfl = vfh + (size_t)lt * 4096 + l * 8;
#pragma unroll
    for (int mt = 0; mt < 4; ++mt) {
      f32x4 s[2] = {};
      __builtin_amdgcn_s_setprio(1);
#pragma unroll
      for (int kk = 0; kk < 2; ++kk) {
        bf16x8 kf = *(const bf16x8*)&kfl[(mt * 2 + kk) * 512];
        s[0] = mfma32(kf, qf[0][kk], s[0]);
        s[1] = mfma32(kf, qf[1][kk], s[1]);
      }
      __builtin_amdgcn_s_setprio(0);
      s16x4 wpk[2];
#pragma unroll
      for (int n = 0; n < 2; ++n) {
        unsigned mm = MASKED ? (mw[n][mt >> 1] >> ((mt & 1) * 16 + shb)) : 0u;
        f32x4 ev;
#pragma unroll
        for (int v = 0; v < 4; ++v) {
          float arg = s[n][v];
          if (MASKED) {
            int spread = ((int)(mm << (31 - v))) >> 31;  // all-ones if keep
            float bias = __uint_as_float((~(unsigned)spread) & 0xC3200000u);  // -160 if drop
            arg = s[n][v] + bias;
          }
          ev[v] = __builtin_amdgcn_exp2f(arg);
        }
        racc4[n] += ev;
        bf16x4v wb = __builtin_convertvector(ev, bf16x4v);
        wpk[n] = __builtin_bit_cast(s16x4, wb);
      }
      __builtin_amdgcn_s_setprio(1);
#pragma unroll
      for (int p = 0; p < 2; ++p) {
        s16x8 vf = *(const s16x8*)&vfl[(mt * 2 + p) * 512];
        s16x4 lo = __builtin_shufflevector(vf, vf, 0, 1, 2, 3);
        s16x4 hi = __builtin_shufflevector(vf, vf, 4, 5, 6, 7);
#pragma unroll
        for (int n = 0; n < 2; ++n) {
          oacc[2 * p + 0][n] = mfma16(lo, wpk[n], oacc[2 * p + 0][n]);
          oacc[2 * p + 1][n] = mfma16(hi, wpk[n], oacc[2 * p + 1][n]);
        }
      }
      __builtin_amdgcn_s_setprio(0);
    }
  }

  // pair exchange: wave 1 publishes partials; wave 0 combines + epilogue
  if (half == 1) {
    float* xl = X + l * 44;
#pragma unroll
    for (int dt = 0; dt < 4; ++dt)
#pragma unroll
      for (int n = 0; n < 2; ++n)
        *(f32x4*)&xl[(dt * 2 + n) * 4] = oacc[dt][n];
    *(f32x4*)&xl[32] = racc4[0];
    *(f32x4*)&xl[36] = racc4[1];
  }
  __syncthreads();
  if (half == 0) {
    const float* xl = X + l * 44;
#pragma unroll
    for (int dt = 0; dt < 4; ++dt)
#pragma unroll
      for (int n = 0; n < 2; ++n)
        oacc[dt][n] += *(const f32x4*)&xl[(dt * 2 + n) * 4];
    racc4[0] += *(const f32x4*)&xl[32];
    racc4[1] += *(const f32x4*)&xl[36];
    float dinv[2], l2d[2];
#pragma unroll
    for (int n = 0; n < 2; ++n) {
      float r = racc4[n][0] + racc4[n][1] + racc4[n][2] + racc4[n][3];
      r += __shfl_xor(r, 16);
      r += __shfl_xor(r, 32);
      dinv[n] = 1.0f / r;
      l2d[n] = -__log2f(r);
    }
    if (l < 16) {
      db[((size_t)z * SS + qt * 32 + li) * HEADS + h]      = l2d[0];
      db[((size_t)z * SS + qt * 32 + 16 + li) * HEADS + h] = l2d[1];
    }
    u16* ob = out01 + (size_t)z * SS * DIM;
#pragma unroll
    for (int dt = 0; dt < 4; ++dt)
#pragma unroll
      for (int n = 0; n < 2; ++n) {
        f32x4 o = oacc[dt][n] * dinv[n];
        ushort4 us;
        us.x = f2b(o[0]); us.y = f2b(o[1]); us.z = f2b(o[2]); us.w = f2b(o[3]);
        *(ushort4*)&ob[((size_t)(qt * 32 + n * 16 + li)) * DIM + h * HD + dt * 16 + 4 * g] = us;
      }
  }
}

__global__ __launch_bounds__(128, 6) void attn_pv(const u16* __restrict__ Qfrag,
                                                  const u16* __restrict__ Kfrag,
                                                  const u16* __restrict__ Vfrag,
                                                  const unsigned* __restrict__ mbits,
                                                  u16* __restrict__ out01,
                                                  float* __restrict__ db) {
  __shared__ float X[64 * 44];  // 11.3 KB pair-exchange buffer
  const int flat = blockIdx.x;
  const int wb = (flat & 7) * 512 + (flat >> 3);  // XCD-contiguous: 8 (z,h) groups per XCD
  const int z = wb >> 10, rem = wb & 1023;
  const int h = rem >> 6, qt = rem & 63;
  const int half = threadIdx.x >> 6, l = threadIdx.x & 63;
  if (z < 2) attn_pv_body<1>(z, h, qt, half, l, Qfrag, Kfrag, Vfrag, mbits, out01, db, X);
  else       attn_pv_body<0>(z, h, qt, half, l, Qfrag, Kfrag, Vfrag, mbits, out01, db, X);
}

// ---------------- amean: head-mean map; block's 4 waves share K tile via per-h lockstep ----------------
template<int MASKED>
static __device__ __forceinline__ void amean_body(int z, int qt2, int lt, int l,
                                                  const u16* __restrict__ Qfrag,
                                                  const u16* __restrict__ Kfrag,
                                                  const unsigned* __restrict__ mbits,
                                                  const float* __restrict__ db,
                                                  float* __restrict__ aout) {
  const int g = l >> 4, li = l & 15;
  const int b = z & 1;
  const int qt = qt2 >> 1, n = qt2 & 1;

  unsigned mw[2];
  if (MASKED) {
    const unsigned* m0 = mbits + (size_t)(qt2 * 16 + li) * (LLL / 32) + lt * 2;
    mw[0] = m0[0]; mw[1] = m0[1];
  }
  const u16* kf_base = Kfrag + (size_t)(z * HEADS) * (32 * 8 * 512) + (size_t)lt * 4096 + l * 8;
  const u16* qf_base = Qfrag + ((((size_t)(b * HEADS) * 64 + qt) * 4 + n * 2)) * 512 + l * 8;

  // l2d for all 16 heads of this lane's q-row: 4 coalesced float4 loads
  f32x4 ld[4];
  {
    const float* dp = db + ((size_t)z * SS + qt2 * 16 + li) * HEADS;
#pragma unroll
    for (int i = 0; i < 4; ++i) ld[i] = *(const f32x4*)&dp[i * 4];
  }

  f32x4 asum[4] = {};
#pragma unroll
  for (int h = 0; h < HEADS; ++h) {
    __syncthreads();  // lockstep: all 4 waves stream the same 8KB K tile (L1 reuse)
    float l2 = ld[h >> 2][h & 3];
    bf16x8 qf0 = *(const bf16x8*)&qf_base[(size_t)h * (64 * 4 * 512)];
    bf16x8 qf1 = *(const bf16x8*)&qf_base[(size_t)h * (64 * 4 * 512) + 512];
    const u16* kfh = kf_base + (size_t)h * (32 * 8 * 512);
#pragma unroll
    for (int mt = 0; mt < 4; ++mt) {
      f32x4 s = {};
      s = mfma32(*(const bf16x8*)&kfh[(mt * 2 + 0) * 512], qf0, s);
      s = mfma32(*(const bf16x8*)&kfh[(mt * 2 + 1) * 512], qf1, s);
      unsigned mm = MASKED ? (mw[mt >> 1] >> ((mt & 1) * 16 + 4 * g)) : 0u;
#pragma unroll
      for (int v = 0; v < 4; ++v) {
        float bias = l2;
        if (MASKED && !((mm >> v) & 1u)) bias = -160.0f;
        asum[mt][v] += __builtin_amdgcn_exp2f(s[v] + bias);
      }
    }
  }
  float* ab = aout + (size_t)z * SS * LLL;
#pragma unroll
  for (int mt = 0; mt < 4; ++mt) {
    f32x4 o = asum[mt] * 0.0625f;
    f32x4* dst = (f32x4*)&ab[(size_t)(qt2 * 16 + li) * LLL + lt * 64 + mt * 16 + 4 * g];
    __builtin_nontemporal_store(o, dst);
  }
}

__global__ __launch_bounds__(256, 8) void amean(const u16* __restrict__ Qfrag,
                                                const u16* __restrict__ Kfrag,
                                                const unsigned* __restrict__ mbits,
                                                const float* __restrict__ db,
                                                float* __restrict__ aout) {
  const int flat = blockIdx.x;
  const int wb = (flat & 7) * 512 + (flat >> 3);   // XCD-contiguous chunks (4096 blocks)
  const int widx = wb * 4 + (threadIdx.x >> 6);    // 16384 waves
  const int z = widx >> 12, rem = widx & 4095;
  const int lt = rem >> 7, qt2 = rem & 127;        // block = 4 qt2 of same (z,lt): share K tile
  if (z < 2) amean_body<1>(z, qt2, lt, threadIdx.x & 63, Qfrag, Kfrag, mbits, db, aout);
  else       amean_body<0>(z, qt2, lt, threadIdx.x & 63, Qfrag, Kfrag, mbits, db, aout);
}

// ---------------- gated merge ----------------
__global__ void merge_kernel(const u16* __restrict__ o01,
                             const float* __restrict__ gate,
                             u16* __restrict__ merged) {
  int i = blockIdx.x * blockDim.x + threadIdx.x;
  float gv = gate[0];
  float g = 1.0f / (1.0f + __builtin_amdgcn_exp2f(-gv * LOG2E));
  const size_t n = (size_t)BB * SS * DIM;
  ushort4 a = ((const ushort4*)o01)[i];
  ushort4 c = ((const ushort4*)(o01 + n))[i];
  ushort4 o;
  o.x = f2b(g * b2f(a.x) + (1.f - g) * b2f(c.x));
  o.y = f2b(g * b2f(a.y) + (1.f - g) * b2f(c.y));
  o.z = f2b(g * b2f(a.z) + (1.f - g) * b2f(c.z));
  o.w = f2b(g * b2f(a.w) + (1.f - g) * b2f(c.w));
  ((ushort4*)merged)[i] = o;
}

extern "C" void kernel_launch(void* const* d_in, const int* in_sizes, int n_in,
                              void* d_out, int out_size, void* d_ws, size_t ws_size,
                              hipStream_t stream) {
  const float* query = (const float*)d_in[0];
  const float* k0f   = (const float*)d_in[1];
  const float* v0f   = (const float*)d_in[2];
  const float* k1f   = (const float*)d_in[3];
  const float* v1f   = (const float*)d_in[4];
  const int*   mask  = (const int*)d_in[5];
  const float* Wqf   = (const float*)d_in[6];
  const float* bq    = (const float*)d_in[7];
  const float* Wof   = (const float*)d_in[8];
  const float* bo    = (const float*)d_in[9];
  const float* gate  = (const float*)d_in[10];
  float* out = (float*)d_out;

  const size_t nQ = (size_t)BB * SS * DIM;
  const size_t nW = (size_t)DIM * DIM;

  char* ws = (char*)d_ws;
  size_t off = 0;
  auto alloc = [&](size_t bytes) -> char* {
    char* p = ws + off;
    off += (bytes + 255) & ~(size_t)255;
    return p;
  };
  u16*      queryb  = (u16*)alloc(nQ * 2);             // reused as mergedb later
  u16*      wqb     = (u16*)alloc(nW * 2);
  u16*      wob     = (u16*)alloc(nW * 2);
  u16*      Qfrag   = (u16*)alloc(nQ * 2);             // [b][h][qt][c][lane][8]
  u16*      Kfrag   = (u16*)alloc((size_t)2 * nQ * 2); // [z][h][lt][c][lane][8] (prescaled)
  u16*      Vfrag   = (u16*)alloc((size_t)2 * nQ * 2);
  unsigned* mbits   = (unsigned*)alloc((size_t)SS * (LLL / 32) * 4);
  float*    db      = (float*)alloc((size_t)4 * SS * HEADS * 4);  // l2d per [z][q][h]
  u16*      out01   = (u16*)alloc((size_t)2 * nQ * 2);
  u16*      mergedb = queryb;  // queryb dead after q-proj gemm

  auto cvt = [&](const float* s, u16* d, size_t n) {
    int n4 = (int)(n / 4);
    cvt_f32_bf16<<<dim3((n4 + 255) / 256), dim3(256), 0, stream>>>(s, d, n4);
  };
  cvt(query, queryb, nQ);
  cvt(Wqf, wqb, nW);
  cvt(Wof, wob, nW);

  mask_pack<<<dim3(SS * (LLL / 32) / 256), dim3(256), 0, stream>>>(mask, mbits);
  pack_k<<<dim3(LLL / 64 / 4, HEADS, 4), dim3(256), 0, stream>>>(k0f, k1f, Kfrag);
  pack_v<<<dim3(LLL / 64, HEADS, 4), dim3(256), 0, stream>>>(v0f, v1f, Vfrag);

  // q projection straight into fragment layout (128x64 tiles)
  gemm_nt<2><<<dim3(DIM / 64, (BB * SS) / 128), dim3(256), 0, stream>>>(
      queryb, wqb, bq, (void*)Qfrag, BB * SS, DIM, DIM);

  // fused single-pass attention: 32 rows/wave, L-split pairs (O + l2d)
  attn_pv<<<dim3(4096), dim3(128), 0, stream>>>(Qfrag, Kfrag, Vfrag, mbits, out01, db);

  // head-mean attention maps straight into d_out
  amean<<<dim3(4096), dim3(256), 0, stream>>>(Qfrag, Kfrag, mbits, db, out + nQ);

  merge_kernel<<<dim3((int)(nQ / 4 / 256)), dim3(256), 0, stream>>>(out01, gate, mergedb);

  gemm_nt<1><<<dim3(DIM / 64, (BB * SS) / 128), dim3(256), 0, stream>>>(
      mergedb, wob, bo, (void*)out, BB * SS, DIM, DIM);
}

// Round 8
// 325.687 us; speedup vs baseline: 2.6363x; 2.6363x over previous
//
#include <hip/hip_runtime.h>

#define DIM   1024
#define HEADS 16
#define HD    64
#define BB    2
#define SS    2048
#define LLL   2048
#define LOG2E 1.4426950408889634f

typedef __bf16 bf16x8 __attribute__((ext_vector_type(8)));
typedef __bf16 bf16x4v __attribute__((ext_vector_type(4)));
typedef float  f32x4  __attribute__((ext_vector_type(4)));
typedef short  s16x4  __attribute__((ext_vector_type(4)));
typedef short  s16x8  __attribute__((ext_vector_type(8)));
typedef unsigned short u16;

static __device__ __forceinline__ u16 f2b(float x) {
  unsigned u = __float_as_uint(x);
  u += 0x7fffu + ((u >> 16) & 1u);
  return (u16)(u >> 16);
}
static __device__ __forceinline__ float b2f(u16 u) {
  return __uint_as_float(((unsigned)u) << 16);
}
static __device__ __forceinline__ f32x4 mfma32(bf16x8 a, bf16x8 b, f32x4 c) {
  return __builtin_amdgcn_mfma_f32_16x16x32_bf16(a, b, c, 0, 0, 0);
}
static __device__ __forceinline__ f32x4 mfma16(s16x4 a, s16x4 b, f32x4 c) {
#if __has_builtin(__builtin_amdgcn_mfma_f32_16x16x16bf16_1k)
  return __builtin_amdgcn_mfma_f32_16x16x16bf16_1k(a, b, c, 0, 0, 0);
#else
  asm volatile("v_mfma_f32_16x16x16_bf16 %0, %1, %2, %0" : "+v"(c) : "v"(a), "v"(b));
  return c;
#endif
}

// ---------------- f32 -> bf16 convert ----------------
__global__ void cvt_f32_bf16(const float* __restrict__ src, u16* __restrict__ dst, int n4) {
  int i = blockIdx.x * blockDim.x + threadIdx.x;
  if (i >= n4) return;
  float4 f = ((const float4*)src)[i];
  ushort4 o;
  o.x = f2b(f.x); o.y = f2b(f.y); o.z = f2b(f.z); o.w = f2b(f.w);
  ((ushort4*)dst)[i] = o;
}

// ---------------- mask -> bitmask ----------------
__global__ void mask_pack(const int* __restrict__ mask, unsigned* __restrict__ mbits) {
  int i = blockIdx.x * blockDim.x + threadIdx.x;
  const int* src = mask + (size_t)i * 32;
  unsigned bm = 0;
#pragma unroll
  for (int j = 0; j < 8; ++j) {
    int4 m = ((const int4*)src)[j];
    bm |= (m.x != 0 ? 1u : 0u) << (j * 4 + 0);
    bm |= (m.y != 0 ? 1u : 0u) << (j * 4 + 1);
    bm |= (m.z != 0 ? 1u : 0u) << (j * 4 + 2);
    bm |= (m.w != 0 ? 1u : 0u) << (j * 4 + 3);
  }
  mbits[i] = bm;
}

// ---------------- K (f32) -> fragment-packed bf16 tiles, PRESCALED by 0.125*log2(e) ----------------
__global__ __launch_bounds__(256) void pack_k(const float* __restrict__ k0,
                                              const float* __restrict__ k1,
                                              u16* __restrict__ Kfrag) {
  const float SCK = 0.125f * LOG2E;
  const int w = threadIdx.x >> 6, l = threadIdx.x & 63, g = l >> 4, li = l & 15;
  const int lt = blockIdx.x * 4 + w, h = blockIdx.y, z = blockIdx.z;
  const int lay = z >> 1, b = z & 1;
  const float* src = (lay ? k1 : k0) + (size_t)b * LLL * DIM;
  u16* dst = Kfrag + ((((size_t)z * HEADS + h) * 32 + lt) * 8) * 512;
#pragma unroll
  for (int c = 0; c < 8; ++c) {
    int mt = c >> 1, kk = c & 1;
    const float* p = &src[(size_t)(lt * 64 + mt * 16 + li) * DIM + h * 64 + kk * 32 + g * 8];
    float4 f0 = *(const float4*)p;
    float4 f1 = *(const float4*)(p + 4);
    u16 u[8] = {f2b(f0.x * SCK), f2b(f0.y * SCK), f2b(f0.z * SCK), f2b(f0.w * SCK),
                f2b(f1.x * SCK), f2b(f1.y * SCK), f2b(f1.z * SCK), f2b(f1.w * SCK)};
    *(uint4*)&dst[c * 512 + l * 8] = *(uint4*)u;
  }
}

// ---------------- V (f32) -> fragment-packed bf16 tiles (transposed) ----------------
__global__ __launch_bounds__(256) void pack_v(const float* __restrict__ v0,
                                              const float* __restrict__ v1,
                                              u16* __restrict__ Vfrag) {
  __shared__ u16 T[64][72];  // T[l][d]
  const int lt = blockIdx.x, h = blockIdx.y, z = blockIdx.z;
  const int lay = z >> 1, b = z & 1;
  const float* v = (lay ? v1 : v0) + (size_t)b * LLL * DIM;
  const int t = threadIdx.x;
  {
    int r = t >> 2, c16 = (t & 3) * 16;
    const float* src = &v[(size_t)(lt * 64 + r) * DIM + h * 64 + c16];
#pragma unroll
    for (int i = 0; i < 4; ++i) {
      float4 f = *(const float4*)&src[i * 4];
      T[r][c16 + i * 4 + 0] = f2b(f.x);
      T[r][c16 + i * 4 + 1] = f2b(f.y);
      T[r][c16 + i * 4 + 2] = f2b(f.z);
      T[r][c16 + i * 4 + 3] = f2b(f.w);
    }
  }
  __syncthreads();
  u16* dst = Vfrag + ((((size_t)z * HEADS + h) * 32 + lt) * 8) * 512;
  {
    int lane = t & 63, g = lane >> 4, li = lane & 15;
#pragma unroll
    for (int cc = 0; cc < 2; ++cc) {
      int c = (t >> 6) + cc * 4;
      int mt = c >> 1, p = c & 1;
      u16 u[8];
#pragma unroll
      for (int j = 0; j < 4; ++j) u[j] = T[mt * 16 + 4 * g + j][p * 32 + li];
#pragma unroll
      for (int j = 0; j < 4; ++j) u[4 + j] = T[mt * 16 + 4 * g + j][p * 32 + 16 + li];
      *(uint4*)&dst[c * 512 + lane * 8] = *(uint4*)u;
    }
  }
}

// ---------------- bf16 NT GEMM, 128x64 tile. MODE 1: f32 row-major out; MODE 2: Q-fragment out
template<int MODE>
__global__ __launch_bounds__(256) void gemm_nt(const u16* __restrict__ A,
                                               const u16* __restrict__ Bt,
                                               const float* __restrict__ bias,
                                               void* __restrict__ Cv,
                                               int M, int N, int K) {
  __shared__ u16 As[128][64];
  __shared__ u16 Bs[64][64];
  const int t = threadIdx.x;
  const int w = t >> 6, l = t & 63, g = l >> 4, li = l & 15;
  const int m0 = blockIdx.y * 128, n0 = blockIdx.x * 64;
  f32x4 acc[2][4] = {};
  for (int kt = 0; kt < K; kt += 64) {
#pragma unroll
    for (int s = 0; s < 4; ++s) {
      int slot = t + s * 256;
      int r = slot >> 3, c8 = (slot & 7) * 8;
      *(uint4*)&As[r][c8 ^ ((r & 7) << 3)] = *(const uint4*)&A[(size_t)(m0 + r) * K + kt + c8];
    }
#pragma unroll
    for (int s = 0; s < 2; ++s) {
      int slot = t + s * 256;
      int r = slot >> 3, c8 = (slot & 7) * 8;
      *(uint4*)&Bs[r][c8 ^ ((r & 7) << 3)] = *(const uint4*)&Bt[(size_t)(n0 + r) * K + kt + c8];
    }
    __syncthreads();
#pragma unroll
    for (int kk = 0; kk < 2; ++kk) {
      bf16x8 a[2], bfr[4];
#pragma unroll
      for (int mi = 0; mi < 2; ++mi) {
        int ra = w * 32 + mi * 16 + li;
        a[mi] = *(const bf16x8*)&As[ra][(kk * 32 + g * 8) ^ ((ra & 7) << 3)];
      }
#pragma unroll
      for (int ni = 0; ni < 4; ++ni) {
        int rb = ni * 16 + li;
        bfr[ni] = *(const bf16x8*)&Bs[rb][(kk * 32 + g * 8) ^ ((rb & 7) << 3)];
      }
#pragma unroll
      for (int mi = 0; mi < 2; ++mi)
#pragma unroll
        for (int ni = 0; ni < 4; ++ni)
          acc[mi][ni] = mfma32(a[mi], bfr[ni], acc[mi][ni]);
    }
    __syncthreads();
  }
#pragma unroll
  for (int mi = 0; mi < 2; ++mi)
#pragma unroll
    for (int ni = 0; ni < 4; ++ni)
#pragma unroll
      for (int v = 0; v < 4; ++v) {
        int rr = m0 + w * 32 + mi * 16 + g * 4 + v;
        int cc = n0 + ni * 16 + li;
        float val = acc[mi][ni][v] + bias[cc];
        if (MODE == 1) {
          ((float*)Cv)[(size_t)rr * N + cc] = val;
        } else {
          // Qfrag[b][h][qt][c=n*2+kk][lane(gp,liq)][8]
          int b = rr >> 11, q = rr & 2047;
          int qt = q >> 5, n = (q >> 4) & 1, liq = q & 15;
          int h = (cc >> 6) & 15, kk2 = (cc >> 5) & 1, gp = (cc >> 3) & 3, j = cc & 7;
          size_t base = ((((size_t)b * HEADS + h) * 64 + qt) * 4 + n * 2 + kk2) * 512;
          ((u16*)Cv)[base + (size_t)(gp * 16 + liq) * 8 + j] = f2b(val);
        }
      }
}

// ---------------- attn_pv: 16 q-rows/wave, L halved across a 2-wave pair ----------------
// Lean body (~45 VGPR live) so (256,8) -> <=64 VGPR bin without spilling.
// db layout: [z][h][q] = dinv
template<int MASKED>
static __device__ __forceinline__ void attn_pv_body(int z, int h, int qt2, int half, int l,
                                                    const u16* __restrict__ Qfrag,
                                                    const u16* __restrict__ Kfrag,
                                                    const u16* __restrict__ Vfrag,
                                                    const unsigned* __restrict__ mbits,
                                                    u16* __restrict__ out01,
                                                    float* __restrict__ db,
                                                    float* __restrict__ X) {
  const int g = l >> 4, li = l & 15;
  const int b = z & 1;
  const int qt = qt2 >> 1, n = qt2 & 1;
  const u16* kfh = Kfrag + (size_t)(z * HEADS + h) * (32 * 8 * 512);
  const u16* vfh = Vfrag + (size_t)(z * HEADS + h) * (32 * 8 * 512);
  const u16* qfh = Qfrag + ((((size_t)(b * HEADS + h) * 64 + qt) * 4 + n * 2)) * 512;

  bf16x8 qf0 = *(const bf16x8*)&qfh[0 * 512 + l * 8];
  bf16x8 qf1 = *(const bf16x8*)&qfh[1 * 512 + l * 8];

  const unsigned* mrow = MASKED ? mbits + (size_t)(qt2 * 16 + li) * (LLL / 32) : nullptr;
  const int shb = 4 * g;

  f32x4 racc4 = {};
  f32x4 oacc[4] = {};  // [dt], unnormalized
  const int lt0 = half * 16;
  for (int lt = lt0; lt < lt0 + 16; ++lt) {
    unsigned mw[2];
    if (MASKED) { mw[0] = mrow[lt * 2]; mw[1] = mrow[lt * 2 + 1]; }
    const u16* kfl = kfh + (size_t)lt * 4096 + l * 8;
    const u16* vfl = vfh + (size_t)lt * 4096 + l * 8;
#pragma unroll
    for (int mt = 0; mt < 4; ++mt) {
      f32x4 s = {};
      __builtin_amdgcn_s_setprio(1);
      s = mfma32(*(const bf16x8*)&kfl[(mt * 2 + 0) * 512], qf0, s);
      s = mfma32(*(const bf16x8*)&kfl[(mt * 2 + 1) * 512], qf1, s);
      __builtin_amdgcn_s_setprio(0);
      f32x4 ev;
      unsigned mm = MASKED ? (mw[mt >> 1] >> ((mt & 1) * 16 + shb)) : 0u;
#pragma unroll
      for (int v = 0; v < 4; ++v) {
        float arg = s[v];
        if (MASKED) {
          int spread = ((int)(mm << (31 - v))) >> 31;  // all-ones if keep
          float bias = __uint_as_float((~(unsigned)spread) & 0xC3200000u);  // -160 if drop
          arg = s[v] + bias;
        }
        ev[v] = __builtin_amdgcn_exp2f(arg);
      }
      racc4 += ev;
      bf16x4v wb = __builtin_convertvector(ev, bf16x4v);
      s16x4 wpk = __builtin_bit_cast(s16x4, wb);
      __builtin_amdgcn_s_setprio(1);
#pragma unroll
      for (int p = 0; p < 2; ++p) {
        s16x8 vf = *(const s16x8*)&vfl[(mt * 2 + p) * 512];
        s16x4 lo = __builtin_shufflevector(vf, vf, 0, 1, 2, 3);
        s16x4 hi = __builtin_shufflevector(vf, vf, 4, 5, 6, 7);
        oacc[2 * p + 0] = mfma16(lo, wpk, oacc[2 * p + 0]);
        oacc[2 * p + 1] = mfma16(hi, wpk, oacc[2 * p + 1]);
      }
      __builtin_amdgcn_s_setprio(0);
    }
  }

  // pair exchange: wave half=1 publishes partials; half=0 combines + epilogue
  float* xl = X + l * 20;
  if (half == 1) {
#pragma unroll
    for (int dt = 0; dt < 4; ++dt) *(f32x4*)&xl[dt * 4] = oacc[dt];
    *(f32x4*)&xl[16] = racc4;
  }
  __syncthreads();
  if (half == 0) {
#pragma unroll
    for (int dt = 0; dt < 4; ++dt) oacc[dt] += *(const f32x4*)&xl[dt * 4];
    racc4 += *(const f32x4*)&xl[16];
    float r = racc4[0] + racc4[1] + racc4[2] + racc4[3];
    r += __shfl_xor(r, 16);
    r += __shfl_xor(r, 32);
    float dinv = 1.0f / r;
    if (l < 16) db[(size_t)(z * HEADS + h) * SS + qt2 * 16 + li] = dinv;
    u16* ob = out01 + (size_t)z * SS * DIM;
#pragma unroll
    for (int dt = 0; dt < 4; ++dt) {
      f32x4 o = oacc[dt] * dinv;
      ushort4 us;
      us.x = f2b(o[0]); us.y = f2b(o[1]); us.z = f2b(o[2]); us.w = f2b(o[3]);
      *(ushort4*)&ob[((size_t)(qt2 * 16 + li)) * DIM + h * HD + dt * 16 + 4 * g] = us;
    }
  }
}

__global__ __launch_bounds__(256, 8) void attn_pv(const u16* __restrict__ Qfrag,
                                                  const u16* __restrict__ Kfrag,
                                                  const u16* __restrict__ Vfrag,
                                                  const unsigned* __restrict__ mbits,
                                                  u16* __restrict__ out01,
                                                  float* __restrict__ db) {
  __shared__ float X[2][64 * 20];  // 10.2 KB: per-pair exchange
  const int flat = blockIdx.x;
  const int wb = (flat & 7) * 512 + (flat >> 3);  // XCD-contiguous chunks (4096 blocks)
  const int z = wb >> 10, rem = wb & 1023;
  const int h = rem >> 6, qg = rem & 63;          // block = 2 qt2-pairs of same (z,h)
  const int w = threadIdx.x >> 6;
  const int pair = w >> 1, half = w & 1, l = threadIdx.x & 63;
  const int qt2 = qg * 2 + pair;
  if (z < 2) attn_pv_body<1>(z, h, qt2, half, l, Qfrag, Kfrag, Vfrag, mbits, out01, db, &X[pair][0]);
  else       attn_pv_body<0>(z, h, qt2, half, l, Qfrag, Kfrag, Vfrag, mbits, out01, db, &X[pair][0]);
}

// ---------------- amean: head-mean map (R6 body: no barriers, scalar l2 per h) ----------------
template<int MASKED>
static __device__ __forceinline__ void amean_body(int z, int qt2, int lt, int l,
                                                  const u16* __restrict__ Qfrag,
                                                  const u16* __restrict__ Kfrag,
                                                  const unsigned* __restrict__ mbits,
                                                  const float* __restrict__ db,
                                                  float* __restrict__ aout) {
  const int g = l >> 4, li = l & 15;
  const int b = z & 1;
  const int qt = qt2 >> 1, n = qt2 & 1;

  unsigned mw[2];
  if (MASKED) {
    const unsigned* m0 = mbits + (size_t)(qt2 * 16 + li) * (LLL / 32) + lt * 2;
    mw[0] = m0[0]; mw[1] = m0[1];
  }
  const u16* kf_base = Kfrag + (size_t)(z * HEADS) * (32 * 8 * 512) + (size_t)lt * 4096 + l * 8;
  const u16* qf_base = Qfrag + ((((size_t)(b * HEADS) * 64 + qt) * 4 + n * 2)) * 512 + l * 8;
  const float* dbb = db + (size_t)(z * HEADS) * SS + qt2 * 16 + li;

  f32x4 asum[4] = {};
#pragma unroll 2
  for (int h = 0; h < HEADS; ++h) {
    float l2 = __log2f(dbb[(size_t)h * SS]);
    bf16x8 qf0 = *(const bf16x8*)&qf_base[(size_t)h * (64 * 4 * 512)];
    bf16x8 qf1 = *(const bf16x8*)&qf_base[(size_t)h * (64 * 4 * 512) + 512];
    const u16* kfh = kf_base + (size_t)h * (32 * 8 * 512);
#pragma unroll
    for (int mt = 0; mt < 4; ++mt) {
      f32x4 s = {};
      s = mfma32(*(const bf16x8*)&kfh[(mt * 2 + 0) * 512], qf0, s);
      s = mfma32(*(const bf16x8*)&kfh[(mt * 2 + 1) * 512], qf1, s);
      unsigned mm = MASKED ? (mw[mt >> 1] >> ((mt & 1) * 16 + 4 * g)) : 0u;
#pragma unroll
      for (int v = 0; v < 4; ++v) {
        float bias = l2;
        if (MASKED && !((mm >> v) & 1u)) bias = -160.0f;
        asum[mt][v] += __builtin_amdgcn_exp2f(s[v] + bias);
      }
    }
  }
  float* ab = aout + (size_t)z * SS * LLL;
#pragma unroll
  for (int mt = 0; mt < 4; ++mt) {
    f32x4 o = asum[mt] * 0.0625f;
    f32x4* dst = (f32x4*)&ab[(size_t)(qt2 * 16 + li) * LLL + lt * 64 + mt * 16 + 4 * g];
    __builtin_nontemporal_store(o, dst);
  }
}

__global__ __launch_bounds__(256, 8) void amean(const u16* __restrict__ Qfrag,
                                                const u16* __restrict__ Kfrag,
                                                const unsigned* __restrict__ mbits,
                                                const float* __restrict__ db,
                                                float* __restrict__ aout) {
  const int flat = blockIdx.x;
  const int wb = (flat & 7) * 512 + (flat >> 3);   // XCD-contiguous chunks (4096 blocks)
  const int widx = wb * 4 + (threadIdx.x >> 6);    // 16384 waves
  const int z = widx >> 12, rem = widx & 4095;
  const int lt = rem >> 7, qt2 = rem & 127;        // block = 4 qt2 of same (z,lt): share K tile
  if (z < 2) amean_body<1>(z, qt2, lt, threadIdx.x & 63, Qfrag, Kfrag, mbits, db, aout);
  else       amean_body<0>(z, qt2, lt, threadIdx.x & 63, Qfrag, Kfrag, mbits, db, aout);
}

// ---------------- gated merge ----------------
__global__ void merge_kernel(const u16* __restrict__ o01,
                             const float* __restrict__ gate,
                             u16* __restrict__ merged) {
  int i = blockIdx.x * blockDim.x + threadIdx.x;
  float gv = gate[0];
  float g = 1.0f / (1.0f + __builtin_amdgcn_exp2f(-gv * LOG2E));
  const size_t n = (size_t)BB * SS * DIM;
  ushort4 a = ((const ushort4*)o01)[i];
  ushort4 c = ((const ushort4*)(o01 + n))[i];
  ushort4 o;
  o.x = f2b(g * b2f(a.x) + (1.f - g) * b2f(c.x));
  o.y = f2b(g * b2f(a.y) + (1.f - g) * b2f(c.y));
  o.z = f2b(g * b2f(a.z) + (1.f - g) * b2f(c.z));
  o.w = f2b(g * b2f(a.w) + (1.f - g) * b2f(c.w));
  ((ushort4*)merged)[i] = o;
}

extern "C" void kernel_launch(void* const* d_in, const int* in_sizes, int n_in,
                              void* d_out, int out_size, void* d_ws, size_t ws_size,
                              hipStream_t stream) {
  const float* query = (const float*)d_in[0];
  const float* k0f   = (const float*)d_in[1];
  const float* v0f   = (const float*)d_in[2];
  const float* k1f   = (const float*)d_in[3];
  const float* v1f   = (const float*)d_in[4];
  const int*   mask  = (const int*)d_in[5];
  const float* Wqf   = (const float*)d_in[6];
  const float* bq    = (const float*)d_in[7];
  const float* Wof   = (const float*)d_in[8];
  const float* bo    = (const float*)d_in[9];
  const float* gate  = (const float*)d_in[10];
  float* out = (float*)d_out;

  const size_t nQ = (size_t)BB * SS * DIM;
  const size_t nW = (size_t)DIM * DIM;

  char* ws = (char*)d_ws;
  size_t off = 0;
  auto alloc = [&](size_t bytes) -> char* {
    char* p = ws + off;
    off += (bytes + 255) & ~(size_t)255;
    return p;
  };
  u16*      queryb  = (u16*)alloc(nQ * 2);             // reused as mergedb later
  u16*      wqb     = (u16*)alloc(nW * 2);
  u16*      wob     = (u16*)alloc(nW * 2);
  u16*      Qfrag   = (u16*)alloc(nQ * 2);             // [b][h][qt][c][lane][8]
  u16*      Kfrag   = (u16*)alloc((size_t)2 * nQ * 2); // [z][h][lt][c][lane][8] (prescaled)
  u16*      Vfrag   = (u16*)alloc((size_t)2 * nQ * 2);
  unsigned* mbits   = (unsigned*)alloc((size_t)SS * (LLL / 32) * 4);
  float*    db      = (float*)alloc((size_t)4 * HEADS * SS * 4);  // dinv per [z][h][q]
  u16*      out01   = (u16*)alloc((size_t)2 * nQ * 2);
  u16*      mergedb = queryb;  // queryb dead after q-proj gemm

  auto cvt = [&](const float* s, u16* d, size_t n) {
    int n4 = (int)(n / 4);
    cvt_f32_bf16<<<dim3((n4 + 255) / 256), dim3(256), 0, stream>>>(s, d, n4);
  };
  cvt(query, queryb, nQ);
  cvt(Wqf, wqb, nW);
  cvt(Wof, wob, nW);

  mask_pack<<<dim3(SS * (LLL / 32) / 256), dim3(256), 0, stream>>>(mask, mbits);
  pack_k<<<dim3(LLL / 64 / 4, HEADS, 4), dim3(256), 0, stream>>>(k0f, k1f, Kfrag);
  pack_v<<<dim3(LLL / 64, HEADS, 4), dim3(256), 0, stream>>>(v0f, v1f, Vfrag);

  // q projection straight into fragment layout (128x64 tiles)
  gemm_nt<2><<<dim3(DIM / 64, (BB * SS) / 128), dim3(256), 0, stream>>>(
      queryb, wqb, bq, (void*)Qfrag, BB * SS, DIM, DIM);

  // fused single-pass attention: 16 rows/wave, L-split pairs (O + dinv)
  attn_pv<<<dim3(4096), dim3(256), 0, stream>>>(Qfrag, Kfrag, Vfrag, mbits, out01, db);

  // head-mean attention maps straight into d_out
  amean<<<dim3(4096), dim3(256), 0, stream>>>(Qfrag, Kfrag, mbits, db, out + nQ);

  merge_kernel<<<dim3((int)(nQ / 4 / 256)), dim3(256), 0, stream>>>(out01, gate, mergedb);

  gemm_nt<1><<<dim3(DIM / 64, (BB * SS) / 128), dim3(256), 0, stream>>>(
      mergedb, wob, bo, (void*)out, BB * SS, DIM, DIM);
}

// Round 9
// 288.676 us; speedup vs baseline: 2.9742x; 1.1282x over previous
//
#include <hip/hip_runtime.h>

#define DIM   1024
#define HEADS 16
#define HD    64
#define BB    2
#define SS    2048
#define LLL   2048
#define LOG2E 1.4426950408889634f

typedef __bf16 bf16x8 __attribute__((ext_vector_type(8)));
typedef __bf16 bf16x4v __attribute__((ext_vector_type(4)));
typedef float  f32x4  __attribute__((ext_vector_type(4)));
typedef short  s16x4  __attribute__((ext_vector_type(4)));
typedef short  s16x8  __attribute__((ext_vector_type(8)));
typedef unsigned short u16;

static __device__ __forceinline__ u16 f2b(float x) {
  unsigned u = __float_as_uint(x);
  u += 0x7fffu + ((u >> 16) & 1u);
  return (u16)(u >> 16);
}
static __device__ __forceinline__ float b2f(u16 u) {
  return __uint_as_float(((unsigned)u) << 16);
}
static __device__ __forceinline__ f32x4 mfma32(bf16x8 a, bf16x8 b, f32x4 c) {
  return __builtin_amdgcn_mfma_f32_16x16x32_bf16(a, b, c, 0, 0, 0);
}
static __device__ __forceinline__ f32x4 mfma16(s16x4 a, s16x4 b, f32x4 c) {
#if __has_builtin(__builtin_amdgcn_mfma_f32_16x16x16bf16_1k)
  return __builtin_amdgcn_mfma_f32_16x16x16bf16_1k(a, b, c, 0, 0, 0);
#else
  asm volatile("v_mfma_f32_16x16x16_bf16 %0, %1, %2, %0" : "+v"(c) : "v"(a), "v"(b));
  return c;
#endif
}

// async global->LDS, 16B/lane. LDS base must be WAVE-UNIFORM (HW adds lane*16).
static __device__ __forceinline__ void gload_lds16(const void* g, void* lds_uniform_base) {
#if __has_builtin(__builtin_amdgcn_global_load_lds)
  __builtin_amdgcn_global_load_lds(
      (const __attribute__((address_space(1))) unsigned int*)g,
      (__attribute__((address_space(3))) unsigned int*)lds_uniform_base, 16, 0, 0);
#else
  // fallback: reg staging (lane-linear layout matches)
  const int l = threadIdx.x & 63;
  ((uint4*)lds_uniform_base)[l] = ((const uint4*)g)[0];
#endif
}

// ---------------- f32 -> bf16 convert ----------------
__global__ void cvt_f32_bf16(const float* __restrict__ src, u16* __restrict__ dst, int n4) {
  int i = blockIdx.x * blockDim.x + threadIdx.x;
  if (i >= n4) return;
  float4 f = ((const float4*)src)[i];
  ushort4 o;
  o.x = f2b(f.x); o.y = f2b(f.y); o.z = f2b(f.z); o.w = f2b(f.w);
  ((ushort4*)dst)[i] = o;
}

// ---------------- mask -> bitmask ----------------
__global__ void mask_pack(const int* __restrict__ mask, unsigned* __restrict__ mbits) {
  int i = blockIdx.x * blockDim.x + threadIdx.x;
  const int* src = mask + (size_t)i * 32;
  unsigned bm = 0;
#pragma unroll
  for (int j = 0; j < 8; ++j) {
    int4 m = ((const int4*)src)[j];
    bm |= (m.x != 0 ? 1u : 0u) << (j * 4 + 0);
    bm |= (m.y != 0 ? 1u : 0u) << (j * 4 + 1);
    bm |= (m.z != 0 ? 1u : 0u) << (j * 4 + 2);
    bm |= (m.w != 0 ? 1u : 0u) << (j * 4 + 3);
  }
  mbits[i] = bm;
}

// ---------------- K (f32) -> fragment-packed bf16 tiles, PRESCALED by 0.125*log2(e) ----------------
__global__ __launch_bounds__(256) void pack_k(const float* __restrict__ k0,
                                              const float* __restrict__ k1,
                                              u16* __restrict__ Kfrag) {
  const float SCK = 0.125f * LOG2E;
  const int w = threadIdx.x >> 6, l = threadIdx.x & 63, g = l >> 4, li = l & 15;
  const int lt = blockIdx.x * 4 + w, h = blockIdx.y, z = blockIdx.z;
  const int lay = z >> 1, b = z & 1;
  const float* src = (lay ? k1 : k0) + (size_t)b * LLL * DIM;
  u16* dst = Kfrag + ((((size_t)z * HEADS + h) * 32 + lt) * 8) * 512;
#pragma unroll
  for (int c = 0; c < 8; ++c) {
    int mt = c >> 1, kk = c & 1;
    const float* p = &src[(size_t)(lt * 64 + mt * 16 + li) * DIM + h * 64 + kk * 32 + g * 8];
    float4 f0 = *(const float4*)p;
    float4 f1 = *(const float4*)(p + 4);
    u16 u[8] = {f2b(f0.x * SCK), f2b(f0.y * SCK), f2b(f0.z * SCK), f2b(f0.w * SCK),
                f2b(f1.x * SCK), f2b(f1.y * SCK), f2b(f1.z * SCK), f2b(f1.w * SCK)};
    *(uint4*)&dst[c * 512 + l * 8] = *(uint4*)u;
  }
}

// ---------------- V (f32) -> fragment-packed bf16 tiles (transposed) ----------------
__global__ __launch_bounds__(256) void pack_v(const float* __restrict__ v0,
                                              const float* __restrict__ v1,
                                              u16* __restrict__ Vfrag) {
  __shared__ u16 T[64][72];  // T[l][d]
  const int lt = blockIdx.x, h = blockIdx.y, z = blockIdx.z;
  const int lay = z >> 1, b = z & 1;
  const float* v = (lay ? v1 : v0) + (size_t)b * LLL * DIM;
  const int t = threadIdx.x;
  {
    int r = t >> 2, c16 = (t & 3) * 16;
    const float* src = &v[(size_t)(lt * 64 + r) * DIM + h * 64 + c16];
#pragma unroll
    for (int i = 0; i < 4; ++i) {
      float4 f = *(const float4*)&src[i * 4];
      T[r][c16 + i * 4 + 0] = f2b(f.x);
      T[r][c16 + i * 4 + 1] = f2b(f.y);
      T[r][c16 + i * 4 + 2] = f2b(f.z);
      T[r][c16 + i * 4 + 3] = f2b(f.w);
    }
  }
  __syncthreads();
  u16* dst = Vfrag + ((((size_t)z * HEADS + h) * 32 + lt) * 8) * 512;
  {
    int lane = t & 63, g = lane >> 4, li = lane & 15;
#pragma unroll
    for (int cc = 0; cc < 2; ++cc) {
      int c = (t >> 6) + cc * 4;
      int mt = c >> 1, p = c & 1;
      u16 u[8];
#pragma unroll
      for (int j = 0; j < 4; ++j) u[j] = T[mt * 16 + 4 * g + j][p * 32 + li];
#pragma unroll
      for (int j = 0; j < 4; ++j) u[4 + j] = T[mt * 16 + 4 * g + j][p * 32 + 16 + li];
      *(uint4*)&dst[c * 512 + lane * 8] = *(uint4*)u;
    }
  }
}

// ---------------- bf16 NT GEMM, 128x64 tile. MODE 1: f32 row-major out; MODE 2: Q-fragment out
template<int MODE>
__global__ __launch_bounds__(256) void gemm_nt(const u16* __restrict__ A,
                                               const u16* __restrict__ Bt,
                                               const float* __restrict__ bias,
                                               void* __restrict__ Cv,
                                               int M, int N, int K) {
  __shared__ u16 As[128][64];
  __shared__ u16 Bs[64][64];
  const int t = threadIdx.x;
  const int w = t >> 6, l = t & 63, g = l >> 4, li = l & 15;
  const int m0 = blockIdx.y * 128, n0 = blockIdx.x * 64;
  f32x4 acc[2][4] = {};
  for (int kt = 0; kt < K; kt += 64) {
#pragma unroll
    for (int s = 0; s < 4; ++s) {
      int slot = t + s * 256;
      int r = slot >> 3, c8 = (slot & 7) * 8;
      *(uint4*)&As[r][c8 ^ ((r & 7) << 3)] = *(const uint4*)&A[(size_t)(m0 + r) * K + kt + c8];
    }
#pragma unroll
    for (int s = 0; s < 2; ++s) {
      int slot = t + s * 256;
      int r = slot >> 3, c8 = (slot & 7) * 8;
      *(uint4*)&Bs[r][c8 ^ ((r & 7) << 3)] = *(const uint4*)&Bt[(size_t)(n0 + r) * K + kt + c8];
    }
    __syncthreads();
#pragma unroll
    for (int kk = 0; kk < 2; ++kk) {
      bf16x8 a[2], bfr[4];
#pragma unroll
      for (int mi = 0; mi < 2; ++mi) {
        int ra = w * 32 + mi * 16 + li;
        a[mi] = *(const bf16x8*)&As[ra][(kk * 32 + g * 8) ^ ((ra & 7) << 3)];
      }
#pragma unroll
      for (int ni = 0; ni < 4; ++ni) {
        int rb = ni * 16 + li;
        bfr[ni] = *(const bf16x8*)&Bs[rb][(kk * 32 + g * 8) ^ ((rb & 7) << 3)];
      }
#pragma unroll
      for (int mi = 0; mi < 2; ++mi)
#pragma unroll
        for (int ni = 0; ni < 4; ++ni)
          acc[mi][ni] = mfma32(a[mi], bfr[ni], acc[mi][ni]);
    }
    __syncthreads();
  }
#pragma unroll
  for (int mi = 0; mi < 2; ++mi)
#pragma unroll
    for (int ni = 0; ni < 4; ++ni)
#pragma unroll
      for (int v = 0; v < 4; ++v) {
        int rr = m0 + w * 32 + mi * 16 + g * 4 + v;
        int cc = n0 + ni * 16 + li;
        float val = acc[mi][ni][v] + bias[cc];
        if (MODE == 1) {
          ((float*)Cv)[(size_t)rr * N + cc] = val;
        } else {
          // Qfrag[b][h][qt][c=n*2+kk][lane(gp,liq)][8]
          int b = rr >> 11, q = rr & 2047;
          int qt = q >> 5, n = (q >> 4) & 1, liq = q & 15;
          int h = (cc >> 6) & 15, kk2 = (cc >> 5) & 1, gp = (cc >> 3) & 3, j = cc & 7;
          size_t base = ((((size_t)b * HEADS + h) * 64 + qt) * 4 + n * 2 + kk2) * 512;
          ((u16*)Cv)[base + (size_t)(gp * 16 + liq) * 8 + j] = f2b(val);
        }
      }
}

// ---------------- attn_pv: m97-style LDS-staged. Block = 4 waves = 4 qt2, same (z,h), full L ----------------
// LDS tile per lt: K 8KB + V 8KB staged via global_load_lds; 2 barriers/lt.
// db layout: [z*HEADS+h][q] = dinv
template<int MASKED>
static __device__ __forceinline__ void attn_pv_body(int z, int h, int qt2, int w, int l,
                                                    const u16* __restrict__ Qfrag,
                                                    const u16* __restrict__ Kfrag,
                                                    const u16* __restrict__ Vfrag,
                                                    const unsigned* __restrict__ mbits,
                                                    u16* __restrict__ out01,
                                                    float* __restrict__ db,
                                                    u16* __restrict__ KV) {
  const int g = l >> 4, li = l & 15;
  const int b = z & 1;
  const int qt = qt2 >> 1, n = qt2 & 1;
  const u16* kfh = Kfrag + (size_t)(z * HEADS + h) * (32 * 8 * 512);
  const u16* vfh = Vfrag + (size_t)(z * HEADS + h) * (32 * 8 * 512);
  const u16* qfh = Qfrag + ((((size_t)(b * HEADS + h) * 64 + qt) * 4 + n * 2)) * 512;

  bf16x8 qf0 = *(const bf16x8*)&qfh[0 * 512 + l * 8];
  bf16x8 qf1 = *(const bf16x8*)&qfh[1 * 512 + l * 8];

  const unsigned* mrow = MASKED ? mbits + (size_t)(qt2 * 16 + li) * (LLL / 32) : nullptr;
  const int shb = 4 * g;

  f32x4 racc4 = {};
  f32x4 oacc[4] = {};  // [dt], unnormalized
  for (int lt = 0; lt < 32; ++lt) {
    // cooperative stage: wave w stages fragments f = w*4 .. w*4+3 (f<8: K, else V)
    {
      const u16* kfl = kfh + (size_t)lt * 4096;
      const u16* vfl = vfh + (size_t)lt * 4096;
#pragma unroll
      for (int i = 0; i < 4; ++i) {
        int f = w * 4 + i;
        const u16* gsrc = (f < 8 ? kfl + f * 512 : vfl + (f - 8) * 512) + l * 8;
        gload_lds16(gsrc, (char*)KV + f * 1024);
      }
    }
    unsigned mw[2];
    if (MASKED) { mw[0] = mrow[lt * 2]; mw[1] = mrow[lt * 2 + 1]; }
    __syncthreads();  // drains global_load_lds (vmcnt 0) + aligns waves
    const u16* Ks = KV;
    const u16* Vs = KV + 4096;
#pragma unroll
    for (int mt = 0; mt < 4; ++mt) {
      f32x4 s = {};
      __builtin_amdgcn_s_setprio(1);
      s = mfma32(*(const bf16x8*)&Ks[(mt * 2 + 0) * 512 + l * 8], qf0, s);
      s = mfma32(*(const bf16x8*)&Ks[(mt * 2 + 1) * 512 + l * 8], qf1, s);
      __builtin_amdgcn_s_setprio(0);
      f32x4 ev;
      unsigned mm = MASKED ? (mw[mt >> 1] >> ((mt & 1) * 16 + shb)) : 0u;
#pragma unroll
      for (int v = 0; v < 4; ++v) {
        float arg = s[v];
        if (MASKED) {
          int spread = ((int)(mm << (31 - v))) >> 31;  // all-ones if keep
          float bias = __uint_as_float((~(unsigned)spread) & 0xC3200000u);  // -160 if drop
          arg = s[v] + bias;
        }
        ev[v] = __builtin_amdgcn_exp2f(arg);
      }
      racc4 += ev;
      bf16x4v wb = __builtin_convertvector(ev, bf16x4v);
      s16x4 wpk = __builtin_bit_cast(s16x4, wb);
      __builtin_amdgcn_s_setprio(1);
#pragma unroll
      for (int p = 0; p < 2; ++p) {
        s16x8 vf = *(const s16x8*)&Vs[(mt * 2 + p) * 512 + l * 8];
        s16x4 lo = __builtin_shufflevector(vf, vf, 0, 1, 2, 3);
        s16x4 hi = __builtin_shufflevector(vf, vf, 4, 5, 6, 7);
        oacc[2 * p + 0] = mfma16(lo, wpk, oacc[2 * p + 0]);
        oacc[2 * p + 1] = mfma16(hi, wpk, oacc[2 * p + 1]);
      }
      __builtin_amdgcn_s_setprio(0);
    }
    __syncthreads();  // protect tile before next stage overwrites
  }
  float r = racc4[0] + racc4[1] + racc4[2] + racc4[3];
  r += __shfl_xor(r, 16);
  r += __shfl_xor(r, 32);
  float dinv = 1.0f / r;
  if (l < 16) db[(size_t)(z * HEADS + h) * SS + qt2 * 16 + li] = dinv;
  u16* ob = out01 + (size_t)z * SS * DIM;
#pragma unroll
  for (int dt = 0; dt < 4; ++dt) {
    f32x4 o = oacc[dt] * dinv;
    ushort4 us;
    us.x = f2b(o[0]); us.y = f2b(o[1]); us.z = f2b(o[2]); us.w = f2b(o[3]);
    *(ushort4*)&ob[((size_t)(qt2 * 16 + li)) * DIM + h * HD + dt * 16 + 4 * g] = us;
  }
}

__global__ __launch_bounds__(256, 8) void attn_pv(const u16* __restrict__ Qfrag,
                                                  const u16* __restrict__ Kfrag,
                                                  const u16* __restrict__ Vfrag,
                                                  const unsigned* __restrict__ mbits,
                                                  u16* __restrict__ out01,
                                                  float* __restrict__ db) {
  __shared__ u16 KV[8192];  // 16 KB: K tile (8KB) + V tile (8KB) for one lt
  const int flat = blockIdx.x;
  const int wb = (flat & 7) * 256 + (flat >> 3);  // XCD-contiguous (2048 blocks)
  const int z = wb >> 9, rem = wb & 511;
  const int h = rem >> 5, qg = rem & 31;
  const int w = threadIdx.x >> 6, l = threadIdx.x & 63;
  const int qt2 = qg * 4 + w;
  if (z < 2) attn_pv_body<1>(z, h, qt2, w, l, Qfrag, Kfrag, Vfrag, mbits, out01, db, KV);
  else       attn_pv_body<0>(z, h, qt2, w, l, Qfrag, Kfrag, Vfrag, mbits, out01, db, KV);
}

// ---------------- amean: head-mean map (R6/R8 body) ----------------
template<int MASKED>
static __device__ __forceinline__ void amean_body(int z, int qt2, int lt, int l,
                                                  const u16* __restrict__ Qfrag,
                                                  const u16* __restrict__ Kfrag,
                                                  const unsigned* __restrict__ mbits,
                                                  const float* __restrict__ db,
                                                  float* __restrict__ aout) {
  const int g = l >> 4, li = l & 15;
  const int b = z & 1;
  const int qt = qt2 >> 1, n = qt2 & 1;

  unsigned mw[2];
  if (MASKED) {
    const unsigned* m0 = mbits + (size_t)(qt2 * 16 + li) * (LLL / 32) + lt * 2;
    mw[0] = m0[0]; mw[1] = m0[1];
  }
  const u16* kf_base = Kfrag + (size_t)(z * HEADS) * (32 * 8 * 512) + (size_t)lt * 4096 + l * 8;
  const u16* qf_base = Qfrag + ((((size_t)(b * HEADS) * 64 + qt) * 4 + n * 2)) * 512 + l * 8;
  const float* dbb = db + (size_t)(z * HEADS) * SS + qt2 * 16 + li;

  f32x4 asum[4] = {};
#pragma unroll 2
  for (int h = 0; h < HEADS; ++h) {
    float l2 = __log2f(dbb[(size_t)h * SS]);
    bf16x8 qf0 = *(const bf16x8*)&qf_base[(size_t)h * (64 * 4 * 512)];
    bf16x8 qf1 = *(const bf16x8*)&qf_base[(size_t)h * (64 * 4 * 512) + 512];
    const u16* kfh = kf_base + (size_t)h * (32 * 8 * 512);
#pragma unroll
    for (int mt = 0; mt < 4; ++mt) {
      f32x4 s = {};
      s = mfma32(*(const bf16x8*)&kfh[(mt * 2 + 0) * 512], qf0, s);
      s = mfma32(*(const bf16x8*)&kfh[(mt * 2 + 1) * 512], qf1, s);
      unsigned mm = MASKED ? (mw[mt >> 1] >> ((mt & 1) * 16 + 4 * g)) : 0u;
#pragma unroll
      for (int v = 0; v < 4; ++v) {
        float bias = l2;
        if (MASKED && !((mm >> v) & 1u)) bias = -160.0f;
        asum[mt][v] += __builtin_amdgcn_exp2f(s[v] + bias);
      }
    }
  }
  float* ab = aout + (size_t)z * SS * LLL;
#pragma unroll
  for (int mt = 0; mt < 4; ++mt) {
    f32x4 o = asum[mt] * 0.0625f;
    f32x4* dst = (f32x4*)&ab[(size_t)(qt2 * 16 + li) * LLL + lt * 64 + mt * 16 + 4 * g];
    __builtin_nontemporal_store(o, dst);
  }
}

__global__ __launch_bounds__(256, 8) void amean(const u16* __restrict__ Qfrag,
                                                const u16* __restrict__ Kfrag,
                                                const unsigned* __restrict__ mbits,
                                                const float* __restrict__ db,
                                                float* __restrict__ aout) {
  const int flat = blockIdx.x;
  const int wb = (flat & 7) * 512 + (flat >> 3);   // XCD-contiguous chunks (4096 blocks)
  const int widx = wb * 4 + (threadIdx.x >> 6);    // 16384 waves
  const int z = widx >> 12, rem = widx & 4095;
  const int lt = rem >> 7, qt2 = rem & 127;        // block = 4 qt2 of same (z,lt): share K tile
  if (z < 2) amean_body<1>(z, qt2, lt, threadIdx.x & 63, Qfrag, Kfrag, mbits, db, aout);
  else       amean_body<0>(z, qt2, lt, threadIdx.x & 63, Qfrag, Kfrag, mbits, db, aout);
}

// ---------------- gated merge ----------------
__global__ void merge_kernel(const u16* __restrict__ o01,
                             const float* __restrict__ gate,
                             u16* __restrict__ merged) {
  int i = blockIdx.x * blockDim.x + threadIdx.x;
  float gv = gate[0];
  float g = 1.0f / (1.0f + __builtin_amdgcn_exp2f(-gv * LOG2E));
  const size_t n = (size_t)BB * SS * DIM;
  ushort4 a = ((const ushort4*)o01)[i];
  ushort4 c = ((const ushort4*)(o01 + n))[i];
  ushort4 o;
  o.x = f2b(g * b2f(a.x) + (1.f - g) * b2f(c.x));
  o.y = f2b(g * b2f(a.y) + (1.f - g) * b2f(c.y));
  o.z = f2b(g * b2f(a.z) + (1.f - g) * b2f(c.z));
  o.w = f2b(g * b2f(a.w) + (1.f - g) * b2f(c.w));
  ((ushort4*)merged)[i] = o;
}

extern "C" void kernel_launch(void* const* d_in, const int* in_sizes, int n_in,
                              void* d_out, int out_size, void* d_ws, size_t ws_size,
                              hipStream_t stream) {
  const float* query = (const float*)d_in[0];
  const float* k0f   = (const float*)d_in[1];
  const float* v0f   = (const float*)d_in[2];
  const float* k1f   = (const float*)d_in[3];
  const float* v1f   = (const float*)d_in[4];
  const int*   mask  = (const int*)d_in[5];
  const float* Wqf   = (const float*)d_in[6];
  const float* bq    = (const float*)d_in[7];
  const float* Wof   = (const float*)d_in[8];
  const float* bo    = (const float*)d_in[9];
  const float* gate  = (const float*)d_in[10];
  float* out = (float*)d_out;

  const size_t nQ = (size_t)BB * SS * DIM;
  const size_t nW = (size_t)DIM * DIM;

  char* ws = (char*)d_ws;
  size_t off = 0;
  auto alloc = [&](size_t bytes) -> char* {
    char* p = ws + off;
    off += (bytes + 255) & ~(size_t)255;
    return p;
  };
  u16*      queryb  = (u16*)alloc(nQ * 2);             // reused as mergedb later
  u16*      wqb     = (u16*)alloc(nW * 2);
  u16*      wob     = (u16*)alloc(nW * 2);
  u16*      Qfrag   = (u16*)alloc(nQ * 2);             // [b][h][qt][c][lane][8]
  u16*      Kfrag   = (u16*)alloc((size_t)2 * nQ * 2); // [z][h][lt][c][lane][8] (prescaled)
  u16*      Vfrag   = (u16*)alloc((size_t)2 * nQ * 2);
  unsigned* mbits   = (unsigned*)alloc((size_t)SS * (LLL / 32) * 4);
  float*    db      = (float*)alloc((size_t)4 * HEADS * SS * 4);  // dinv per [z][h][q]
  u16*      out01   = (u16*)alloc((size_t)2 * nQ * 2);
  u16*      mergedb = queryb;  // queryb dead after q-proj gemm

  auto cvt = [&](const float* s, u16* d, size_t n) {
    int n4 = (int)(n / 4);
    cvt_f32_bf16<<<dim3((n4 + 255) / 256), dim3(256), 0, stream>>>(s, d, n4);
  };
  cvt(query, queryb, nQ);
  cvt(Wqf, wqb, nW);
  cvt(Wof, wob, nW);

  mask_pack<<<dim3(SS * (LLL / 32) / 256), dim3(256), 0, stream>>>(mask, mbits);
  pack_k<<<dim3(LLL / 64 / 4, HEADS, 4), dim3(256), 0, stream>>>(k0f, k1f, Kfrag);
  pack_v<<<dim3(LLL / 64, HEADS, 4), dim3(256), 0, stream>>>(v0f, v1f, Vfrag);

  // q projection straight into fragment layout (128x64 tiles)
  gemm_nt<2><<<dim3(DIM / 64, (BB * SS) / 128), dim3(256), 0, stream>>>(
      queryb, wqb, bq, (void*)Qfrag, BB * SS, DIM, DIM);

  // fused single-pass attention: LDS-staged K/V tiles, 64 q-rows per block
  attn_pv<<<dim3(2048), dim3(256), 0, stream>>>(Qfrag, Kfrag, Vfrag, mbits, out01, db);

  // head-mean attention maps straight into d_out
  amean<<<dim3(4096), dim3(256), 0, stream>>>(Qfrag, Kfrag, mbits, db, out + nQ);

  merge_kernel<<<dim3((int)(nQ / 4 / 256)), dim3(256), 0, stream>>>(out01, gate, mergedb);

  gemm_nt<1><<<dim3(DIM / 64, (BB * SS) / 128), dim3(256), 0, stream>>>(
      mergedb, wob, bo, (void*)out, BB * SS, DIM, DIM);
}

// Round 10
// 265.760 us; speedup vs baseline: 3.2307x; 1.0862x over previous
//
#include <hip/hip_runtime.h>

#define DIM   1024
#define HEADS 16
#define HD    64
#define BB    2
#define SS    2048
#define LLL   2048
#define LOG2E 1.4426950408889634f

typedef __bf16 bf16x8 __attribute__((ext_vector_type(8)));
typedef __bf16 bf16x4v __attribute__((ext_vector_type(4)));
typedef float  f32x4  __attribute__((ext_vector_type(4)));
typedef short  s16x4  __attribute__((ext_vector_type(4)));
typedef short  s16x8  __attribute__((ext_vector_type(8)));
typedef unsigned short u16;

static __device__ __forceinline__ u16 f2b(float x) {
  unsigned u = __float_as_uint(x);
  u += 0x7fffu + ((u >> 16) & 1u);
  return (u16)(u >> 16);
}
static __device__ __forceinline__ float b2f(u16 u) {
  return __uint_as_float(((unsigned)u) << 16);
}
static __device__ __forceinline__ f32x4 mfma32(bf16x8 a, bf16x8 b, f32x4 c) {
  return __builtin_amdgcn_mfma_f32_16x16x32_bf16(a, b, c, 0, 0, 0);
}
static __device__ __forceinline__ f32x4 mfma16(s16x4 a, s16x4 b, f32x4 c) {
#if __has_builtin(__builtin_amdgcn_mfma_f32_16x16x16bf16_1k)
  return __builtin_amdgcn_mfma_f32_16x16x16bf16_1k(a, b, c, 0, 0, 0);
#else
  asm volatile("v_mfma_f32_16x16x16_bf16 %0, %1, %2, %0" : "+v"(c) : "v"(a), "v"(b));
  return c;
#endif
}

// async global->LDS, 16B/lane. LDS base must be WAVE-UNIFORM (HW adds lane*16).
static __device__ __forceinline__ void gload_lds16(const void* g, void* lds_uniform_base) {
#if __has_builtin(__builtin_amdgcn_global_load_lds)
  __builtin_amdgcn_global_load_lds(
      (const __attribute__((address_space(1))) unsigned int*)g,
      (__attribute__((address_space(3))) unsigned int*)lds_uniform_base, 16, 0, 0);
#else
  const int l = threadIdx.x & 63;
  ((uint4*)lds_uniform_base)[l] = ((const uint4*)g)[0];
#endif
}

// ---------------- f32 -> bf16 convert ----------------
__global__ void cvt_f32_bf16(const float* __restrict__ src, u16* __restrict__ dst, int n4) {
  int i = blockIdx.x * blockDim.x + threadIdx.x;
  if (i >= n4) return;
  float4 f = ((const float4*)src)[i];
  ushort4 o;
  o.x = f2b(f.x); o.y = f2b(f.y); o.z = f2b(f.z); o.w = f2b(f.w);
  ((ushort4*)dst)[i] = o;
}

// ---------------- mask -> bitmask ----------------
__global__ void mask_pack(const int* __restrict__ mask, unsigned* __restrict__ mbits) {
  int i = blockIdx.x * blockDim.x + threadIdx.x;
  const int* src = mask + (size_t)i * 32;
  unsigned bm = 0;
#pragma unroll
  for (int j = 0; j < 8; ++j) {
    int4 m = ((const int4*)src)[j];
    bm |= (m.x != 0 ? 1u : 0u) << (j * 4 + 0);
    bm |= (m.y != 0 ? 1u : 0u) << (j * 4 + 1);
    bm |= (m.z != 0 ? 1u : 0u) << (j * 4 + 2);
    bm |= (m.w != 0 ? 1u : 0u) << (j * 4 + 3);
  }
  mbits[i] = bm;
}

// ---------------- K (f32) -> fragment-packed bf16 tiles, PRESCALED by 0.125*log2(e) ----------------
__global__ __launch_bounds__(256) void pack_k(const float* __restrict__ k0,
                                              const float* __restrict__ k1,
                                              u16* __restrict__ Kfrag) {
  const float SCK = 0.125f * LOG2E;
  const int w = threadIdx.x >> 6, l = threadIdx.x & 63, g = l >> 4, li = l & 15;
  const int lt = blockIdx.x * 4 + w, h = blockIdx.y, z = blockIdx.z;
  const int lay = z >> 1, b = z & 1;
  const float* src = (lay ? k1 : k0) + (size_t)b * LLL * DIM;
  u16* dst = Kfrag + ((((size_t)z * HEADS + h) * 32 + lt) * 8) * 512;
#pragma unroll
  for (int c = 0; c < 8; ++c) {
    int mt = c >> 1, kk = c & 1;
    const float* p = &src[(size_t)(lt * 64 + mt * 16 + li) * DIM + h * 64 + kk * 32 + g * 8];
    float4 f0 = *(const float4*)p;
    float4 f1 = *(const float4*)(p + 4);
    u16 u[8] = {f2b(f0.x * SCK), f2b(f0.y * SCK), f2b(f0.z * SCK), f2b(f0.w * SCK),
                f2b(f1.x * SCK), f2b(f1.y * SCK), f2b(f1.z * SCK), f2b(f1.w * SCK)};
    *(uint4*)&dst[c * 512 + l * 8] = *(uint4*)u;
  }
}

// ---------------- V (f32) -> fragment-packed bf16 tiles (transposed) ----------------
__global__ __launch_bounds__(256) void pack_v(const float* __restrict__ v0,
                                              const float* __restrict__ v1,
                                              u16* __restrict__ Vfrag) {
  __shared__ u16 T[64][72];  // T[l][d]
  const int lt = blockIdx.x, h = blockIdx.y, z = blockIdx.z;
  const int lay = z >> 1, b = z & 1;
  const float* v = (lay ? v1 : v0) + (size_t)b * LLL * DIM;
  const int t = threadIdx.x;
  {
    int r = t >> 2, c16 = (t & 3) * 16;
    const float* src = &v[(size_t)(lt * 64 + r) * DIM + h * 64 + c16];
#pragma unroll
    for (int i = 0; i < 4; ++i) {
      float4 f = *(const float4*)&src[i * 4];
      T[r][c16 + i * 4 + 0] = f2b(f.x);
      T[r][c16 + i * 4 + 1] = f2b(f.y);
      T[r][c16 + i * 4 + 2] = f2b(f.z);
      T[r][c16 + i * 4 + 3] = f2b(f.w);
    }
  }
  __syncthreads();
  u16* dst = Vfrag + ((((size_t)z * HEADS + h) * 32 + lt) * 8) * 512;
  {
    int lane = t & 63, g = lane >> 4, li = lane & 15;
#pragma unroll
    for (int cc = 0; cc < 2; ++cc) {
      int c = (t >> 6) + cc * 4;
      int mt = c >> 1, p = c & 1;
      u16 u[8];
#pragma unroll
      for (int j = 0; j < 4; ++j) u[j] = T[mt * 16 + 4 * g + j][p * 32 + li];
#pragma unroll
      for (int j = 0; j < 4; ++j) u[4 + j] = T[mt * 16 + 4 * g + j][p * 32 + 16 + li];
      *(uint4*)&dst[c * 512 + lane * 8] = *(uint4*)u;
    }
  }
}

// ---------------- bf16 NT GEMM, 128x64 tile. MODE 1: f32 row-major out; MODE 2: Q-fragment out
template<int MODE>
__global__ __launch_bounds__(256) void gemm_nt(const u16* __restrict__ A,
                                               const u16* __restrict__ Bt,
                                               const float* __restrict__ bias,
                                               void* __restrict__ Cv,
                                               int M, int N, int K) {
  __shared__ u16 As[128][64];
  __shared__ u16 Bs[64][64];
  const int t = threadIdx.x;
  const int w = t >> 6, l = t & 63, g = l >> 4, li = l & 15;
  const int m0 = blockIdx.y * 128, n0 = blockIdx.x * 64;
  f32x4 acc[2][4] = {};
  for (int kt = 0; kt < K; kt += 64) {
#pragma unroll
    for (int s = 0; s < 4; ++s) {
      int slot = t + s * 256;
      int r = slot >> 3, c8 = (slot & 7) * 8;
      *(uint4*)&As[r][c8 ^ ((r & 7) << 3)] = *(const uint4*)&A[(size_t)(m0 + r) * K + kt + c8];
    }
#pragma unroll
    for (int s = 0; s < 2; ++s) {
      int slot = t + s * 256;
      int r = slot >> 3, c8 = (slot & 7) * 8;
      *(uint4*)&Bs[r][c8 ^ ((r & 7) << 3)] = *(const uint4*)&Bt[(size_t)(n0 + r) * K + kt + c8];
    }
    __syncthreads();
#pragma unroll
    for (int kk = 0; kk < 2; ++kk) {
      bf16x8 a[2], bfr[4];
#pragma unroll
      for (int mi = 0; mi < 2; ++mi) {
        int ra = w * 32 + mi * 16 + li;
        a[mi] = *(const bf16x8*)&As[ra][(kk * 32 + g * 8) ^ ((ra & 7) << 3)];
      }
#pragma unroll
      for (int ni = 0; ni < 4; ++ni) {
        int rb = ni * 16 + li;
        bfr[ni] = *(const bf16x8*)&Bs[rb][(kk * 32 + g * 8) ^ ((rb & 7) << 3)];
      }
#pragma unroll
      for (int mi = 0; mi < 2; ++mi)
#pragma unroll
        for (int ni = 0; ni < 4; ++ni)
          acc[mi][ni] = mfma32(a[mi], bfr[ni], acc[mi][ni]);
    }
    __syncthreads();
  }
#pragma unroll
  for (int mi = 0; mi < 2; ++mi)
#pragma unroll
    for (int ni = 0; ni < 4; ++ni)
#pragma unroll
      for (int v = 0; v < 4; ++v) {
        int rr = m0 + w * 32 + mi * 16 + g * 4 + v;
        int cc = n0 + ni * 16 + li;
        float val = acc[mi][ni][v] + bias[cc];
        if (MODE == 1) {
          ((float*)Cv)[(size_t)rr * N + cc] = val;
        } else {
          // Qfrag[b][h][qt][c=n*2+kk][lane(gp,liq)][8]
          int b = rr >> 11, q = rr & 2047;
          int qt = q >> 5, n = (q >> 4) & 1, liq = q & 15;
          int h = (cc >> 6) & 15, kk2 = (cc >> 5) & 1, gp = (cc >> 3) & 3, j = cc & 7;
          size_t base = ((((size_t)b * HEADS + h) * 64 + qt) * 4 + n * 2 + kk2) * 512;
          ((u16*)Cv)[base + (size_t)(gp * 16 + liq) * 8 + j] = f2b(val);
        }
      }
}

// ---------------- attn_pv: 8 waves share double-buffered LDS K/V tile; z-balanced XCD map ----------------
// db layout: [z*HEADS+h][q] = dinv
template<int MASKED>
static __device__ __forceinline__ void attn_pv_body(int z, int h, int qt2, int w, int l,
                                                    const u16* __restrict__ Qfrag,
                                                    const u16* __restrict__ Kfrag,
                                                    const u16* __restrict__ Vfrag,
                                                    const unsigned* __restrict__ mbits,
                                                    u16* __restrict__ out01,
                                                    float* __restrict__ db,
                                                    u16* __restrict__ KV) {
  const int g = l >> 4, li = l & 15;
  const int b = z & 1;
  const int qt = qt2 >> 1, n = qt2 & 1;
  const u16* kfh = Kfrag + (size_t)(z * HEADS + h) * (32 * 8 * 512);
  const u16* vfh = Vfrag + (size_t)(z * HEADS + h) * (32 * 8 * 512);
  const u16* qfh = Qfrag + ((((size_t)(b * HEADS + h) * 64 + qt) * 4 + n * 2)) * 512;

  bf16x8 qf0 = *(const bf16x8*)&qfh[0 * 512 + l * 8];
  bf16x8 qf1 = *(const bf16x8*)&qfh[1 * 512 + l * 8];

  const unsigned* mrow = MASKED ? mbits + (size_t)(qt2 * 16 + li) * (LLL / 32) : nullptr;
  const int shb = 4 * g;

  // stage: wave w stages fragments f = 2w, 2w+1 (f<8: K, else V) of tile lt into buffer buf
  auto stage = [&](int buf, int lt) {
    const u16* kfl = kfh + (size_t)lt * 4096;
    const u16* vfl = vfh + (size_t)lt * 4096;
#pragma unroll
    for (int i2 = 0; i2 < 2; ++i2) {
      int f = w * 2 + i2;
      const u16* gsrc = (f < 8 ? kfl + f * 512 : vfl + (f - 8) * 512) + l * 8;
      gload_lds16(gsrc, (char*)KV + buf * 16384 + f * 1024);
    }
  };

  f32x4 racc4 = {};
  f32x4 oacc[4] = {};  // [dt], unnormalized

  stage(0, 0);
  __syncthreads();
  int cur = 0;
  for (int lt = 0; lt < 32; ++lt) {
    if (lt + 1 < 32) stage(cur ^ 1, lt + 1);  // prefetch flies under compute
    unsigned mw[2];
    if (MASKED) { mw[0] = mrow[lt * 2]; mw[1] = mrow[lt * 2 + 1]; }
    const u16* Ks = KV + cur * 8192;
    const u16* Vs = Ks + 4096;
#pragma unroll
    for (int mt = 0; mt < 4; ++mt) {
      f32x4 s = {};
      __builtin_amdgcn_s_setprio(1);
      s = mfma32(*(const bf16x8*)&Ks[(mt * 2 + 0) * 512 + l * 8], qf0, s);
      s = mfma32(*(const bf16x8*)&Ks[(mt * 2 + 1) * 512 + l * 8], qf1, s);
      __builtin_amdgcn_s_setprio(0);
      f32x4 ev;
      unsigned mm = MASKED ? (mw[mt >> 1] >> ((mt & 1) * 16 + shb)) : 0u;
#pragma unroll
      for (int v = 0; v < 4; ++v) {
        float arg = s[v];
        if (MASKED) {
          int spread = ((int)(mm << (31 - v))) >> 31;  // all-ones if keep
          float bias = __uint_as_float((~(unsigned)spread) & 0xC3200000u);  // -160 if drop
          arg = s[v] + bias;
        }
        ev[v] = __builtin_amdgcn_exp2f(arg);
      }
      racc4 += ev;
      bf16x4v wb = __builtin_convertvector(ev, bf16x4v);
      s16x4 wpk = __builtin_bit_cast(s16x4, wb);
      __builtin_amdgcn_s_setprio(1);
#pragma unroll
      for (int p = 0; p < 2; ++p) {
        s16x8 vf = *(const s16x8*)&Vs[(mt * 2 + p) * 512 + l * 8];
        s16x4 lo = __builtin_shufflevector(vf, vf, 0, 1, 2, 3);
        s16x4 hi = __builtin_shufflevector(vf, vf, 4, 5, 6, 7);
        oacc[2 * p + 0] = mfma16(lo, wpk, oacc[2 * p + 0]);
        oacc[2 * p + 1] = mfma16(hi, wpk, oacc[2 * p + 1]);
      }
      __builtin_amdgcn_s_setprio(0);
    }
    __syncthreads();  // all waves done reading buf[cur]; next-tile loads also drained
    cur ^= 1;
  }
  float r = racc4[0] + racc4[1] + racc4[2] + racc4[3];
  r += __shfl_xor(r, 16);
  r += __shfl_xor(r, 32);
  float dinv = 1.0f / r;
  if (l < 16) db[(size_t)(z * HEADS + h) * SS + qt2 * 16 + li] = dinv;
  u16* ob = out01 + (size_t)z * SS * DIM;
#pragma unroll
  for (int dt = 0; dt < 4; ++dt) {
    f32x4 o = oacc[dt] * dinv;
    ushort4 us;
    us.x = f2b(o[0]); us.y = f2b(o[1]); us.z = f2b(o[2]); us.w = f2b(o[3]);
    *(ushort4*)&ob[((size_t)(qt2 * 16 + li)) * DIM + h * HD + dt * 16 + 4 * g] = us;
  }
}

__global__ __launch_bounds__(512, 8) void attn_pv(const u16* __restrict__ Qfrag,
                                                  const u16* __restrict__ Kfrag,
                                                  const u16* __restrict__ Vfrag,
                                                  const unsigned* __restrict__ mbits,
                                                  u16* __restrict__ out01,
                                                  float* __restrict__ db) {
  __shared__ u16 KV[2][8192];  // 32 KB double-buffered K+V tile
  // z-balanced XCD map: each XCD gets 8 (z,h) groups spanning all z (equal masked/unmasked)
  const int flat = blockIdx.x;                 // 1024 blocks
  const int xcd = flat & 7, i = flat >> 3;     // i in [0,128)
  const int k = i >> 4, qg = i & 15;
  const int zh = xcd + 8 * k;                  // [0,64)
  const int z = zh >> 4, h = zh & 15;
  const int w = threadIdx.x >> 6, l = threadIdx.x & 63;
  const int qt2 = qg * 8 + w;
  if (z < 2) attn_pv_body<1>(z, h, qt2, w, l, Qfrag, Kfrag, Vfrag, mbits, out01, db, &KV[0][0]);
  else       attn_pv_body<0>(z, h, qt2, w, l, Qfrag, Kfrag, Vfrag, mbits, out01, db, &KV[0][0]);
}

// ---------------- amean: head-mean map; z-balanced XCD map ----------------
template<int MASKED>
static __device__ __forceinline__ void amean_body(int z, int qt2, int lt, int l,
                                                  const u16* __restrict__ Qfrag,
                                                  const u16* __restrict__ Kfrag,
                                                  const unsigned* __restrict__ mbits,
                                                  const float* __restrict__ db,
                                                  float* __restrict__ aout) {
  const int g = l >> 4, li = l & 15;
  const int b = z & 1;
  const int qt = qt2 >> 1, n = qt2 & 1;

  unsigned mw[2];
  if (MASKED) {
    const unsigned* m0 = mbits + (size_t)(qt2 * 16 + li) * (LLL / 32) + lt * 2;
    mw[0] = m0[0]; mw[1] = m0[1];
  }
  const u16* kf_base = Kfrag + (size_t)(z * HEADS) * (32 * 8 * 512) + (size_t)lt * 4096 + l * 8;
  const u16* qf_base = Qfrag + ((((size_t)(b * HEADS) * 64 + qt) * 4 + n * 2)) * 512 + l * 8;
  const float* dbb = db + (size_t)(z * HEADS) * SS + qt2 * 16 + li;

  f32x4 asum[4] = {};
#pragma unroll 2
  for (int h = 0; h < HEADS; ++h) {
    float l2 = __log2f(dbb[(size_t)h * SS]);
    bf16x8 qf0 = *(const bf16x8*)&qf_base[(size_t)h * (64 * 4 * 512)];
    bf16x8 qf1 = *(const bf16x8*)&qf_base[(size_t)h * (64 * 4 * 512) + 512];
    const u16* kfh = kf_base + (size_t)h * (32 * 8 * 512);
#pragma unroll
    for (int mt = 0; mt < 4; ++mt) {
      f32x4 s = {};
      s = mfma32(*(const bf16x8*)&kfh[(mt * 2 + 0) * 512], qf0, s);
      s = mfma32(*(const bf16x8*)&kfh[(mt * 2 + 1) * 512], qf1, s);
      unsigned mm = MASKED ? (mw[mt >> 1] >> ((mt & 1) * 16 + 4 * g)) : 0u;
#pragma unroll
      for (int v = 0; v < 4; ++v) {
        float bias = l2;
        if (MASKED && !((mm >> v) & 1u)) bias = -160.0f;
        asum[mt][v] += __builtin_amdgcn_exp2f(s[v] + bias);
      }
    }
  }
  float* ab = aout + (size_t)z * SS * LLL;
#pragma unroll
  for (int mt = 0; mt < 4; ++mt) {
    f32x4 o = asum[mt] * 0.0625f;
    f32x4* dst = (f32x4*)&ab[(size_t)(qt2 * 16 + li) * LLL + lt * 64 + mt * 16 + 4 * g];
    __builtin_nontemporal_store(o, dst);
  }
}

__global__ __launch_bounds__(256, 8) void amean(const u16* __restrict__ Qfrag,
                                                const u16* __restrict__ Kfrag,
                                                const unsigned* __restrict__ mbits,
                                                const float* __restrict__ db,
                                                float* __restrict__ aout) {
  // z-balanced XCD map over (z,lt) groups
  const int flat = blockIdx.x;                 // 4096 blocks
  const int xcd = flat & 7, i = flat >> 3;     // i in [0,512)
  const int k = i >> 5, qg = i & 31;           // k in [0,16)
  const int zlt = xcd + 8 * k;                 // [0,128)
  const int z = zlt >> 5, lt = zlt & 31;
  const int w = threadIdx.x >> 6;
  const int qt2 = qg * 4 + w;
  if (z < 2) amean_body<1>(z, qt2, lt, threadIdx.x & 63, Qfrag, Kfrag, mbits, db, aout);
  else       amean_body<0>(z, qt2, lt, threadIdx.x & 63, Qfrag, Kfrag, mbits, db, aout);
}

// ---------------- gated merge ----------------
__global__ void merge_kernel(const u16* __restrict__ o01,
                             const float* __restrict__ gate,
                             u16* __restrict__ merged) {
  int i = blockIdx.x * blockDim.x + threadIdx.x;
  float gv = gate[0];
  float g = 1.0f / (1.0f + __builtin_amdgcn_exp2f(-gv * LOG2E));
  const size_t n = (size_t)BB * SS * DIM;
  ushort4 a = ((const ushort4*)o01)[i];
  ushort4 c = ((const ushort4*)(o01 + n))[i];
  ushort4 o;
  o.x = f2b(g * b2f(a.x) + (1.f - g) * b2f(c.x));
  o.y = f2b(g * b2f(a.y) + (1.f - g) * b2f(c.y));
  o.z = f2b(g * b2f(a.z) + (1.f - g) * b2f(c.z));
  o.w = f2b(g * b2f(a.w) + (1.f - g) * b2f(c.w));
  ((ushort4*)merged)[i] = o;
}

extern "C" void kernel_launch(void* const* d_in, const int* in_sizes, int n_in,
                              void* d_out, int out_size, void* d_ws, size_t ws_size,
                              hipStream_t stream) {
  const float* query = (const float*)d_in[0];
  const float* k0f   = (const float*)d_in[1];
  const float* v0f   = (const float*)d_in[2];
  const float* k1f   = (const float*)d_in[3];
  const float* v1f   = (const float*)d_in[4];
  const int*   mask  = (const int*)d_in[5];
  const float* Wqf   = (const float*)d_in[6];
  const float* bq    = (const float*)d_in[7];
  const float* Wof   = (const float*)d_in[8];
  const float* bo    = (const float*)d_in[9];
  const float* gate  = (const float*)d_in[10];
  float* out = (float*)d_out;

  const size_t nQ = (size_t)BB * SS * DIM;
  const size_t nW = (size_t)DIM * DIM;

  char* ws = (char*)d_ws;
  size_t off = 0;
  auto alloc = [&](size_t bytes) -> char* {
    char* p = ws + off;
    off += (bytes + 255) & ~(size_t)255;
    return p;
  };
  u16*      queryb  = (u16*)alloc(nQ * 2);             // reused as mergedb later
  u16*      wqb     = (u16*)alloc(nW * 2);
  u16*      wob     = (u16*)alloc(nW * 2);
  u16*      Qfrag   = (u16*)alloc(nQ * 2);             // [b][h][qt][c][lane][8]
  u16*      Kfrag   = (u16*)alloc((size_t)2 * nQ * 2); // [z][h][lt][c][lane][8] (prescaled)
  u16*      Vfrag   = (u16*)alloc((size_t)2 * nQ * 2);
  unsigned* mbits   = (unsigned*)alloc((size_t)SS * (LLL / 32) * 4);
  float*    db      = (float*)alloc((size_t)4 * HEADS * SS * 4);  // dinv per [z][h][q]
  u16*      out01   = (u16*)alloc((size_t)2 * nQ * 2);
  u16*      mergedb = queryb;  // queryb dead after q-proj gemm

  auto cvt = [&](const float* s, u16* d, size_t n) {
    int n4 = (int)(n / 4);
    cvt_f32_bf16<<<dim3((n4 + 255) / 256), dim3(256), 0, stream>>>(s, d, n4);
  };
  cvt(query, queryb, nQ);
  cvt(Wqf, wqb, nW);
  cvt(Wof, wob, nW);

  mask_pack<<<dim3(SS * (LLL / 32) / 256), dim3(256), 0, stream>>>(mask, mbits);
  pack_k<<<dim3(LLL / 64 / 4, HEADS, 4), dim3(256), 0, stream>>>(k0f, k1f, Kfrag);
  pack_v<<<dim3(LLL / 64, HEADS, 4), dim3(256), 0, stream>>>(v0f, v1f, Vfrag);

  // q projection straight into fragment layout (128x64 tiles)
  gemm_nt<2><<<dim3(DIM / 64, (BB * SS) / 128), dim3(256), 0, stream>>>(
      queryb, wqb, bq, (void*)Qfrag, BB * SS, DIM, DIM);

  // fused single-pass attention: double-buffered LDS staging, 128 q-rows per block
  attn_pv<<<dim3(1024), dim3(512), 0, stream>>>(Qfrag, Kfrag, Vfrag, mbits, out01, db);

  // head-mean attention maps straight into d_out
  amean<<<dim3(4096), dim3(256), 0, stream>>>(Qfrag, Kfrag, mbits, db, out + nQ);

  merge_kernel<<<dim3((int)(nQ / 4 / 256)), dim3(256), 0, stream>>>(out01, gate, mergedb);

  gemm_nt<1><<<dim3(DIM / 64, (BB * SS) / 128), dim3(256), 0, stream>>>(
      mergedb, wob, bo, (void*)out, BB * SS, DIM, DIM);
}

// Round 11
// 261.279 us; speedup vs baseline: 3.2861x; 1.0172x over previous
//
#include <hip/hip_runtime.h>

#define DIM   1024
#define HEADS 16
#define HD    64
#define BB    2
#define SS    2048
#define LLL   2048
#define LOG2E 1.4426950408889634f

typedef __bf16 bf16x8 __attribute__((ext_vector_type(8)));
typedef __bf16 bf16x4v __attribute__((ext_vector_type(4)));
typedef float  f32x4  __attribute__((ext_vector_type(4)));
typedef short  s16x4  __attribute__((ext_vector_type(4)));
typedef short  s16x8  __attribute__((ext_vector_type(8)));
typedef unsigned short u16;

static __device__ __forceinline__ u16 f2b(float x) {
  unsigned u = __float_as_uint(x);
  u += 0x7fffu + ((u >> 16) & 1u);
  return (u16)(u >> 16);
}
static __device__ __forceinline__ float b2f(u16 u) {
  return __uint_as_float(((unsigned)u) << 16);
}
static __device__ __forceinline__ f32x4 mfma32(bf16x8 a, bf16x8 b, f32x4 c) {
  return __builtin_amdgcn_mfma_f32_16x16x32_bf16(a, b, c, 0, 0, 0);
}
static __device__ __forceinline__ f32x4 mfma16(s16x4 a, s16x4 b, f32x4 c) {
#if __has_builtin(__builtin_amdgcn_mfma_f32_16x16x16bf16_1k)
  return __builtin_amdgcn_mfma_f32_16x16x16bf16_1k(a, b, c, 0, 0, 0);
#else
  asm volatile("v_mfma_f32_16x16x16_bf16 %0, %1, %2, %0" : "+v"(c) : "v"(a), "v"(b));
  return c;
#endif
}

// async global->LDS, 16B/lane. LDS base must be WAVE-UNIFORM (HW adds lane*16).
static __device__ __forceinline__ void gload_lds16(const void* g, void* lds_uniform_base) {
#if __has_builtin(__builtin_amdgcn_global_load_lds)
  __builtin_amdgcn_global_load_lds(
      (const __attribute__((address_space(1))) unsigned int*)g,
      (__attribute__((address_space(3))) unsigned int*)lds_uniform_base, 16, 0, 0);
#else
  const int l = threadIdx.x & 63;
  ((uint4*)lds_uniform_base)[l] = ((const uint4*)g)[0];
#endif
}

// ---------------- f32 -> bf16 convert ----------------
__global__ void cvt_f32_bf16(const float* __restrict__ src, u16* __restrict__ dst, int n4) {
  int i = blockIdx.x * blockDim.x + threadIdx.x;
  if (i >= n4) return;
  float4 f = ((const float4*)src)[i];
  ushort4 o;
  o.x = f2b(f.x); o.y = f2b(f.y); o.z = f2b(f.z); o.w = f2b(f.w);
  ((ushort4*)dst)[i] = o;
}

// ---------------- mask -> bitmask ----------------
__global__ void mask_pack(const int* __restrict__ mask, unsigned* __restrict__ mbits) {
  int i = blockIdx.x * blockDim.x + threadIdx.x;
  const int* src = mask + (size_t)i * 32;
  unsigned bm = 0;
#pragma unroll
  for (int j = 0; j < 8; ++j) {
    int4 m = ((const int4*)src)[j];
    bm |= (m.x != 0 ? 1u : 0u) << (j * 4 + 0);
    bm |= (m.y != 0 ? 1u : 0u) << (j * 4 + 1);
    bm |= (m.z != 0 ? 1u : 0u) << (j * 4 + 2);
    bm |= (m.w != 0 ? 1u : 0u) << (j * 4 + 3);
  }
  mbits[i] = bm;
}

// ---------------- K (f32) -> fragment-packed bf16 tiles, PRESCALED by 0.125*log2(e) ----------------
__global__ __launch_bounds__(256) void pack_k(const float* __restrict__ k0,
                                              const float* __restrict__ k1,
                                              u16* __restrict__ Kfrag) {
  const float SCK = 0.125f * LOG2E;
  const int w = threadIdx.x >> 6, l = threadIdx.x & 63, g = l >> 4, li = l & 15;
  const int lt = blockIdx.x * 4 + w, h = blockIdx.y, z = blockIdx.z;
  const int lay = z >> 1, b = z & 1;
  const float* src = (lay ? k1 : k0) + (size_t)b * LLL * DIM;
  u16* dst = Kfrag + ((((size_t)z * HEADS + h) * 32 + lt) * 8) * 512;
#pragma unroll
  for (int c = 0; c < 8; ++c) {
    int mt = c >> 1, kk = c & 1;
    const float* p = &src[(size_t)(lt * 64 + mt * 16 + li) * DIM + h * 64 + kk * 32 + g * 8];
    float4 f0 = *(const float4*)p;
    float4 f1 = *(const float4*)(p + 4);
    u16 u[8] = {f2b(f0.x * SCK), f2b(f0.y * SCK), f2b(f0.z * SCK), f2b(f0.w * SCK),
                f2b(f1.x * SCK), f2b(f1.y * SCK), f2b(f1.z * SCK), f2b(f1.w * SCK)};
    *(uint4*)&dst[c * 512 + l * 8] = *(uint4*)u;
  }
}

// ---------------- V (f32) -> fragment-packed bf16 tiles (transposed) ----------------
__global__ __launch_bounds__(256) void pack_v(const float* __restrict__ v0,
                                              const float* __restrict__ v1,
                                              u16* __restrict__ Vfrag) {
  __shared__ u16 T[64][72];  // T[l][d]
  const int lt = blockIdx.x, h = blockIdx.y, z = blockIdx.z;
  const int lay = z >> 1, b = z & 1;
  const float* v = (lay ? v1 : v0) + (size_t)b * LLL * DIM;
  const int t = threadIdx.x;
  {
    int r = t >> 2, c16 = (t & 3) * 16;
    const float* src = &v[(size_t)(lt * 64 + r) * DIM + h * 64 + c16];
#pragma unroll
    for (int i = 0; i < 4; ++i) {
      float4 f = *(const float4*)&src[i * 4];
      T[r][c16 + i * 4 + 0] = f2b(f.x);
      T[r][c16 + i * 4 + 1] = f2b(f.y);
      T[r][c16 + i * 4 + 2] = f2b(f.z);
      T[r][c16 + i * 4 + 3] = f2b(f.w);
    }
  }
  __syncthreads();
  u16* dst = Vfrag + ((((size_t)z * HEADS + h) * 32 + lt) * 8) * 512;
  {
    int lane = t & 63, g = lane >> 4, li = lane & 15;
#pragma unroll
    for (int cc = 0; cc < 2; ++cc) {
      int c = (t >> 6) + cc * 4;
      int mt = c >> 1, p = c & 1;
      u16 u[8];
#pragma unroll
      for (int j = 0; j < 4; ++j) u[j] = T[mt * 16 + 4 * g + j][p * 32 + li];
#pragma unroll
      for (int j = 0; j < 4; ++j) u[4 + j] = T[mt * 16 + 4 * g + j][p * 32 + 16 + li];
      *(uint4*)&dst[c * 512 + lane * 8] = *(uint4*)u;
    }
  }
}

// ---------------- bf16 NT GEMM, 128x64 tile, global_load_lds staging ----------------
// LDS linear dest; XOR swizzle pre-applied to the GLOBAL source offset (rule #21);
// swizzled ds-read side unchanged.
template<int MODE>
__global__ __launch_bounds__(256) void gemm_nt(const u16* __restrict__ A,
                                               const u16* __restrict__ Bt,
                                               const float* __restrict__ bias,
                                               void* __restrict__ Cv,
                                               int M, int N, int K) {
  __shared__ u16 As[128][64];
  __shared__ u16 Bs[64][64];
  const int t = threadIdx.x;
  const int w = t >> 6, l = t & 63, g = l >> 4, li = l & 15;
  const int m0 = blockIdx.y * 128, n0 = blockIdx.x * 64;
  const int slotL = w * 64 + l;
  const int rA = slotL >> 3, cA = ((slotL & 7) * 8) ^ ((rA & 7) * 8);
  f32x4 acc[2][4] = {};
  for (int kt = 0; kt < K; kt += 64) {
#pragma unroll
    for (int s = 0; s < 4; ++s) {
      int r = rA + s * 32;
      gload_lds16(&A[(size_t)(m0 + r) * K + kt + cA], &As[0][0] + (s * 256 + w * 64) * 8);
    }
#pragma unroll
    for (int s = 0; s < 2; ++s) {
      int r = rA + s * 32;
      gload_lds16(&Bt[(size_t)(n0 + r) * K + kt + cA], &Bs[0][0] + (s * 256 + w * 64) * 8);
    }
    __syncthreads();
#pragma unroll
    for (int kk = 0; kk < 2; ++kk) {
      bf16x8 a[2], bfr[4];
#pragma unroll
      for (int mi = 0; mi < 2; ++mi) {
        int ra = w * 32 + mi * 16 + li;
        a[mi] = *(const bf16x8*)&As[ra][(kk * 32 + g * 8) ^ ((ra & 7) << 3)];
      }
#pragma unroll
      for (int ni = 0; ni < 4; ++ni) {
        int rb = ni * 16 + li;
        bfr[ni] = *(const bf16x8*)&Bs[rb][(kk * 32 + g * 8) ^ ((rb & 7) << 3)];
      }
#pragma unroll
      for (int mi = 0; mi < 2; ++mi)
#pragma unroll
        for (int ni = 0; ni < 4; ++ni)
          acc[mi][ni] = mfma32(a[mi], bfr[ni], acc[mi][ni]);
    }
    __syncthreads();
  }
#pragma unroll
  for (int mi = 0; mi < 2; ++mi)
#pragma unroll
    for (int ni = 0; ni < 4; ++ni)
#pragma unroll
      for (int v = 0; v < 4; ++v) {
        int rr = m0 + w * 32 + mi * 16 + g * 4 + v;
        int cc = n0 + ni * 16 + li;
        float val = acc[mi][ni][v] + bias[cc];
        if (MODE == 1) {
          ((float*)Cv)[(size_t)rr * N + cc] = val;
        } else {
          // Qfrag[b][h][qt][c=n*2+kk][lane(gp,liq)][8]
          int b = rr >> 11, q = rr & 2047;
          int qt = q >> 5, n = (q >> 4) & 1, liq = q & 15;
          int h = (cc >> 6) & 15, kk2 = (cc >> 5) & 1, gp = (cc >> 3) & 3, j = cc & 7;
          size_t base = ((((size_t)b * HEADS + h) * 64 + qt) * 4 + n * 2 + kk2) * 512;
          ((u16*)Cv)[base + (size_t)(gp * 16 + liq) * 8 + j] = f2b(val);
        }
      }
}

// ---------------- attn_pv: VALU-diet body; denominator via ones-row MFMA ----------------
// db layout: [z*HEADS+h][q] = dinv
template<int MASKED>
static __device__ __forceinline__ void attn_pv_body(int z, int h, int qt2, int w, int l,
                                                    const u16* __restrict__ Qfrag,
                                                    const u16* __restrict__ Kfrag,
                                                    const u16* __restrict__ Vfrag,
                                                    const unsigned* __restrict__ mbits,
                                                    u16* __restrict__ out01,
                                                    float* __restrict__ db,
                                                    u16* __restrict__ KV) {
  const int g = l >> 4, li = l & 15;
  const int b = z & 1;
  const int qt = qt2 >> 1, n = qt2 & 1;
  const u16* kfh = Kfrag + (size_t)(z * HEADS + h) * (32 * 8 * 512);
  const u16* vfh = Vfrag + (size_t)(z * HEADS + h) * (32 * 8 * 512);
  const u16* qfh = Qfrag + ((((size_t)(b * HEADS + h) * 64 + qt) * 4 + n * 2)) * 512;

  bf16x8 qf0 = *(const bf16x8*)&qfh[0 * 512 + l * 8];
  bf16x8 qf1 = *(const bf16x8*)&qfh[1 * 512 + l * 8];

  const unsigned* mrow = MASKED ? mbits + (size_t)(qt2 * 16 + li) * (LLL / 32) : nullptr;
  const int shb = 4 * g;
  const s16x4 ones = {(short)0x3F80, (short)0x3F80, (short)0x3F80, (short)0x3F80};

  // stage: wave w stages fragments f = 2w, 2w+1 (f<8: K, else V) of tile lt into buffer buf
  auto stage = [&](int buf, int lt) {
    const u16* kfl = kfh + (size_t)lt * 4096;
    const u16* vfl = vfh + (size_t)lt * 4096;
#pragma unroll
    for (int i2 = 0; i2 < 2; ++i2) {
      int f = w * 2 + i2;
      const u16* gsrc = (f < 8 ? kfl + f * 512 : vfl + (f - 8) * 512) + l * 8;
      gload_lds16(gsrc, (char*)KV + buf * 16384 + f * 1024);
    }
  };

  f32x4 dacc = {};     // denominator, accumulated on the MATRIX pipe (A = ones)
  f32x4 oacc[4] = {};  // [dt], unnormalized

  stage(0, 0);
  __syncthreads();
  int cur = 0;
  for (int lt = 0; lt < 32; ++lt) {
    if (lt + 1 < 32) stage(cur ^ 1, lt + 1);  // prefetch flies under compute
    unsigned mw[2];
    if (MASKED) { mw[0] = mrow[lt * 2]; mw[1] = mrow[lt * 2 + 1]; }
    const u16* Ks = KV + cur * 8192;
    const u16* Vs = Ks + 4096;
#pragma unroll
    for (int mt = 0; mt < 4; ++mt) {
      f32x4 s = {};
      __builtin_amdgcn_s_setprio(1);
      s = mfma32(*(const bf16x8*)&Ks[(mt * 2 + 0) * 512 + l * 8], qf0, s);
      s = mfma32(*(const bf16x8*)&Ks[(mt * 2 + 1) * 512 + l * 8], qf1, s);
      __builtin_amdgcn_s_setprio(0);
      f32x4 ev;
      unsigned mm = MASKED ? (mw[mt >> 1] >> ((mt & 1) * 16 + shb)) : 0u;
#pragma unroll
      for (int v = 0; v < 4; ++v) {
        float e = __builtin_amdgcn_exp2f(s[v]);       // K prescaled: zero prep
        if (MASKED) {
          int spread = ((int)(mm << (31 - v))) >> 31; // all-ones if keep
          e = __uint_as_float(__float_as_uint(e) & (unsigned)spread);
        }
        ev[v] = e;
      }
      bf16x4v wb = __builtin_convertvector(ev, bf16x4v);
      s16x4 wpk = __builtin_bit_cast(s16x4, wb);
      __builtin_amdgcn_s_setprio(1);
      dacc = mfma16(ones, wpk, dacc);                 // row-sum: denominator, free VALU
#pragma unroll
      for (int p = 0; p < 2; ++p) {
        s16x8 vf = *(const s16x8*)&Vs[(mt * 2 + p) * 512 + l * 8];
        s16x4 lo = __builtin_shufflevector(vf, vf, 0, 1, 2, 3);
        s16x4 hi = __builtin_shufflevector(vf, vf, 4, 5, 6, 7);
        oacc[2 * p + 0] = mfma16(lo, wpk, oacc[2 * p + 0]);
        oacc[2 * p + 1] = mfma16(hi, wpk, oacc[2 * p + 1]);
      }
      __builtin_amdgcn_s_setprio(0);
    }
    __syncthreads();  // all waves done reading buf[cur]; next-tile loads also drained
    cur ^= 1;
  }
  // dacc[v] (any v) = full denominator for q = li, in every lane — no shuffles needed
  float dinv = 1.0f / dacc[0];
  if (l < 16) db[(size_t)(z * HEADS + h) * SS + qt2 * 16 + li] = dinv;
  u16* ob = out01 + (size_t)z * SS * DIM;
#pragma unroll
  for (int dt = 0; dt < 4; ++dt) {
    f32x4 o = oacc[dt] * dinv;
    ushort4 us;
    us.x = f2b(o[0]); us.y = f2b(o[1]); us.z = f2b(o[2]); us.w = f2b(o[3]);
    *(ushort4*)&ob[((size_t)(qt2 * 16 + li)) * DIM + h * HD + dt * 16 + 4 * g] = us;
  }
}

__global__ __launch_bounds__(512, 8) void attn_pv(const u16* __restrict__ Qfrag,
                                                  const u16* __restrict__ Kfrag,
                                                  const u16* __restrict__ Vfrag,
                                                  const unsigned* __restrict__ mbits,
                                                  u16* __restrict__ out01,
                                                  float* __restrict__ db) {
  __shared__ u16 KV[2][8192];  // 32 KB double-buffered K+V tile
  // z-balanced XCD map: each XCD gets 8 (z,h) groups spanning all z (equal masked/unmasked)
  const int flat = blockIdx.x;                 // 1024 blocks
  const int xcd = flat & 7, i = flat >> 3;     // i in [0,128)
  const int k = i >> 4, qg = i & 15;
  const int zh = xcd + 8 * k;                  // [0,64)
  const int z = zh >> 4, h = zh & 15;
  const int w = threadIdx.x >> 6, l = threadIdx.x & 63;
  const int qt2 = qg * 8 + w;
  if (z < 2) attn_pv_body<1>(z, h, qt2, w, l, Qfrag, Kfrag, Vfrag, mbits, out01, db, &KV[0][0]);
  else       attn_pv_body<0>(z, h, qt2, w, l, Qfrag, Kfrag, Vfrag, mbits, out01, db, &KV[0][0]);
}

// ---------------- amean: head-mean map; z-balanced XCD map ----------------
template<int MASKED>
static __device__ __forceinline__ void amean_body(int z, int qt2, int lt, int l,
                                                  const u16* __restrict__ Qfrag,
                                                  const u16* __restrict__ Kfrag,
                                                  const unsigned* __restrict__ mbits,
                                                  const float* __restrict__ db,
                                                  float* __restrict__ aout) {
  const int g = l >> 4, li = l & 15;
  const int b = z & 1;
  const int qt = qt2 >> 1, n = qt2 & 1;

  unsigned mw[2];
  if (MASKED) {
    const unsigned* m0 = mbits + (size_t)(qt2 * 16 + li) * (LLL / 32) + lt * 2;
    mw[0] = m0[0]; mw[1] = m0[1];
  }
  const u16* kf_base = Kfrag + (size_t)(z * HEADS) * (32 * 8 * 512) + (size_t)lt * 4096 + l * 8;
  const u16* qf_base = Qfrag + ((((size_t)(b * HEADS) * 64 + qt) * 4 + n * 2)) * 512 + l * 8;
  const float* dbb = db + (size_t)(z * HEADS) * SS + qt2 * 16 + li;

  f32x4 asum[4] = {};
#pragma unroll 2
  for (int h = 0; h < HEADS; ++h) {
    float l2 = __log2f(dbb[(size_t)h * SS]);
    bf16x8 qf0 = *(const bf16x8*)&qf_base[(size_t)h * (64 * 4 * 512)];
    bf16x8 qf1 = *(const bf16x8*)&qf_base[(size_t)h * (64 * 4 * 512) + 512];
    const u16* kfh = kf_base + (size_t)h * (32 * 8 * 512);
#pragma unroll
    for (int mt = 0; mt < 4; ++mt) {
      f32x4 s = {};
      s = mfma32(*(const bf16x8*)&kfh[(mt * 2 + 0) * 512], qf0, s);
      s = mfma32(*(const bf16x8*)&kfh[(mt * 2 + 1) * 512], qf1, s);
      unsigned mm = MASKED ? (mw[mt >> 1] >> ((mt & 1) * 16 + 4 * g)) : 0u;
#pragma unroll
      for (int v = 0; v < 4; ++v) {
        float bias = l2;
        if (MASKED && !((mm >> v) & 1u)) bias = -160.0f;
        asum[mt][v] += __builtin_amdgcn_exp2f(s[v] + bias);
      }
    }
  }
  float* ab = aout + (size_t)z * SS * LLL;
#pragma unroll
  for (int mt = 0; mt < 4; ++mt) {
    f32x4 o = asum[mt] * 0.0625f;
    f32x4* dst = (f32x4*)&ab[(size_t)(qt2 * 16 + li) * LLL + lt * 64 + mt * 16 + 4 * g];
    __builtin_nontemporal_store(o, dst);
  }
}

__global__ __launch_bounds__(256, 8) void amean(const u16* __restrict__ Qfrag,
                                                const u16* __restrict__ Kfrag,
                                                const unsigned* __restrict__ mbits,
                                                const float* __restrict__ db,
                                                float* __restrict__ aout) {
  // z-balanced XCD map over (z,lt) groups
  const int flat = blockIdx.x;                 // 4096 blocks
  const int xcd = flat & 7, i = flat >> 3;     // i in [0,512)
  const int k = i >> 5, qg = i & 31;           // k in [0,16)
  const int zlt = xcd + 8 * k;                 // [0,128)
  const int z = zlt >> 5, lt = zlt & 31;
  const int w = threadIdx.x >> 6;
  const int qt2 = qg * 4 + w;
  if (z < 2) amean_body<1>(z, qt2, lt, threadIdx.x & 63, Qfrag, Kfrag, mbits, db, aout);
  else       amean_body<0>(z, qt2, lt, threadIdx.x & 63, Qfrag, Kfrag, mbits, db, aout);
}

// ---------------- gated merge ----------------
__global__ void merge_kernel(const u16* __restrict__ o01,
                             const float* __restrict__ gate,
                             u16* __restrict__ merged) {
  int i = blockIdx.x * blockDim.x + threadIdx.x;
  float gv = gate[0];
  float g = 1.0f / (1.0f + __builtin_amdgcn_exp2f(-gv * LOG2E));
  const size_t n = (size_t)BB * SS * DIM;
  ushort4 a = ((const ushort4*)o01)[i];
  ushort4 c = ((const ushort4*)(o01 + n))[i];
  ushort4 o;
  o.x = f2b(g * b2f(a.x) + (1.f - g) * b2f(c.x));
  o.y = f2b(g * b2f(a.y) + (1.f - g) * b2f(c.y));
  o.z = f2b(g * b2f(a.z) + (1.f - g) * b2f(c.z));
  o.w = f2b(g * b2f(a.w) + (1.f - g) * b2f(c.w));
  ((ushort4*)merged)[i] = o;
}

extern "C" void kernel_launch(void* const* d_in, const int* in_sizes, int n_in,
                              void* d_out, int out_size, void* d_ws, size_t ws_size,
                              hipStream_t stream) {
  const float* query = (const float*)d_in[0];
  const float* k0f   = (const float*)d_in[1];
  const float* v0f   = (const float*)d_in[2];
  const float* k1f   = (const float*)d_in[3];
  const float* v1f   = (const float*)d_in[4];
  const int*   mask  = (const int*)d_in[5];
  const float* Wqf   = (const float*)d_in[6];
  const float* bq    = (const float*)d_in[7];
  const float* Wof   = (const float*)d_in[8];
  const float* bo    = (const float*)d_in[9];
  const float* gate  = (const float*)d_in[10];
  float* out = (float*)d_out;

  const size_t nQ = (size_t)BB * SS * DIM;
  const size_t nW = (size_t)DIM * DIM;

  char* ws = (char*)d_ws;
  size_t off = 0;
  auto alloc = [&](size_t bytes) -> char* {
    char* p = ws + off;
    off += (bytes + 255) & ~(size_t)255;
    return p;
  };
  u16*      queryb  = (u16*)alloc(nQ * 2);             // reused as mergedb later
  u16*      wqb     = (u16*)alloc(nW * 2);
  u16*      wob     = (u16*)alloc(nW * 2);
  u16*      Qfrag   = (u16*)alloc(nQ * 2);             // [b][h][qt][c][lane][8]
  u16*      Kfrag   = (u16*)alloc((size_t)2 * nQ * 2); // [z][h][lt][c][lane][8] (prescaled)
  u16*      Vfrag   = (u16*)alloc((size_t)2 * nQ * 2);
  unsigned* mbits   = (unsigned*)alloc((size_t)SS * (LLL / 32) * 4);
  float*    db      = (float*)alloc((size_t)4 * HEADS * SS * 4);  // dinv per [z][h][q]
  u16*      out01   = (u16*)alloc((size_t)2 * nQ * 2);
  u16*      mergedb = queryb;  // queryb dead after q-proj gemm

  auto cvt = [&](const float* s, u16* d, size_t n) {
    int n4 = (int)(n / 4);
    cvt_f32_bf16<<<dim3((n4 + 255) / 256), dim3(256), 0, stream>>>(s, d, n4);
  };
  cvt(query, queryb, nQ);
  cvt(Wqf, wqb, nW);
  cvt(Wof, wob, nW);

  mask_pack<<<dim3(SS * (LLL / 32) / 256), dim3(256), 0, stream>>>(mask, mbits);
  pack_k<<<dim3(LLL / 64 / 4, HEADS, 4), dim3(256), 0, stream>>>(k0f, k1f, Kfrag);
  pack_v<<<dim3(LLL / 64, HEADS, 4), dim3(256), 0, stream>>>(v0f, v1f, Vfrag);

  // q projection straight into fragment layout (128x64 tiles)
  gemm_nt<2><<<dim3(DIM / 64, (BB * SS) / 128), dim3(256), 0, stream>>>(
      queryb, wqb, bq, (void*)Qfrag, BB * SS, DIM, DIM);

  // fused single-pass attention: double-buffered LDS staging, 128 q-rows per block
  attn_pv<<<dim3(1024), dim3(512), 0, stream>>>(Qfrag, Kfrag, Vfrag, mbits, out01, db);

  // head-mean attention maps straight into d_out
  amean<<<dim3(4096), dim3(256), 0, stream>>>(Qfrag, Kfrag, mbits, db, out + nQ);

  merge_kernel<<<dim3((int)(nQ / 4 / 256)), dim3(256), 0, stream>>>(out01, gate, mergedb);

  gemm_nt<1><<<dim3(DIM / 64, (BB * SS) / 128), dim3(256), 0, stream>>>(
      mergedb, wob, bo, (void*)out, BB * SS, DIM, DIM);
}

// Round 12
// 235.656 us; speedup vs baseline: 3.6434x; 1.1087x over previous
//
#include <hip/hip_runtime.h>

#define DIM   1024
#define HEADS 16
#define HD    64
#define BB    2
#define SS    2048
#define LLL   2048
#define LOG2E 1.4426950408889634f

typedef __bf16 bf16x8 __attribute__((ext_vector_type(8)));
typedef __bf16 bf16x4v __attribute__((ext_vector_type(4)));
typedef float  f32x4  __attribute__((ext_vector_type(4)));
typedef short  s16x4  __attribute__((ext_vector_type(4)));
typedef short  s16x8  __attribute__((ext_vector_type(8)));
typedef unsigned short u16;

static __device__ __forceinline__ u16 f2b(float x) {
  unsigned u = __float_as_uint(x);
  u += 0x7fffu + ((u >> 16) & 1u);
  return (u16)(u >> 16);
}
static __device__ __forceinline__ float b2f(u16 u) {
  return __uint_as_float(((unsigned)u) << 16);
}
static __device__ __forceinline__ f32x4 mfma32(bf16x8 a, bf16x8 b, f32x4 c) {
  return __builtin_amdgcn_mfma_f32_16x16x32_bf16(a, b, c, 0, 0, 0);
}
static __device__ __forceinline__ f32x4 mfma16(s16x4 a, s16x4 b, f32x4 c) {
#if __has_builtin(__builtin_amdgcn_mfma_f32_16x16x16bf16_1k)
  return __builtin_amdgcn_mfma_f32_16x16x16bf16_1k(a, b, c, 0, 0, 0);
#else
  asm volatile("v_mfma_f32_16x16x16_bf16 %0, %1, %2, %0" : "+v"(c) : "v"(a), "v"(b));
  return c;
#endif
}

// async global->LDS, 16B/lane. LDS base must be WAVE-UNIFORM (HW adds lane*16).
static __device__ __forceinline__ void gload_lds16(const void* g, void* lds_uniform_base) {
#if __has_builtin(__builtin_amdgcn_global_load_lds)
  __builtin_amdgcn_global_load_lds(
      (const __attribute__((address_space(1))) unsigned int*)g,
      (__attribute__((address_space(3))) unsigned int*)lds_uniform_base, 16, 0, 0);
#else
  const int l = threadIdx.x & 63;
  ((uint4*)lds_uniform_base)[l] = ((const uint4*)g)[0];
#endif
}

// ---------------- f32 -> bf16 convert ----------------
__global__ void cvt_f32_bf16(const float* __restrict__ src, u16* __restrict__ dst, int n4) {
  int i = blockIdx.x * blockDim.x + threadIdx.x;
  if (i >= n4) return;
  float4 f = ((const float4*)src)[i];
  ushort4 o;
  o.x = f2b(f.x); o.y = f2b(f.y); o.z = f2b(f.z); o.w = f2b(f.w);
  ((ushort4*)dst)[i] = o;
}

// ---------------- mask -> bitmask ----------------
__global__ void mask_pack(const int* __restrict__ mask, unsigned* __restrict__ mbits) {
  int i = blockIdx.x * blockDim.x + threadIdx.x;
  const int* src = mask + (size_t)i * 32;
  unsigned bm = 0;
#pragma unroll
  for (int j = 0; j < 8; ++j) {
    int4 m = ((const int4*)src)[j];
    bm |= (m.x != 0 ? 1u : 0u) << (j * 4 + 0);
    bm |= (m.y != 0 ? 1u : 0u) << (j * 4 + 1);
    bm |= (m.z != 0 ? 1u : 0u) << (j * 4 + 2);
    bm |= (m.w != 0 ? 1u : 0u) << (j * 4 + 3);
  }
  mbits[i] = bm;
}

// ---------------- K (f32) -> fragment-packed bf16 tiles, PRESCALED by 0.125*log2(e) ----------------
__global__ __launch_bounds__(256) void pack_k(const float* __restrict__ k0,
                                              const float* __restrict__ k1,
                                              u16* __restrict__ Kfrag) {
  const float SCK = 0.125f * LOG2E;
  const int w = threadIdx.x >> 6, l = threadIdx.x & 63, g = l >> 4, li = l & 15;
  const int lt = blockIdx.x * 4 + w, h = blockIdx.y, z = blockIdx.z;
  const int lay = z >> 1, b = z & 1;
  const float* src = (lay ? k1 : k0) + (size_t)b * LLL * DIM;
  u16* dst = Kfrag + ((((size_t)z * HEADS + h) * 32 + lt) * 8) * 512;
#pragma unroll
  for (int c = 0; c < 8; ++c) {
    int mt = c >> 1, kk = c & 1;
    const float* p = &src[(size_t)(lt * 64 + mt * 16 + li) * DIM + h * 64 + kk * 32 + g * 8];
    float4 f0 = *(const float4*)p;
    float4 f1 = *(const float4*)(p + 4);
    u16 u[8] = {f2b(f0.x * SCK), f2b(f0.y * SCK), f2b(f0.z * SCK), f2b(f0.w * SCK),
                f2b(f1.x * SCK), f2b(f1.y * SCK), f2b(f1.z * SCK), f2b(f1.w * SCK)};
    *(uint4*)&dst[c * 512 + l * 8] = *(uint4*)u;
  }
}

// ---------------- V (f32) -> fragment-packed bf16 tiles (transposed) ----------------
__global__ __launch_bounds__(256) void pack_v(const float* __restrict__ v0,
                                              const float* __restrict__ v1,
                                              u16* __restrict__ Vfrag) {
  __shared__ u16 T[64][72];  // T[l][d]
  const int lt = blockIdx.x, h = blockIdx.y, z = blockIdx.z;
  const int lay = z >> 1, b = z & 1;
  const float* v = (lay ? v1 : v0) + (size_t)b * LLL * DIM;
  const int t = threadIdx.x;
  {
    int r = t >> 2, c16 = (t & 3) * 16;
    const float* src = &v[(size_t)(lt * 64 + r) * DIM + h * 64 + c16];
#pragma unroll
    for (int i = 0; i < 4; ++i) {
      float4 f = *(const float4*)&src[i * 4];
      T[r][c16 + i * 4 + 0] = f2b(f.x);
      T[r][c16 + i * 4 + 1] = f2b(f.y);
      T[r][c16 + i * 4 + 2] = f2b(f.z);
      T[r][c16 + i * 4 + 3] = f2b(f.w);
    }
  }
  __syncthreads();
  u16* dst = Vfrag + ((((size_t)z * HEADS + h) * 32 + lt) * 8) * 512;
  {
    int lane = t & 63, g = lane >> 4, li = lane & 15;
#pragma unroll
    for (int cc = 0; cc < 2; ++cc) {
      int c = (t >> 6) + cc * 4;
      int mt = c >> 1, p = c & 1;
      u16 u[8];
#pragma unroll
      for (int j = 0; j < 4; ++j) u[j] = T[mt * 16 + 4 * g + j][p * 32 + li];
#pragma unroll
      for (int j = 0; j < 4; ++j) u[4 + j] = T[mt * 16 + 4 * g + j][p * 32 + 16 + li];
      *(uint4*)&dst[c * 512 + lane * 8] = *(uint4*)u;
    }
  }
}

// ---------------- bf16 NT GEMM, 128x64 tile, global_load_lds staging ----------------
template<int MODE>
__global__ __launch_bounds__(256) void gemm_nt(const u16* __restrict__ A,
                                               const u16* __restrict__ Bt,
                                               const float* __restrict__ bias,
                                               void* __restrict__ Cv,
                                               int M, int N, int K) {
  __shared__ u16 As[128][64];
  __shared__ u16 Bs[64][64];
  const int t = threadIdx.x;
  const int w = t >> 6, l = t & 63, g = l >> 4, li = l & 15;
  const int m0 = blockIdx.y * 128, n0 = blockIdx.x * 64;
  const int slotL = w * 64 + l;
  const int rA = slotL >> 3, cA = ((slotL & 7) * 8) ^ ((rA & 7) * 8);
  f32x4 acc[2][4] = {};
  for (int kt = 0; kt < K; kt += 64) {
#pragma unroll
    for (int s = 0; s < 4; ++s) {
      int r = rA + s * 32;
      gload_lds16(&A[(size_t)(m0 + r) * K + kt + cA], &As[0][0] + (s * 256 + w * 64) * 8);
    }
#pragma unroll
    for (int s = 0; s < 2; ++s) {
      int r = rA + s * 32;
      gload_lds16(&Bt[(size_t)(n0 + r) * K + kt + cA], &Bs[0][0] + (s * 256 + w * 64) * 8);
    }
    __syncthreads();
#pragma unroll
    for (int kk = 0; kk < 2; ++kk) {
      bf16x8 a[2], bfr[4];
#pragma unroll
      for (int mi = 0; mi < 2; ++mi) {
        int ra = w * 32 + mi * 16 + li;
        a[mi] = *(const bf16x8*)&As[ra][(kk * 32 + g * 8) ^ ((ra & 7) << 3)];
      }
#pragma unroll
      for (int ni = 0; ni < 4; ++ni) {
        int rb = ni * 16 + li;
        bfr[ni] = *(const bf16x8*)&Bs[rb][(kk * 32 + g * 8) ^ ((rb & 7) << 3)];
      }
#pragma unroll
      for (int mi = 0; mi < 2; ++mi)
#pragma unroll
        for (int ni = 0; ni < 4; ++ni)
          acc[mi][ni] = mfma32(a[mi], bfr[ni], acc[mi][ni]);
    }
    __syncthreads();
  }
#pragma unroll
  for (int mi = 0; mi < 2; ++mi)
#pragma unroll
    for (int ni = 0; ni < 4; ++ni)
#pragma unroll
      for (int v = 0; v < 4; ++v) {
        int rr = m0 + w * 32 + mi * 16 + g * 4 + v;
        int cc = n0 + ni * 16 + li;
        float val = acc[mi][ni][v] + bias[cc];
        if (MODE == 1) {
          ((float*)Cv)[(size_t)rr * N + cc] = val;
        } else {
          // Qfrag[b][h][qt][c=n*2+kk][lane(gp,liq)][8]
          int b = rr >> 11, q = rr & 2047;
          int qt = q >> 5, n = (q >> 4) & 1, liq = q & 15;
          int h = (cc >> 6) & 15, kk2 = (cc >> 5) & 1, gp = (cc >> 3) & 3, j = cc & 7;
          size_t base = ((((size_t)b * HEADS + h) * 64 + qt) * 4 + n * 2 + kk2) * 512;
          ((u16*)Cv)[base + (size_t)(gp * 16 + liq) * 8 + j] = f2b(val);
        }
      }
}

// ---------------- attn_pv: VALU-diet body; denominator via ones-row MFMA ----------------
// db layout: [z*HEADS+h][q] = -log2(denominator)  (consumed by amean as exp2 bias)
template<int MASKED>
static __device__ __forceinline__ void attn_pv_body(int z, int h, int qt2, int w, int l,
                                                    const u16* __restrict__ Qfrag,
                                                    const u16* __restrict__ Kfrag,
                                                    const u16* __restrict__ Vfrag,
                                                    const unsigned* __restrict__ mbits,
                                                    u16* __restrict__ out01,
                                                    float* __restrict__ db,
                                                    u16* __restrict__ KV) {
  const int g = l >> 4, li = l & 15;
  const int b = z & 1;
  const int qt = qt2 >> 1, n = qt2 & 1;
  const u16* kfh = Kfrag + (size_t)(z * HEADS + h) * (32 * 8 * 512);
  const u16* vfh = Vfrag + (size_t)(z * HEADS + h) * (32 * 8 * 512);
  const u16* qfh = Qfrag + ((((size_t)(b * HEADS + h) * 64 + qt) * 4 + n * 2)) * 512;

  bf16x8 qf0 = *(const bf16x8*)&qfh[0 * 512 + l * 8];
  bf16x8 qf1 = *(const bf16x8*)&qfh[1 * 512 + l * 8];

  const unsigned* mrow = MASKED ? mbits + (size_t)(qt2 * 16 + li) * (LLL / 32) : nullptr;
  const int shb = 4 * g;
  const s16x4 ones = {(short)0x3F80, (short)0x3F80, (short)0x3F80, (short)0x3F80};

  auto stage = [&](int buf, int lt) {
    const u16* kfl = kfh + (size_t)lt * 4096;
    const u16* vfl = vfh + (size_t)lt * 4096;
#pragma unroll
    for (int i2 = 0; i2 < 2; ++i2) {
      int f = w * 2 + i2;
      const u16* gsrc = (f < 8 ? kfl + f * 512 : vfl + (f - 8) * 512) + l * 8;
      gload_lds16(gsrc, (char*)KV + buf * 16384 + f * 1024);
    }
  };

  f32x4 dacc = {};     // denominator, accumulated on the MATRIX pipe (A = ones)
  f32x4 oacc[4] = {};  // [dt], unnormalized

  stage(0, 0);
  __syncthreads();
  int cur = 0;
  for (int lt = 0; lt < 32; ++lt) {
    if (lt + 1 < 32) stage(cur ^ 1, lt + 1);  // prefetch flies under compute
    unsigned mw[2];
    if (MASKED) { mw[0] = mrow[lt * 2]; mw[1] = mrow[lt * 2 + 1]; }
    const u16* Ks = KV + cur * 8192;
    const u16* Vs = Ks + 4096;
#pragma unroll
    for (int mt = 0; mt < 4; ++mt) {
      f32x4 s = {};
      __builtin_amdgcn_s_setprio(1);
      s = mfma32(*(const bf16x8*)&Ks[(mt * 2 + 0) * 512 + l * 8], qf0, s);
      s = mfma32(*(const bf16x8*)&Ks[(mt * 2 + 1) * 512 + l * 8], qf1, s);
      __builtin_amdgcn_s_setprio(0);
      f32x4 ev;
      unsigned mm = MASKED ? (mw[mt >> 1] >> ((mt & 1) * 16 + shb)) : 0u;
#pragma unroll
      for (int v = 0; v < 4; ++v) {
        float e = __builtin_amdgcn_exp2f(s[v]);       // K prescaled: zero prep
        if (MASKED) {
          int spread = ((int)(mm << (31 - v))) >> 31; // all-ones if keep
          e = __uint_as_float(__float_as_uint(e) & (unsigned)spread);
        }
        ev[v] = e;
      }
      bf16x4v wb = __builtin_convertvector(ev, bf16x4v);
      s16x4 wpk = __builtin_bit_cast(s16x4, wb);
      __builtin_amdgcn_s_setprio(1);
      dacc = mfma16(ones, wpk, dacc);                 // row-sum: denominator, free VALU
#pragma unroll
      for (int p = 0; p < 2; ++p) {
        s16x8 vf = *(const s16x8*)&Vs[(mt * 2 + p) * 512 + l * 8];
        s16x4 lo = __builtin_shufflevector(vf, vf, 0, 1, 2, 3);
        s16x4 hi = __builtin_shufflevector(vf, vf, 4, 5, 6, 7);
        oacc[2 * p + 0] = mfma16(lo, wpk, oacc[2 * p + 0]);
        oacc[2 * p + 1] = mfma16(hi, wpk, oacc[2 * p + 1]);
      }
      __builtin_amdgcn_s_setprio(0);
    }
    __syncthreads();
    cur ^= 1;
  }
  float r = dacc[0];
  float dinv = 1.0f / r;
  if (l < 16) db[(size_t)(z * HEADS + h) * SS + qt2 * 16 + li] = -__log2f(r);
  u16* ob = out01 + (size_t)z * SS * DIM;
#pragma unroll
  for (int dt = 0; dt < 4; ++dt) {
    f32x4 o = oacc[dt] * dinv;
    ushort4 us;
    us.x = f2b(o[0]); us.y = f2b(o[1]); us.z = f2b(o[2]); us.w = f2b(o[3]);
    *(ushort4*)&ob[((size_t)(qt2 * 16 + li)) * DIM + h * HD + dt * 16 + 4 * g] = us;
  }
}

__global__ __launch_bounds__(512, 8) void attn_pv(const u16* __restrict__ Qfrag,
                                                  const u16* __restrict__ Kfrag,
                                                  const u16* __restrict__ Vfrag,
                                                  const unsigned* __restrict__ mbits,
                                                  u16* __restrict__ out01,
                                                  float* __restrict__ db) {
  __shared__ u16 KV[2][8192];  // 32 KB double-buffered K+V tile
  const int flat = blockIdx.x;                 // 1024 blocks
  const int xcd = flat & 7, i = flat >> 3;     // i in [0,128)
  const int k = i >> 4, qg = i & 15;
  const int zh = xcd + 8 * k;                  // [0,64)
  const int z = zh >> 4, h = zh & 15;
  const int w = threadIdx.x >> 6, l = threadIdx.x & 63;
  const int qt2 = qg * 8 + w;
  if (z < 2) attn_pv_body<1>(z, h, qt2, w, l, Qfrag, Kfrag, Vfrag, mbits, out01, db, &KV[0][0]);
  else       attn_pv_body<0>(z, h, qt2, w, l, Qfrag, Kfrag, Vfrag, mbits, out01, db, &KV[0][0]);
}

// ---------------- amean: LDS-staged K (double-buffered per head), z-balanced XCD map ----------------
// block = 4 waves, same (z,lt), 4 consecutive qt2; K-tile for head h staged cooperatively.
template<int MASKED>
static __device__ __forceinline__ void amean_body(int z, int qt2, int lt, int w, int l,
                                                  const u16* __restrict__ Qfrag,
                                                  const u16* __restrict__ Kfrag,
                                                  const unsigned* __restrict__ mbits,
                                                  const float* __restrict__ db,
                                                  float* __restrict__ aout,
                                                  u16* __restrict__ KS) {
  const int g = l >> 4, li = l & 15;
  const int b = z & 1;
  const int qt = qt2 >> 1, n = qt2 & 1;

  unsigned mw[2];
  if (MASKED) {
    const unsigned* m0 = mbits + (size_t)(qt2 * 16 + li) * (LLL / 32) + lt * 2;
    mw[0] = m0[0]; mw[1] = m0[1];
  }
  const u16* qf_base = Qfrag + ((((size_t)(b * HEADS) * 64 + qt) * 4 + n * 2)) * 512 + l * 8;
  const float* dbb = db + (size_t)(z * HEADS) * SS + qt2 * 16 + li;

  // stage K-tile of head h into buffer buf: wave w stages fragments {2w, 2w+1}
  auto stageK = [&](int buf, int h) {
    const u16* kfh = Kfrag + ((((size_t)(z * HEADS + h)) * 32 + lt) * 8) * 512;
#pragma unroll
    for (int i2 = 0; i2 < 2; ++i2) {
      int f = w * 2 + i2;
      gload_lds16(kfh + f * 512 + l * 8, (char*)KS + buf * 8192 + f * 1024);
    }
  };

  f32x4 asum[4] = {};
  stageK(0, 0);
  __syncthreads();
#pragma unroll 2
  for (int h = 0; h < HEADS; ++h) {
    if (h + 1 < HEADS) stageK((h + 1) & 1, h + 1);   // prefetch under compute
    float l2 = dbb[(size_t)h * SS];                  // -log2(denom), precomputed
    bf16x8 qf0 = *(const bf16x8*)&qf_base[(size_t)h * (64 * 4 * 512)];
    bf16x8 qf1 = *(const bf16x8*)&qf_base[(size_t)h * (64 * 4 * 512) + 512];
    const u16* Ks = KS + (h & 1) * 4096;
#pragma unroll
    for (int mt = 0; mt < 4; ++mt) {
      f32x4 s = {};
      s = mfma32(*(const bf16x8*)&Ks[(mt * 2 + 0) * 512 + l * 8], qf0, s);
      s = mfma32(*(const bf16x8*)&Ks[(mt * 2 + 1) * 512 + l * 8], qf1, s);
      unsigned mm = MASKED ? (mw[mt >> 1] >> ((mt & 1) * 16 + 4 * g)) : 0u;
#pragma unroll
      for (int v = 0; v < 4; ++v) {
        float e = __builtin_amdgcn_exp2f(s[v] + l2);
        if (MASKED) {
          int spread = ((int)(mm << (31 - v))) >> 31;  // all-ones if keep
          e = __uint_as_float(__float_as_uint(e) & (unsigned)spread);
        }
        asum[mt][v] += e;
      }
    }
    __syncthreads();  // waves done reading Ks[h&1]; h+1 loads drained
  }
  float* ab = aout + (size_t)z * SS * LLL;
#pragma unroll
  for (int mt = 0; mt < 4; ++mt) {
    f32x4 o = asum[mt] * 0.0625f;
    f32x4* dst = (f32x4*)&ab[(size_t)(qt2 * 16 + li) * LLL + lt * 64 + mt * 16 + 4 * g];
    __builtin_nontemporal_store(o, dst);
  }
}

__global__ __launch_bounds__(256, 8) void amean(const u16* __restrict__ Qfrag,
                                                const u16* __restrict__ Kfrag,
                                                const unsigned* __restrict__ mbits,
                                                const float* __restrict__ db,
                                                float* __restrict__ aout) {
  __shared__ u16 KS[2][4096];  // 16 KB double-buffered K tile
  // z-balanced XCD map over (z,lt) groups
  const int flat = blockIdx.x;                 // 4096 blocks
  const int xcd = flat & 7, i = flat >> 3;     // i in [0,512)
  const int k = i >> 5, qg = i & 31;           // k in [0,16)
  const int zlt = xcd + 8 * k;                 // [0,128)
  const int z = zlt >> 5, lt = zlt & 31;
  const int w = threadIdx.x >> 6, l = threadIdx.x & 63;
  const int qt2 = qg * 4 + w;
  if (z < 2) amean_body<1>(z, qt2, lt, w, l, Qfrag, Kfrag, mbits, db, aout, &KS[0][0]);
  else       amean_body<0>(z, qt2, lt, w, l, Qfrag, Kfrag, mbits, db, aout, &KS[0][0]);
}

// ---------------- gated merge ----------------
__global__ void merge_kernel(const u16* __restrict__ o01,
                             const float* __restrict__ gate,
                             u16* __restrict__ merged) {
  int i = blockIdx.x * blockDim.x + threadIdx.x;
  float gv = gate[0];
  float g = 1.0f / (1.0f + __builtin_amdgcn_exp2f(-gv * LOG2E));
  const size_t n = (size_t)BB * SS * DIM;
  ushort4 a = ((const ushort4*)o01)[i];
  ushort4 c = ((const ushort4*)(o01 + n))[i];
  ushort4 o;
  o.x = f2b(g * b2f(a.x) + (1.f - g) * b2f(c.x));
  o.y = f2b(g * b2f(a.y) + (1.f - g) * b2f(c.y));
  o.z = f2b(g * b2f(a.z) + (1.f - g) * b2f(c.z));
  o.w = f2b(g * b2f(a.w) + (1.f - g) * b2f(c.w));
  ((ushort4*)merged)[i] = o;
}

extern "C" void kernel_launch(void* const* d_in, const int* in_sizes, int n_in,
                              void* d_out, int out_size, void* d_ws, size_t ws_size,
                              hipStream_t stream) {
  const float* query = (const float*)d_in[0];
  const float* k0f   = (const float*)d_in[1];
  const float* v0f   = (const float*)d_in[2];
  const float* k1f   = (const float*)d_in[3];
  const float* v1f   = (const float*)d_in[4];
  const int*   mask  = (const int*)d_in[5];
  const float* Wqf   = (const float*)d_in[6];
  const float* bq    = (const float*)d_in[7];
  const float* Wof   = (const float*)d_in[8];
  const float* bo    = (const float*)d_in[9];
  const float* gate  = (const float*)d_in[10];
  float* out = (float*)d_out;

  const size_t nQ = (size_t)BB * SS * DIM;
  const size_t nW = (size_t)DIM * DIM;

  char* ws = (char*)d_ws;
  size_t off = 0;
  auto alloc = [&](size_t bytes) -> char* {
    char* p = ws + off;
    off += (bytes + 255) & ~(size_t)255;
    return p;
  };
  u16*      queryb  = (u16*)alloc(nQ * 2);             // reused as mergedb later
  u16*      wqb     = (u16*)alloc(nW * 2);
  u16*      wob     = (u16*)alloc(nW * 2);
  u16*      Qfrag   = (u16*)alloc(nQ * 2);             // [b][h][qt][c][lane][8]
  u16*      Kfrag   = (u16*)alloc((size_t)2 * nQ * 2); // [z][h][lt][c][lane][8] (prescaled)
  u16*      Vfrag   = (u16*)alloc((size_t)2 * nQ * 2);
  unsigned* mbits   = (unsigned*)alloc((size_t)SS * (LLL / 32) * 4);
  float*    db      = (float*)alloc((size_t)4 * HEADS * SS * 4);  // -log2(denom) per [z][h][q]
  u16*      out01   = (u16*)alloc((size_t)2 * nQ * 2);
  u16*      mergedb = queryb;  // queryb dead after q-proj gemm

  auto cvt = [&](const float* s, u16* d, size_t n) {
    int n4 = (int)(n / 4);
    cvt_f32_bf16<<<dim3((n4 + 255) / 256), dim3(256), 0, stream>>>(s, d, n4);
  };
  cvt(query, queryb, nQ);
  cvt(Wqf, wqb, nW);
  cvt(Wof, wob, nW);

  mask_pack<<<dim3(SS * (LLL / 32) / 256), dim3(256), 0, stream>>>(mask, mbits);
  pack_k<<<dim3(LLL / 64 / 4, HEADS, 4), dim3(256), 0, stream>>>(k0f, k1f, Kfrag);
  pack_v<<<dim3(LLL / 64, HEADS, 4), dim3(256), 0, stream>>>(v0f, v1f, Vfrag);

  // q projection straight into fragment layout (128x64 tiles)
  gemm_nt<2><<<dim3(DIM / 64, (BB * SS) / 128), dim3(256), 0, stream>>>(
      queryb, wqb, bq, (void*)Qfrag, BB * SS, DIM, DIM);

  // fused single-pass attention: double-buffered LDS staging, 128 q-rows per block
  attn_pv<<<dim3(1024), dim3(512), 0, stream>>>(Qfrag, Kfrag, Vfrag, mbits, out01, db);

  // head-mean attention maps straight into d_out (LDS-staged K)
  amean<<<dim3(4096), dim3(256), 0, stream>>>(Qfrag, Kfrag, mbits, db, out + nQ);

  merge_kernel<<<dim3((int)(nQ / 4 / 256)), dim3(256), 0, stream>>>(out01, gate, mergedb);

  gemm_nt<1><<<dim3(DIM / 64, (BB * SS) / 128), dim3(256), 0, stream>>>(
      mergedb, wob, bo, (void*)out, BB * SS, DIM, DIM);
}

// Round 13
// 226.360 us; speedup vs baseline: 3.7931x; 1.0411x over previous
//
#include <hip/hip_runtime.h>

#define DIM   1024
#define HEADS 16
#define HD    64
#define BB    2
#define SS    2048
#define LLL   2048
#define LOG2E 1.4426950408889634f

typedef __bf16 bf16x8 __attribute__((ext_vector_type(8)));
typedef __bf16 bf16x4v __attribute__((ext_vector_type(4)));
typedef float  f32x4  __attribute__((ext_vector_type(4)));
typedef short  s16x4  __attribute__((ext_vector_type(4)));
typedef short  s16x8  __attribute__((ext_vector_type(8)));
typedef unsigned short u16;

static __device__ __forceinline__ u16 f2b(float x) {
  unsigned u = __float_as_uint(x);
  u += 0x7fffu + ((u >> 16) & 1u);
  return (u16)(u >> 16);
}
static __device__ __forceinline__ float b2f(u16 u) {
  return __uint_as_float(((unsigned)u) << 16);
}
static __device__ __forceinline__ f32x4 mfma32(bf16x8 a, bf16x8 b, f32x4 c) {
  return __builtin_amdgcn_mfma_f32_16x16x32_bf16(a, b, c, 0, 0, 0);
}
static __device__ __forceinline__ f32x4 mfma16(s16x4 a, s16x4 b, f32x4 c) {
#if __has_builtin(__builtin_amdgcn_mfma_f32_16x16x16bf16_1k)
  return __builtin_amdgcn_mfma_f32_16x16x16bf16_1k(a, b, c, 0, 0, 0);
#else
  asm volatile("v_mfma_f32_16x16x16_bf16 %0, %1, %2, %0" : "+v"(c) : "v"(a), "v"(b));
  return c;
#endif
}

// async global->LDS, 16B/lane. LDS base must be WAVE-UNIFORM (HW adds lane*16).
static __device__ __forceinline__ void gload_lds16(const void* g, void* lds_uniform_base) {
#if __has_builtin(__builtin_amdgcn_global_load_lds)
  __builtin_amdgcn_global_load_lds(
      (const __attribute__((address_space(1))) unsigned int*)g,
      (__attribute__((address_space(3))) unsigned int*)lds_uniform_base, 16, 0, 0);
#else
  const int l = threadIdx.x & 63;
  ((uint4*)lds_uniform_base)[l] = ((const uint4*)g)[0];
#endif
}

// ---------------- f32 -> bf16 convert ----------------
__global__ void cvt_f32_bf16(const float* __restrict__ src, u16* __restrict__ dst, int n4) {
  int i = blockIdx.x * blockDim.x + threadIdx.x;
  if (i >= n4) return;
  float4 f = ((const float4*)src)[i];
  ushort4 o;
  o.x = f2b(f.x); o.y = f2b(f.y); o.z = f2b(f.z); o.w = f2b(f.w);
  ((ushort4*)dst)[i] = o;
}

// ---------------- mask -> bitmask ----------------
__global__ void mask_pack(const int* __restrict__ mask, unsigned* __restrict__ mbits) {
  int i = blockIdx.x * blockDim.x + threadIdx.x;
  const int* src = mask + (size_t)i * 32;
  unsigned bm = 0;
#pragma unroll
  for (int j = 0; j < 8; ++j) {
    int4 m = ((const int4*)src)[j];
    bm |= (m.x != 0 ? 1u : 0u) << (j * 4 + 0);
    bm |= (m.y != 0 ? 1u : 0u) << (j * 4 + 1);
    bm |= (m.z != 0 ? 1u : 0u) << (j * 4 + 2);
    bm |= (m.w != 0 ? 1u : 0u) << (j * 4 + 3);
  }
  mbits[i] = bm;
}

// ---------------- K (f32) -> fragment-packed bf16 tiles, PRESCALED by 0.125*log2(e) ----------------
__global__ __launch_bounds__(256) void pack_k(const float* __restrict__ k0,
                                              const float* __restrict__ k1,
                                              u16* __restrict__ Kfrag) {
  const float SCK = 0.125f * LOG2E;
  const int w = threadIdx.x >> 6, l = threadIdx.x & 63, g = l >> 4, li = l & 15;
  const int lt = blockIdx.x * 4 + w, h = blockIdx.y, z = blockIdx.z;
  const int lay = z >> 1, b = z & 1;
  const float* src = (lay ? k1 : k0) + (size_t)b * LLL * DIM;
  u16* dst = Kfrag + ((((size_t)z * HEADS + h) * 32 + lt) * 8) * 512;
#pragma unroll
  for (int c = 0; c < 8; ++c) {
    int mt = c >> 1, kk = c & 1;
    const float* p = &src[(size_t)(lt * 64 + mt * 16 + li) * DIM + h * 64 + kk * 32 + g * 8];
    float4 f0 = *(const float4*)p;
    float4 f1 = *(const float4*)(p + 4);
    u16 u[8] = {f2b(f0.x * SCK), f2b(f0.y * SCK), f2b(f0.z * SCK), f2b(f0.w * SCK),
                f2b(f1.x * SCK), f2b(f1.y * SCK), f2b(f1.z * SCK), f2b(f1.w * SCK)};
    *(uint4*)&dst[c * 512 + l * 8] = *(uint4*)u;
  }
}

// ---------------- V (f32) -> fragment-packed bf16 tiles (transposed) ----------------
__global__ __launch_bounds__(256) void pack_v(const float* __restrict__ v0,
                                              const float* __restrict__ v1,
                                              u16* __restrict__ Vfrag) {
  __shared__ u16 T[64][72];  // T[l][d]
  const int lt = blockIdx.x, h = blockIdx.y, z = blockIdx.z;
  const int lay = z >> 1, b = z & 1;
  const float* v = (lay ? v1 : v0) + (size_t)b * LLL * DIM;
  const int t = threadIdx.x;
  {
    int r = t >> 2, c16 = (t & 3) * 16;
    const float* src = &v[(size_t)(lt * 64 + r) * DIM + h * 64 + c16];
#pragma unroll
    for (int i = 0; i < 4; ++i) {
      float4 f = *(const float4*)&src[i * 4];
      T[r][c16 + i * 4 + 0] = f2b(f.x);
      T[r][c16 + i * 4 + 1] = f2b(f.y);
      T[r][c16 + i * 4 + 2] = f2b(f.z);
      T[r][c16 + i * 4 + 3] = f2b(f.w);
    }
  }
  __syncthreads();
  u16* dst = Vfrag + ((((size_t)z * HEADS + h) * 32 + lt) * 8) * 512;
  {
    int lane = t & 63, g = lane >> 4, li = lane & 15;
#pragma unroll
    for (int cc = 0; cc < 2; ++cc) {
      int c = (t >> 6) + cc * 4;
      int mt = c >> 1, p = c & 1;
      u16 u[8];
#pragma unroll
      for (int j = 0; j < 4; ++j) u[j] = T[mt * 16 + 4 * g + j][p * 32 + li];
#pragma unroll
      for (int j = 0; j < 4; ++j) u[4 + j] = T[mt * 16 + 4 * g + j][p * 32 + 16 + li];
      *(uint4*)&dst[c * 512 + lane * 8] = *(uint4*)u;
    }
  }
}

// ---------------- bf16 NT GEMM, 128x64 tile, global_load_lds staging ----------------
template<int MODE>
__global__ __launch_bounds__(256) void gemm_nt(const u16* __restrict__ A,
                                               const u16* __restrict__ Bt,
                                               const float* __restrict__ bias,
                                               void* __restrict__ Cv,
                                               int M, int N, int K) {
  __shared__ u16 As[128][64];
  __shared__ u16 Bs[64][64];
  const int t = threadIdx.x;
  const int w = t >> 6, l = t & 63, g = l >> 4, li = l & 15;
  const int m0 = blockIdx.y * 128, n0 = blockIdx.x * 64;
  const int slotL = w * 64 + l;
  const int rA = slotL >> 3, cA = ((slotL & 7) * 8) ^ ((rA & 7) * 8);
  f32x4 acc[2][4] = {};
  for (int kt = 0; kt < K; kt += 64) {
#pragma unroll
    for (int s = 0; s < 4; ++s) {
      int r = rA + s * 32;
      gload_lds16(&A[(size_t)(m0 + r) * K + kt + cA], &As[0][0] + (s * 256 + w * 64) * 8);
    }
#pragma unroll
    for (int s = 0; s < 2; ++s) {
      int r = rA + s * 32;
      gload_lds16(&Bt[(size_t)(n0 + r) * K + kt + cA], &Bs[0][0] + (s * 256 + w * 64) * 8);
    }
    __syncthreads();
#pragma unroll
    for (int kk = 0; kk < 2; ++kk) {
      bf16x8 a[2], bfr[4];
#pragma unroll
      for (int mi = 0; mi < 2; ++mi) {
        int ra = w * 32 + mi * 16 + li;
        a[mi] = *(const bf16x8*)&As[ra][(kk * 32 + g * 8) ^ ((ra & 7) << 3)];
      }
#pragma unroll
      for (int ni = 0; ni < 4; ++ni) {
        int rb = ni * 16 + li;
        bfr[ni] = *(const bf16x8*)&Bs[rb][(kk * 32 + g * 8) ^ ((rb & 7) << 3)];
      }
#pragma unroll
      for (int mi = 0; mi < 2; ++mi)
#pragma unroll
        for (int ni = 0; ni < 4; ++ni)
          acc[mi][ni] = mfma32(a[mi], bfr[ni], acc[mi][ni]);
    }
    __syncthreads();
  }
#pragma unroll
  for (int mi = 0; mi < 2; ++mi)
#pragma unroll
    for (int ni = 0; ni < 4; ++ni)
#pragma unroll
      for (int v = 0; v < 4; ++v) {
        int rr = m0 + w * 32 + mi * 16 + g * 4 + v;
        int cc = n0 + ni * 16 + li;
        float val = acc[mi][ni][v] + bias[cc];
        if (MODE == 1) {
          ((float*)Cv)[(size_t)rr * N + cc] = val;
        } else {
          // Qfrag[b][h][qt][c=n*2+kk][lane(gp,liq)][8]
          int b = rr >> 11, q = rr & 2047;
          int qt = q >> 5, n = (q >> 4) & 1, liq = q & 15;
          int h = (cc >> 6) & 15, kk2 = (cc >> 5) & 1, gp = (cc >> 3) & 3, j = cc & 7;
          size_t base = ((((size_t)b * HEADS + h) * 64 + qt) * 4 + n * 2 + kk2) * 512;
          ((u16*)Cv)[base + (size_t)(gp * 16 + liq) * 8 + j] = f2b(val);
        }
      }
}

// ---------------- attn_pv: 32 q-rows/wave (both n-halves) — halves LDS reads per row ----------------
// db layout: [z*HEADS+h][q] = -log2(denominator)  (consumed by amean as exp2 bias)
template<int MASKED>
static __device__ __forceinline__ void attn_pv_body(int z, int h, int qt, int w, int l,
                                                    const u16* __restrict__ Qfrag,
                                                    const u16* __restrict__ Kfrag,
                                                    const u16* __restrict__ Vfrag,
                                                    const unsigned* __restrict__ mbits,
                                                    u16* __restrict__ out01,
                                                    float* __restrict__ db,
                                                    u16* __restrict__ KV) {
  const int g = l >> 4, li = l & 15;
  const int b = z & 1;
  const u16* kfh = Kfrag + (size_t)(z * HEADS + h) * (32 * 8 * 512);
  const u16* vfh = Vfrag + (size_t)(z * HEADS + h) * (32 * 8 * 512);
  const u16* qfh = Qfrag + (((size_t)(b * HEADS + h) * 64 + qt) * 4) * 512;

  bf16x8 qf[2][2];
#pragma unroll
  for (int n = 0; n < 2; ++n)
#pragma unroll
    for (int kk = 0; kk < 2; ++kk)
      qf[n][kk] = *(const bf16x8*)&qfh[(n * 2 + kk) * 512 + l * 8];

  const unsigned* mrow0 = MASKED ? mbits + (size_t)(qt * 32 + li) * (LLL / 32) : nullptr;
  const unsigned* mrow1 = MASKED ? mrow0 + 16 * (LLL / 32) : nullptr;
  const int shb = 4 * g;
  const s16x4 ones = {(short)0x3F80, (short)0x3F80, (short)0x3F80, (short)0x3F80};

  auto stage = [&](int buf, int lt) {
    const u16* kfl = kfh + (size_t)lt * 4096;
    const u16* vfl = vfh + (size_t)lt * 4096;
#pragma unroll
    for (int i2 = 0; i2 < 2; ++i2) {
      int f = w * 2 + i2;
      const u16* gsrc = (f < 8 ? kfl + f * 512 : vfl + (f - 8) * 512) + l * 8;
      gload_lds16(gsrc, (char*)KV + buf * 16384 + f * 1024);
    }
  };

  f32x4 dacc[2] = {};     // denominator per n-half, on the MATRIX pipe (A = ones)
  f32x4 oacc[4][2] = {};  // [dt][n], unnormalized

  stage(0, 0);
  __syncthreads();
  int cur = 0;
  for (int lt = 0; lt < 32; ++lt) {
    if (lt + 1 < 32) stage(cur ^ 1, lt + 1);  // prefetch flies under compute
    unsigned mw[2][2];
    if (MASKED) {
      mw[0][0] = mrow0[lt * 2]; mw[0][1] = mrow0[lt * 2 + 1];
      mw[1][0] = mrow1[lt * 2]; mw[1][1] = mrow1[lt * 2 + 1];
    }
    const u16* Ks = KV + cur * 8192;
    const u16* Vs = Ks + 4096;
#pragma unroll
    for (int mt = 0; mt < 4; ++mt) {
      bf16x8 k0 = *(const bf16x8*)&Ks[(mt * 2 + 0) * 512 + l * 8];
      bf16x8 k1 = *(const bf16x8*)&Ks[(mt * 2 + 1) * 512 + l * 8];
      f32x4 s[2] = {};
      __builtin_amdgcn_s_setprio(1);
#pragma unroll
      for (int n = 0; n < 2; ++n) {
        s[n] = mfma32(k0, qf[n][0], s[n]);
        s[n] = mfma32(k1, qf[n][1], s[n]);
      }
      __builtin_amdgcn_s_setprio(0);
      s16x4 wpk[2];
#pragma unroll
      for (int n = 0; n < 2; ++n) {
        unsigned mm = MASKED ? (mw[n][mt >> 1] >> ((mt & 1) * 16 + shb)) : 0u;
        f32x4 ev;
#pragma unroll
        for (int v = 0; v < 4; ++v) {
          float e = __builtin_amdgcn_exp2f(s[n][v]);    // K prescaled: zero prep
          if (MASKED) {
            int spread = ((int)(mm << (31 - v))) >> 31; // all-ones if keep
            e = __uint_as_float(__float_as_uint(e) & (unsigned)spread);
          }
          ev[v] = e;
        }
        bf16x4v wb = __builtin_convertvector(ev, bf16x4v);
        wpk[n] = __builtin_bit_cast(s16x4, wb);
      }
      __builtin_amdgcn_s_setprio(1);
      dacc[0] = mfma16(ones, wpk[0], dacc[0]);
      dacc[1] = mfma16(ones, wpk[1], dacc[1]);
#pragma unroll
      for (int p = 0; p < 2; ++p) {
        s16x8 vf = *(const s16x8*)&Vs[(mt * 2 + p) * 512 + l * 8];
        s16x4 lo = __builtin_shufflevector(vf, vf, 0, 1, 2, 3);
        s16x4 hi = __builtin_shufflevector(vf, vf, 4, 5, 6, 7);
#pragma unroll
        for (int n = 0; n < 2; ++n) {
          oacc[2 * p + 0][n] = mfma16(lo, wpk[n], oacc[2 * p + 0][n]);
          oacc[2 * p + 1][n] = mfma16(hi, wpk[n], oacc[2 * p + 1][n]);
        }
      }
      __builtin_amdgcn_s_setprio(0);
    }
    __syncthreads();
    cur ^= 1;
  }
  float dinv[2];
  dinv[0] = 1.0f / dacc[0][0];
  dinv[1] = 1.0f / dacc[1][0];
  if (l < 16) {
    db[(size_t)(z * HEADS + h) * SS + qt * 32 + li]      = -__log2f(dacc[0][0]);
    db[(size_t)(z * HEADS + h) * SS + qt * 32 + 16 + li] = -__log2f(dacc[1][0]);
  }
  u16* ob = out01 + (size_t)z * SS * DIM;
#pragma unroll
  for (int dt = 0; dt < 4; ++dt)
#pragma unroll
    for (int n = 0; n < 2; ++n) {
      f32x4 o = oacc[dt][n] * dinv[n];
      ushort4 us;
      us.x = f2b(o[0]); us.y = f2b(o[1]); us.z = f2b(o[2]); us.w = f2b(o[3]);
      *(ushort4*)&ob[((size_t)(qt * 32 + n * 16 + li)) * DIM + h * HD + dt * 16 + 4 * g] = us;
    }
}

__global__ __launch_bounds__(512, 4) void attn_pv(const u16* __restrict__ Qfrag,
                                                  const u16* __restrict__ Kfrag,
                                                  const u16* __restrict__ Vfrag,
                                                  const unsigned* __restrict__ mbits,
                                                  u16* __restrict__ out01,
                                                  float* __restrict__ db) {
  __shared__ u16 KV[2][8192];  // 32 KB double-buffered K+V tile
  // z-balanced XCD map (512 blocks): each XCD gets zh spanning all z
  const int flat = blockIdx.x;
  const int xcd = flat & 7, i = flat >> 3;     // i in [0,64)
  const int k = i >> 3, qg = i & 7;            // k in [0,8)
  const int zh = xcd + 8 * k;                  // [0,64)
  const int z = zh >> 4, h = zh & 15;
  const int w = threadIdx.x >> 6, l = threadIdx.x & 63;
  const int qt = qg * 8 + w;                   // [0,64)
  if (z < 2) attn_pv_body<1>(z, h, qt, w, l, Qfrag, Kfrag, Vfrag, mbits, out01, db, &KV[0][0]);
  else       attn_pv_body<0>(z, h, qt, w, l, Qfrag, Kfrag, Vfrag, mbits, out01, db, &KV[0][0]);
}

// ---------------- amean: 32 q-rows/wave, LDS-staged K (double-buffered per head) ----------------
template<int MASKED>
static __device__ __forceinline__ void amean_body(int z, int qt, int lt, int w, int l,
                                                  const u16* __restrict__ Qfrag,
                                                  const u16* __restrict__ Kfrag,
                                                  const unsigned* __restrict__ mbits,
                                                  const float* __restrict__ db,
                                                  float* __restrict__ aout,
                                                  u16* __restrict__ KS) {
  const int g = l >> 4, li = l & 15;
  const int b = z & 1;

  unsigned mw[2][2];
  if (MASKED) {
    const unsigned* m0 = mbits + (size_t)(qt * 32 + li) * (LLL / 32) + lt * 2;
    const unsigned* m1 = m0 + 16 * (LLL / 32);
    mw[0][0] = m0[0]; mw[0][1] = m0[1];
    mw[1][0] = m1[0]; mw[1][1] = m1[1];
  }
  const u16* qf_base = Qfrag + (((size_t)(b * HEADS) * 64 + qt) * 4) * 512 + l * 8;
  const float* dbb = db + (size_t)(z * HEADS) * SS + qt * 32 + li;

  auto stageK = [&](int buf, int h) {
    const u16* kfh = Kfrag + ((((size_t)(z * HEADS + h)) * 32 + lt) * 8) * 512;
#pragma unroll
    for (int i2 = 0; i2 < 2; ++i2) {
      int f = w * 2 + i2;
      gload_lds16(kfh + f * 512 + l * 8, (char*)KS + buf * 8192 + f * 1024);
    }
  };

  f32x4 asum[4][2] = {};
  stageK(0, 0);
  __syncthreads();
#pragma unroll 2
  for (int h = 0; h < HEADS; ++h) {
    if (h + 1 < HEADS) stageK((h + 1) & 1, h + 1);   // prefetch under compute
    float l2[2];
    l2[0] = dbb[(size_t)h * SS];                     // -log2(denom), precomputed
    l2[1] = dbb[(size_t)h * SS + 16];
    bf16x8 qf[2][2];
#pragma unroll
    for (int n = 0; n < 2; ++n)
#pragma unroll
      for (int kk = 0; kk < 2; ++kk)
        qf[n][kk] = *(const bf16x8*)&qf_base[(size_t)h * (64 * 4 * 512) + (n * 2 + kk) * 512];
    const u16* Ks = KS + (h & 1) * 4096;
#pragma unroll
    for (int mt = 0; mt < 4; ++mt) {
      bf16x8 k0 = *(const bf16x8*)&Ks[(mt * 2 + 0) * 512 + l * 8];
      bf16x8 k1 = *(const bf16x8*)&Ks[(mt * 2 + 1) * 512 + l * 8];
#pragma unroll
      for (int n = 0; n < 2; ++n) {
        f32x4 s = {};
        s = mfma32(k0, qf[n][0], s);
        s = mfma32(k1, qf[n][1], s);
        unsigned mm = MASKED ? (mw[n][mt >> 1] >> ((mt & 1) * 16 + 4 * g)) : 0u;
#pragma unroll
        for (int v = 0; v < 4; ++v) {
          float e = __builtin_amdgcn_exp2f(s[v] + l2[n]);
          if (MASKED) {
            int spread = ((int)(mm << (31 - v))) >> 31;  // all-ones if keep
            e = __uint_as_float(__float_as_uint(e) & (unsigned)spread);
          }
          asum[mt][n][v] += e;
        }
      }
    }
    __syncthreads();  // waves done reading Ks[h&1]; h+1 loads drained
  }
  float* ab = aout + (size_t)z * SS * LLL;
#pragma unroll
  for (int mt = 0; mt < 4; ++mt)
#pragma unroll
    for (int n = 0; n < 2; ++n) {
      f32x4 o = asum[mt][n] * 0.0625f;
      f32x4* dst = (f32x4*)&ab[(size_t)(qt * 32 + n * 16 + li) * LLL + lt * 64 + mt * 16 + 4 * g];
      __builtin_nontemporal_store(o, dst);
    }
}

__global__ __launch_bounds__(256, 4) void amean(const u16* __restrict__ Qfrag,
                                                const u16* __restrict__ Kfrag,
                                                const unsigned* __restrict__ mbits,
                                                const float* __restrict__ db,
                                                float* __restrict__ aout) {
  __shared__ u16 KS[2][4096];  // 16 KB double-buffered K tile
  // z-balanced XCD map over (z,lt) groups (2048 blocks)
  const int flat = blockIdx.x;
  const int xcd = flat & 7, i = flat >> 3;     // i in [0,256)
  const int k = i >> 4, qg = i & 15;           // k in [0,16)
  const int zlt = xcd + 8 * k;                 // [0,128)
  const int z = zlt >> 5, lt = zlt & 31;
  const int w = threadIdx.x >> 6, l = threadIdx.x & 63;
  const int qt = qg * 4 + w;                   // [0,64)
  if (z < 2) amean_body<1>(z, qt, lt, w, l, Qfrag, Kfrag, mbits, db, aout, &KS[0][0]);
  else       amean_body<0>(z, qt, lt, w, l, Qfrag, Kfrag, mbits, db, aout, &KS[0][0]);
}

// ---------------- gated merge ----------------
__global__ void merge_kernel(const u16* __restrict__ o01,
                             const float* __restrict__ gate,
                             u16* __restrict__ merged) {
  int i = blockIdx.x * blockDim.x + threadIdx.x;
  float gv = gate[0];
  float g = 1.0f / (1.0f + __builtin_amdgcn_exp2f(-gv * LOG2E));
  const size_t n = (size_t)BB * SS * DIM;
  ushort4 a = ((const ushort4*)o01)[i];
  ushort4 c = ((const ushort4*)(o01 + n))[i];
  ushort4 o;
  o.x = f2b(g * b2f(a.x) + (1.f - g) * b2f(c.x));
  o.y = f2b(g * b2f(a.y) + (1.f - g) * b2f(c.y));
  o.z = f2b(g * b2f(a.z) + (1.f - g) * b2f(c.z));
  o.w = f2b(g * b2f(a.w) + (1.f - g) * b2f(c.w));
  ((ushort4*)merged)[i] = o;
}

extern "C" void kernel_launch(void* const* d_in, const int* in_sizes, int n_in,
                              void* d_out, int out_size, void* d_ws, size_t ws_size,
                              hipStream_t stream) {
  const float* query = (const float*)d_in[0];
  const float* k0f   = (const float*)d_in[1];
  const float* v0f   = (const float*)d_in[2];
  const float* k1f   = (const float*)d_in[3];
  const float* v1f   = (const float*)d_in[4];
  const int*   mask  = (const int*)d_in[5];
  const float* Wqf   = (const float*)d_in[6];
  const float* bq    = (const float*)d_in[7];
  const float* Wof   = (const float*)d_in[8];
  const float* bo    = (const float*)d_in[9];
  const float* gate  = (const float*)d_in[10];
  float* out = (float*)d_out;

  const size_t nQ = (size_t)BB * SS * DIM;
  const size_t nW = (size_t)DIM * DIM;

  char* ws = (char*)d_ws;
  size_t off = 0;
  auto alloc = [&](size_t bytes) -> char* {
    char* p = ws + off;
    off += (bytes + 255) & ~(size_t)255;
    return p;
  };
  u16*      queryb  = (u16*)alloc(nQ * 2);             // reused as mergedb later
  u16*      wqb     = (u16*)alloc(nW * 2);
  u16*      wob     = (u16*)alloc(nW * 2);
  u16*      Qfrag   = (u16*)alloc(nQ * 2);             // [b][h][qt][c][lane][8]
  u16*      Kfrag   = (u16*)alloc((size_t)2 * nQ * 2); // [z][h][lt][c][lane][8] (prescaled)
  u16*      Vfrag   = (u16*)alloc((size_t)2 * nQ * 2);
  unsigned* mbits   = (unsigned*)alloc((size_t)SS * (LLL / 32) * 4);
  float*    db      = (float*)alloc((size_t)4 * HEADS * SS * 4);  // -log2(denom) per [z][h][q]
  u16*      out01   = (u16*)alloc((size_t)2 * nQ * 2);
  u16*      mergedb = queryb;  // queryb dead after q-proj gemm

  auto cvt = [&](const float* s, u16* d, size_t n) {
    int n4 = (int)(n / 4);
    cvt_f32_bf16<<<dim3((n4 + 255) / 256), dim3(256), 0, stream>>>(s, d, n4);
  };
  cvt(query, queryb, nQ);
  cvt(Wqf, wqb, nW);
  cvt(Wof, wob, nW);

  mask_pack<<<dim3(SS * (LLL / 32) / 256), dim3(256), 0, stream>>>(mask, mbits);
  pack_k<<<dim3(LLL / 64 / 4, HEADS, 4), dim3(256), 0, stream>>>(k0f, k1f, Kfrag);
  pack_v<<<dim3(LLL / 64, HEADS, 4), dim3(256), 0, stream>>>(v0f, v1f, Vfrag);

  // q projection straight into fragment layout (128x64 tiles)
  gemm_nt<2><<<dim3(DIM / 64, (BB * SS) / 128), dim3(256), 0, stream>>>(
      queryb, wqb, bq, (void*)Qfrag, BB * SS, DIM, DIM);

  // fused single-pass attention: 32 rows/wave, double-buffered LDS staging
  attn_pv<<<dim3(512), dim3(512), 0, stream>>>(Qfrag, Kfrag, Vfrag, mbits, out01, db);

  // head-mean attention maps straight into d_out (LDS-staged K, 32 rows/wave)
  amean<<<dim3(2048), dim3(256), 0, stream>>>(Qfrag, Kfrag, mbits, db, out + nQ);

  merge_kernel<<<dim3((int)(nQ / 4 / 256)), dim3(256), 0, stream>>>(out01, gate, mergedb);

  gemm_nt<1><<<dim3(DIM / 64, (BB * SS) / 128), dim3(256), 0, stream>>>(
      mergedb, wob, bo, (void*)out, BB * SS, DIM, DIM);
}

// Round 14
// 219.363 us; speedup vs baseline: 3.9140x; 1.0319x over previous
//
#include <hip/hip_runtime.h>

#define DIM   1024
#define HEADS 16
#define HD    64
#define BB    2
#define SS    2048
#define LLL   2048
#define LOG2E 1.4426950408889634f

typedef __bf16 bf16x8 __attribute__((ext_vector_type(8)));
typedef __bf16 bf16x4v __attribute__((ext_vector_type(4)));
typedef float  f32x4  __attribute__((ext_vector_type(4)));
typedef short  s16x4  __attribute__((ext_vector_type(4)));
typedef short  s16x8  __attribute__((ext_vector_type(8)));
typedef unsigned short u16;

static __device__ __forceinline__ u16 f2b(float x) {
  unsigned u = __float_as_uint(x);
  u += 0x7fffu + ((u >> 16) & 1u);
  return (u16)(u >> 16);
}
static __device__ __forceinline__ float b2f(u16 u) {
  return __uint_as_float(((unsigned)u) << 16);
}
static __device__ __forceinline__ f32x4 mfma32(bf16x8 a, bf16x8 b, f32x4 c) {
  return __builtin_amdgcn_mfma_f32_16x16x32_bf16(a, b, c, 0, 0, 0);
}
static __device__ __forceinline__ f32x4 mfma16(s16x4 a, s16x4 b, f32x4 c) {
#if __has_builtin(__builtin_amdgcn_mfma_f32_16x16x16bf16_1k)
  return __builtin_amdgcn_mfma_f32_16x16x16bf16_1k(a, b, c, 0, 0, 0);
#else
  asm volatile("v_mfma_f32_16x16x16_bf16 %0, %1, %2, %0" : "+v"(c) : "v"(a), "v"(b));
  return c;
#endif
}

// async global->LDS, 16B/lane. LDS base must be WAVE-UNIFORM (HW adds lane*16).
static __device__ __forceinline__ void gload_lds16(const void* g, void* lds_uniform_base) {
#if __has_builtin(__builtin_amdgcn_global_load_lds)
  __builtin_amdgcn_global_load_lds(
      (const __attribute__((address_space(1))) unsigned int*)g,
      (__attribute__((address_space(3))) unsigned int*)lds_uniform_base, 16, 0, 0);
#else
  const int l = threadIdx.x & 63;
  ((uint4*)lds_uniform_base)[l] = ((const uint4*)g)[0];
#endif
}

// ---------------- fused f32 -> bf16 convert for query/Wq/Wo ----------------
__global__ void cvt3(const float* __restrict__ a, const float* __restrict__ b,
                     const float* __restrict__ c, u16* __restrict__ da,
                     u16* __restrict__ db_, u16* __restrict__ dc, int na4, int nb4) {
  int i = blockIdx.x * blockDim.x + threadIdx.x;
  const float* s; u16* d; int j = i;
  if (j < na4) { s = a; d = da; }
  else if ((j -= na4) < nb4) { s = b; d = db_; }
  else { j -= nb4; s = c; d = dc; }
  float4 f = ((const float4*)s)[j];
  ushort4 o;
  o.x = f2b(f.x); o.y = f2b(f.y); o.z = f2b(f.z); o.w = f2b(f.w);
  ((ushort4*)d)[j] = o;
}

// ---------------- mask -> bitmask ----------------
__global__ void mask_pack(const int* __restrict__ mask, unsigned* __restrict__ mbits) {
  int i = blockIdx.x * blockDim.x + threadIdx.x;
  const int* src = mask + (size_t)i * 32;
  unsigned bm = 0;
#pragma unroll
  for (int j = 0; j < 8; ++j) {
    int4 m = ((const int4*)src)[j];
    bm |= (m.x != 0 ? 1u : 0u) << (j * 4 + 0);
    bm |= (m.y != 0 ? 1u : 0u) << (j * 4 + 1);
    bm |= (m.z != 0 ? 1u : 0u) << (j * 4 + 2);
    bm |= (m.w != 0 ? 1u : 0u) << (j * 4 + 3);
  }
  mbits[i] = bm;
}

// ---------------- K (f32) -> fragment-packed bf16 tiles, PRESCALED by 0.125*log2(e) ----------------
__global__ __launch_bounds__(256) void pack_k(const float* __restrict__ k0,
                                              const float* __restrict__ k1,
                                              u16* __restrict__ Kfrag) {
  const float SCK = 0.125f * LOG2E;
  const int w = threadIdx.x >> 6, l = threadIdx.x & 63, g = l >> 4, li = l & 15;
  const int lt = blockIdx.x * 4 + w, h = blockIdx.y, z = blockIdx.z;
  const int lay = z >> 1, b = z & 1;
  const float* src = (lay ? k1 : k0) + (size_t)b * LLL * DIM;
  u16* dst = Kfrag + ((((size_t)z * HEADS + h) * 32 + lt) * 8) * 512;
#pragma unroll
  for (int c = 0; c < 8; ++c) {
    int mt = c >> 1, kk = c & 1;
    const float* p = &src[(size_t)(lt * 64 + mt * 16 + li) * DIM + h * 64 + kk * 32 + g * 8];
    float4 f0 = *(const float4*)p;
    float4 f1 = *(const float4*)(p + 4);
    u16 u[8] = {f2b(f0.x * SCK), f2b(f0.y * SCK), f2b(f0.z * SCK), f2b(f0.w * SCK),
                f2b(f1.x * SCK), f2b(f1.y * SCK), f2b(f1.z * SCK), f2b(f1.w * SCK)};
    *(uint4*)&dst[c * 512 + l * 8] = *(uint4*)u;
  }
}

// ---------------- V (f32) -> fragment-packed bf16 tiles (transposed) ----------------
__global__ __launch_bounds__(256) void pack_v(const float* __restrict__ v0,
                                              const float* __restrict__ v1,
                                              u16* __restrict__ Vfrag) {
  __shared__ u16 T[64][72];  // T[l][d]
  const int lt = blockIdx.x, h = blockIdx.y, z = blockIdx.z;
  const int lay = z >> 1, b = z & 1;
  const float* v = (lay ? v1 : v0) + (size_t)b * LLL * DIM;
  const int t = threadIdx.x;
  {
    int r = t >> 2, c16 = (t & 3) * 16;
    const float* src = &v[(size_t)(lt * 64 + r) * DIM + h * 64 + c16];
#pragma unroll
    for (int i = 0; i < 4; ++i) {
      float4 f = *(const float4*)&src[i * 4];
      T[r][c16 + i * 4 + 0] = f2b(f.x);
      T[r][c16 + i * 4 + 1] = f2b(f.y);
      T[r][c16 + i * 4 + 2] = f2b(f.z);
      T[r][c16 + i * 4 + 3] = f2b(f.w);
    }
  }
  __syncthreads();
  u16* dst = Vfrag + ((((size_t)z * HEADS + h) * 32 + lt) * 8) * 512;
  {
    int lane = t & 63, g = lane >> 4, li = lane & 15;
#pragma unroll
    for (int cc = 0; cc < 2; ++cc) {
      int c = (t >> 6) + cc * 4;
      int mt = c >> 1, p = c & 1;
      u16 u[8];
#pragma unroll
      for (int j = 0; j < 4; ++j) u[j] = T[mt * 16 + 4 * g + j][p * 32 + li];
#pragma unroll
      for (int j = 0; j < 4; ++j) u[4 + j] = T[mt * 16 + 4 * g + j][p * 32 + 16 + li];
      *(uint4*)&dst[c * 512 + lane * 8] = *(uint4*)u;
    }
  }
}

// ---------------- bf16 NT GEMM, 128x64 tile, double-buffered global_load_lds staging ----------------
template<int MODE>
__global__ __launch_bounds__(256) void gemm_nt(const u16* __restrict__ A,
                                               const u16* __restrict__ Bt,
                                               const float* __restrict__ bias,
                                               void* __restrict__ Cv,
                                               int M, int N, int K) {
  __shared__ u16 As[2][128][64];
  __shared__ u16 Bs[2][64][64];
  const int t = threadIdx.x;
  const int w = t >> 6, l = t & 63, g = l >> 4, li = l & 15;
  const int m0 = blockIdx.y * 128, n0 = blockIdx.x * 64;
  const int slotL = w * 64 + l;
  const int rA = slotL >> 3, cA = ((slotL & 7) * 8) ^ ((rA & 7) * 8);

  auto stageAB = [&](int buf, int kt) {
#pragma unroll
    for (int s = 0; s < 4; ++s) {
      int r = rA + s * 32;
      gload_lds16(&A[(size_t)(m0 + r) * K + kt + cA], &As[buf][0][0] + (s * 256 + w * 64) * 8);
    }
#pragma unroll
    for (int s = 0; s < 2; ++s) {
      int r = rA + s * 32;
      gload_lds16(&Bt[(size_t)(n0 + r) * K + kt + cA], &Bs[buf][0][0] + (s * 256 + w * 64) * 8);
    }
  };

  f32x4 acc[2][4] = {};
  stageAB(0, 0);
  __syncthreads();
  int cur = 0;
  for (int kt = 0; kt < K; kt += 64) {
    if (kt + 64 < K) stageAB(cur ^ 1, kt + 64);
#pragma unroll
    for (int kk = 0; kk < 2; ++kk) {
      bf16x8 a[2], bfr[4];
#pragma unroll
      for (int mi = 0; mi < 2; ++mi) {
        int ra = w * 32 + mi * 16 + li;
        a[mi] = *(const bf16x8*)&As[cur][ra][(kk * 32 + g * 8) ^ ((ra & 7) << 3)];
      }
#pragma unroll
      for (int ni = 0; ni < 4; ++ni) {
        int rb = ni * 16 + li;
        bfr[ni] = *(const bf16x8*)&Bs[cur][rb][(kk * 32 + g * 8) ^ ((rb & 7) << 3)];
      }
#pragma unroll
      for (int mi = 0; mi < 2; ++mi)
#pragma unroll
        for (int ni = 0; ni < 4; ++ni)
          acc[mi][ni] = mfma32(a[mi], bfr[ni], acc[mi][ni]);
    }
    __syncthreads();
    cur ^= 1;
  }
#pragma unroll
  for (int mi = 0; mi < 2; ++mi)
#pragma unroll
    for (int ni = 0; ni < 4; ++ni)
#pragma unroll
      for (int v = 0; v < 4; ++v) {
        int rr = m0 + w * 32 + mi * 16 + g * 4 + v;
        int cc = n0 + ni * 16 + li;
        float val = acc[mi][ni][v] + bias[cc];
        if (MODE == 1) {
          ((float*)Cv)[(size_t)rr * N + cc] = val;
        } else {
          // Qfrag[b][h][qt][c=n*2+kk][lane(gp,liq)][8]
          int b = rr >> 11, q = rr & 2047;
          int qt = q >> 5, n = (q >> 4) & 1, liq = q & 15;
          int h = (cc >> 6) & 15, kk2 = (cc >> 5) & 1, gp = (cc >> 3) & 3, j = cc & 7;
          size_t base = ((((size_t)b * HEADS + h) * 64 + qt) * 4 + n * 2 + kk2) * 512;
          ((u16*)Cv)[base + (size_t)(gp * 16 + liq) * 8 + j] = f2b(val);
        }
      }
}

// ---------------- attn_pv: 32 q-rows/wave; intra-wave mt software pipeline ----------------
// db layout: [z*HEADS+h][q] = -log2(denominator)  (consumed by amean as exp2 bias)
template<int MASKED>
static __device__ __forceinline__ void attn_pv_body(int z, int h, int qt, int w, int l,
                                                    const u16* __restrict__ Qfrag,
                                                    const u16* __restrict__ Kfrag,
                                                    const u16* __restrict__ Vfrag,
                                                    const unsigned* __restrict__ mbits,
                                                    u16* __restrict__ out01,
                                                    float* __restrict__ db,
                                                    u16* __restrict__ KV) {
  const int g = l >> 4, li = l & 15;
  const int b = z & 1;
  const u16* kfh = Kfrag + (size_t)(z * HEADS + h) * (32 * 8 * 512);
  const u16* vfh = Vfrag + (size_t)(z * HEADS + h) * (32 * 8 * 512);
  const u16* qfh = Qfrag + (((size_t)(b * HEADS + h) * 64 + qt) * 4) * 512;

  bf16x8 qf[2][2];
#pragma unroll
  for (int n = 0; n < 2; ++n)
#pragma unroll
    for (int kk = 0; kk < 2; ++kk)
      qf[n][kk] = *(const bf16x8*)&qfh[(n * 2 + kk) * 512 + l * 8];

  const unsigned* mrow0 = MASKED ? mbits + (size_t)(qt * 32 + li) * (LLL / 32) : nullptr;
  const unsigned* mrow1 = MASKED ? mrow0 + 16 * (LLL / 32) : nullptr;
  const int shb = 4 * g;
  const s16x4 ones = {(short)0x3F80, (short)0x3F80, (short)0x3F80, (short)0x3F80};

  auto stage = [&](int buf, int lt) {
    const u16* kfl = kfh + (size_t)lt * 4096;
    const u16* vfl = vfh + (size_t)lt * 4096;
#pragma unroll
    for (int i2 = 0; i2 < 2; ++i2) {
      int f = w * 2 + i2;
      const u16* gsrc = (f < 8 ? kfl + f * 512 : vfl + (f - 8) * 512) + l * 8;
      gload_lds16(gsrc, (char*)KV + buf * 16384 + f * 1024);
    }
  };

  f32x4 dacc[2] = {};     // denominator per n-half, on the MATRIX pipe (A = ones)
  f32x4 oacc[4][2] = {};  // [dt][n], unnormalized

  stage(0, 0);
  __syncthreads();
  int cur = 0;
  for (int lt = 0; lt < 32; ++lt) {
    if (lt + 1 < 32) stage(cur ^ 1, lt + 1);  // prefetch flies under compute
    unsigned mw[2][2];
    if (MASKED) {
      mw[0][0] = mrow0[lt * 2]; mw[0][1] = mrow0[lt * 2 + 1];
      mw[1][0] = mrow1[lt * 2]; mw[1][1] = mrow1[lt * 2 + 1];
    }
    const u16* Ks = KV + cur * 8192;
    const u16* Vs = Ks + 4096;

    auto qk = [&](f32x4 (&s)[2], int mt) {
      bf16x8 k0 = *(const bf16x8*)&Ks[(mt * 2 + 0) * 512 + l * 8];
      bf16x8 k1 = *(const bf16x8*)&Ks[(mt * 2 + 1) * 512 + l * 8];
      f32x4 zz = {};
      __builtin_amdgcn_s_setprio(1);
      s[0] = mfma32(k0, qf[0][0], zz);
      s[0] = mfma32(k1, qf[0][1], s[0]);
      s[1] = mfma32(k0, qf[1][0], zz);
      s[1] = mfma32(k1, qf[1][1], s[1]);
      __builtin_amdgcn_s_setprio(0);
    };
    // softmax + PV for tile mt, consuming s; QK(mt+1) already issued -> overlaps this VALU
    auto sm_pv = [&](f32x4 (&s)[2], int mt) {
      s16x4 wpk[2];
#pragma unroll
      for (int n = 0; n < 2; ++n) {
        unsigned mm = MASKED ? (mw[n][mt >> 1] >> ((mt & 1) * 16 + shb)) : 0u;
        f32x4 ev;
#pragma unroll
        for (int v = 0; v < 4; ++v) {
          float e = __builtin_amdgcn_exp2f(s[n][v]);    // K prescaled: zero prep
          if (MASKED) {
            int spread = ((int)(mm << (31 - v))) >> 31; // all-ones if keep
            e = __uint_as_float(__float_as_uint(e) & (unsigned)spread);
          }
          ev[v] = e;
        }
        bf16x4v wb = __builtin_convertvector(ev, bf16x4v);
        wpk[n] = __builtin_bit_cast(s16x4, wb);
      }
      __builtin_amdgcn_s_setprio(1);
      dacc[0] = mfma16(ones, wpk[0], dacc[0]);
      dacc[1] = mfma16(ones, wpk[1], dacc[1]);
#pragma unroll
      for (int p = 0; p < 2; ++p) {
        s16x8 vf = *(const s16x8*)&Vs[(mt * 2 + p) * 512 + l * 8];
        s16x4 lo = __builtin_shufflevector(vf, vf, 0, 1, 2, 3);
        s16x4 hi = __builtin_shufflevector(vf, vf, 4, 5, 6, 7);
#pragma unroll
        for (int n = 0; n < 2; ++n) {
          oacc[2 * p + 0][n] = mfma16(lo, wpk[n], oacc[2 * p + 0][n]);
          oacc[2 * p + 1][n] = mfma16(hi, wpk[n], oacc[2 * p + 1][n]);
        }
      }
      __builtin_amdgcn_s_setprio(0);
    };

    f32x4 sA[2], sB[2];
    qk(sA, 0);
    qk(sB, 1); sm_pv(sA, 0);   // QK(1) in flight while softmax/PV(0) runs
    qk(sA, 2); sm_pv(sB, 1);
    qk(sB, 3); sm_pv(sA, 2);
    sm_pv(sB, 3);
    __syncthreads();
    cur ^= 1;
  }
  float dinv[2];
  dinv[0] = 1.0f / dacc[0][0];
  dinv[1] = 1.0f / dacc[1][0];
  if (l < 16) {
    db[(size_t)(z * HEADS + h) * SS + qt * 32 + li]      = -__log2f(dacc[0][0]);
    db[(size_t)(z * HEADS + h) * SS + qt * 32 + 16 + li] = -__log2f(dacc[1][0]);
  }
  u16* ob = out01 + (size_t)z * SS * DIM;
#pragma unroll
  for (int dt = 0; dt < 4; ++dt)
#pragma unroll
    for (int n = 0; n < 2; ++n) {
      f32x4 o = oacc[dt][n] * dinv[n];
      ushort4 us;
      us.x = f2b(o[0]); us.y = f2b(o[1]); us.z = f2b(o[2]); us.w = f2b(o[3]);
      *(ushort4*)&ob[((size_t)(qt * 32 + n * 16 + li)) * DIM + h * HD + dt * 16 + 4 * g] = us;
    }
}

__global__ __launch_bounds__(512, 4) void attn_pv(const u16* __restrict__ Qfrag,
                                                  const u16* __restrict__ Kfrag,
                                                  const u16* __restrict__ Vfrag,
                                                  const unsigned* __restrict__ mbits,
                                                  u16* __restrict__ out01,
                                                  float* __restrict__ db) {
  __shared__ u16 KV[2][8192];  // 32 KB double-buffered K+V tile
  // z-balanced XCD map (512 blocks): each XCD gets zh spanning all z
  const int flat = blockIdx.x;
  const int xcd = flat & 7, i = flat >> 3;     // i in [0,64)
  const int k = i >> 3, qg = i & 7;            // k in [0,8)
  const int zh = xcd + 8 * k;                  // [0,64)
  const int z = zh >> 4, h = zh & 15;
  const int w = threadIdx.x >> 6, l = threadIdx.x & 63;
  const int qt = qg * 8 + w;                   // [0,64)
  if (z < 2) attn_pv_body<1>(z, h, qt, w, l, Qfrag, Kfrag, Vfrag, mbits, out01, db, &KV[0][0]);
  else       attn_pv_body<0>(z, h, qt, w, l, Qfrag, Kfrag, Vfrag, mbits, out01, db, &KV[0][0]);
}

// ---------------- amean: 32 q-rows/wave, LDS-staged K (double-buffered per head) ----------------
template<int MASKED>
static __device__ __forceinline__ void amean_body(int z, int qt, int lt, int w, int l,
                                                  const u16* __restrict__ Qfrag,
                                                  const u16* __restrict__ Kfrag,
                                                  const unsigned* __restrict__ mbits,
                                                  const float* __restrict__ db,
                                                  float* __restrict__ aout,
                                                  u16* __restrict__ KS) {
  const int g = l >> 4, li = l & 15;
  const int b = z & 1;

  unsigned mw[2][2];
  if (MASKED) {
    const unsigned* m0 = mbits + (size_t)(qt * 32 + li) * (LLL / 32) + lt * 2;
    const unsigned* m1 = m0 + 16 * (LLL / 32);
    mw[0][0] = m0[0]; mw[0][1] = m0[1];
    mw[1][0] = m1[0]; mw[1][1] = m1[1];
  }
  const u16* qf_base = Qfrag + (((size_t)(b * HEADS) * 64 + qt) * 4) * 512 + l * 8;
  const float* dbb = db + (size_t)(z * HEADS) * SS + qt * 32 + li;

  auto stageK = [&](int buf, int h) {
    const u16* kfh = Kfrag + ((((size_t)(z * HEADS + h)) * 32 + lt) * 8) * 512;
#pragma unroll
    for (int i2 = 0; i2 < 2; ++i2) {
      int f = w * 2 + i2;
      gload_lds16(kfh + f * 512 + l * 8, (char*)KS + buf * 8192 + f * 1024);
    }
  };

  f32x4 asum[4][2] = {};
  stageK(0, 0);
  __syncthreads();
#pragma unroll 2
  for (int h = 0; h < HEADS; ++h) {
    if (h + 1 < HEADS) stageK((h + 1) & 1, h + 1);   // prefetch under compute
    float l2[2];
    l2[0] = dbb[(size_t)h * SS];                     // -log2(denom), precomputed
    l2[1] = dbb[(size_t)h * SS + 16];
    bf16x8 qf[2][2];
#pragma unroll
    for (int n = 0; n < 2; ++n)
#pragma unroll
      for (int kk = 0; kk < 2; ++kk)
        qf[n][kk] = *(const bf16x8*)&qf_base[(size_t)h * (64 * 4 * 512) + (n * 2 + kk) * 512];
    const u16* Ks = KS + (h & 1) * 4096;
#pragma unroll
    for (int mt = 0; mt < 4; ++mt) {
      bf16x8 k0 = *(const bf16x8*)&Ks[(mt * 2 + 0) * 512 + l * 8];
      bf16x8 k1 = *(const bf16x8*)&Ks[(mt * 2 + 1) * 512 + l * 8];
#pragma unroll
      for (int n = 0; n < 2; ++n) {
        f32x4 s = {};
        s = mfma32(k0, qf[n][0], s);
        s = mfma32(k1, qf[n][1], s);
        unsigned mm = MASKED ? (mw[n][mt >> 1] >> ((mt & 1) * 16 + 4 * g)) : 0u;
#pragma unroll
        for (int v = 0; v < 4; ++v) {
          float e = __builtin_amdgcn_exp2f(s[v] + l2[n]);
          if (MASKED) {
            int spread = ((int)(mm << (31 - v))) >> 31;  // all-ones if keep
            e = __uint_as_float(__float_as_uint(e) & (unsigned)spread);
          }
          asum[mt][n][v] += e;
        }
      }
    }
    __syncthreads();  // waves done reading Ks[h&1]; h+1 loads drained
  }
  float* ab = aout + (size_t)z * SS * LLL;
#pragma unroll
  for (int mt = 0; mt < 4; ++mt)
#pragma unroll
    for (int n = 0; n < 2; ++n) {
      f32x4 o = asum[mt][n] * 0.0625f;
      f32x4* dst = (f32x4*)&ab[(size_t)(qt * 32 + n * 16 + li) * LLL + lt * 64 + mt * 16 + 4 * g];
      __builtin_nontemporal_store(o, dst);
    }
}

__global__ __launch_bounds__(256, 4) void amean(const u16* __restrict__ Qfrag,
                                                const u16* __restrict__ Kfrag,
                                                const unsigned* __restrict__ mbits,
                                                const float* __restrict__ db,
                                                float* __restrict__ aout) {
  __shared__ u16 KS[2][4096];  // 16 KB double-buffered K tile
  // z-balanced XCD map over (z,lt) groups (2048 blocks)
  const int flat = blockIdx.x;
  const int xcd = flat & 7, i = flat >> 3;     // i in [0,256)
  const int k = i >> 4, qg = i & 15;           // k in [0,16)
  const int zlt = xcd + 8 * k;                 // [0,128)
  const int z = zlt >> 5, lt = zlt & 31;
  const int w = threadIdx.x >> 6, l = threadIdx.x & 63;
  const int qt = qg * 4 + w;                   // [0,64)
  if (z < 2) amean_body<1>(z, qt, lt, w, l, Qfrag, Kfrag, mbits, db, aout, &KS[0][0]);
  else       amean_body<0>(z, qt, lt, w, l, Qfrag, Kfrag, mbits, db, aout, &KS[0][0]);
}

// ---------------- gated merge ----------------
__global__ void merge_kernel(const u16* __restrict__ o01,
                             const float* __restrict__ gate,
                             u16* __restrict__ merged) {
  int i = blockIdx.x * blockDim.x + threadIdx.x;
  float gv = gate[0];
  float g = 1.0f / (1.0f + __builtin_amdgcn_exp2f(-gv * LOG2E));
  const size_t n = (size_t)BB * SS * DIM;
  ushort4 a = ((const ushort4*)o01)[i];
  ushort4 c = ((const ushort4*)(o01 + n))[i];
  ushort4 o;
  o.x = f2b(g * b2f(a.x) + (1.f - g) * b2f(c.x));
  o.y = f2b(g * b2f(a.y) + (1.f - g) * b2f(c.y));
  o.z = f2b(g * b2f(a.z) + (1.f - g) * b2f(c.z));
  o.w = f2b(g * b2f(a.w) + (1.f - g) * b2f(c.w));
  ((ushort4*)merged)[i] = o;
}

extern "C" void kernel_launch(void* const* d_in, const int* in_sizes, int n_in,
                              void* d_out, int out_size, void* d_ws, size_t ws_size,
                              hipStream_t stream) {
  const float* query = (const float*)d_in[0];
  const float* k0f   = (const float*)d_in[1];
  const float* v0f   = (const float*)d_in[2];
  const float* k1f   = (const float*)d_in[3];
  const float* v1f   = (const float*)d_in[4];
  const int*   mask  = (const int*)d_in[5];
  const float* Wqf   = (const float*)d_in[6];
  const float* bq    = (const float*)d_in[7];
  const float* Wof   = (const float*)d_in[8];
  const float* bo    = (const float*)d_in[9];
  const float* gate  = (const float*)d_in[10];
  float* out = (float*)d_out;

  const size_t nQ = (size_t)BB * SS * DIM;
  const size_t nW = (size_t)DIM * DIM;

  char* ws = (char*)d_ws;
  size_t off = 0;
  auto alloc = [&](size_t bytes) -> char* {
    char* p = ws + off;
    off += (bytes + 255) & ~(size_t)255;
    return p;
  };
  u16*      queryb  = (u16*)alloc(nQ * 2);             // reused as mergedb later
  u16*      wqb     = (u16*)alloc(nW * 2);
  u16*      wob     = (u16*)alloc(nW * 2);
  u16*      Qfrag   = (u16*)alloc(nQ * 2);             // [b][h][qt][c][lane][8]
  u16*      Kfrag   = (u16*)alloc((size_t)2 * nQ * 2); // [z][h][lt][c][lane][8] (prescaled)
  u16*      Vfrag   = (u16*)alloc((size_t)2 * nQ * 2);
  unsigned* mbits   = (unsigned*)alloc((size_t)SS * (LLL / 32) * 4);
  float*    db      = (float*)alloc((size_t)4 * HEADS * SS * 4);  // -log2(denom) per [z][h][q]
  u16*      out01   = (u16*)alloc((size_t)2 * nQ * 2);
  u16*      mergedb = queryb;  // queryb dead after q-proj gemm

  {
    int na4 = (int)(nQ / 4), nb4 = (int)(nW / 4);
    int tot = na4 + 2 * nb4;
    cvt3<<<dim3(tot / 256), dim3(256), 0, stream>>>(query, Wqf, Wof, queryb, wqb, wob, na4, nb4);
  }

  mask_pack<<<dim3(SS * (LLL / 32) / 256), dim3(256), 0, stream>>>(mask, mbits);
  pack_k<<<dim3(LLL / 64 / 4, HEADS, 4), dim3(256), 0, stream>>>(k0f, k1f, Kfrag);
  pack_v<<<dim3(LLL / 64, HEADS, 4), dim3(256), 0, stream>>>(v0f, v1f, Vfrag);

  // q projection straight into fragment layout (128x64 tiles, double-buffered)
  gemm_nt<2><<<dim3(DIM / 64, (BB * SS) / 128), dim3(256), 0, stream>>>(
      queryb, wqb, bq, (void*)Qfrag, BB * SS, DIM, DIM);

  // fused single-pass attention: 32 rows/wave, mt-pipelined, double-buffered LDS staging
  attn_pv<<<dim3(512), dim3(512), 0, stream>>>(Qfrag, Kfrag, Vfrag, mbits, out01, db);

  // head-mean attention maps straight into d_out (LDS-staged K, 32 rows/wave)
  amean<<<dim3(2048), dim3(256), 0, stream>>>(Qfrag, Kfrag, mbits, db, out + nQ);

  merge_kernel<<<dim3((int)(nQ / 4 / 256)), dim3(256), 0, stream>>>(out01, gate, mergedb);

  gemm_nt<1><<<dim3(DIM / 64, (BB * SS) / 128), dim3(256), 0, stream>>>(
      mergedb, wob, bo, (void*)out, BB * SS, DIM, DIM);
}

// Round 15
// 207.812 us; speedup vs baseline: 4.1316x; 1.0556x over previous
//
#include <hip/hip_runtime.h>

#define DIM   1024
#define HEADS 16
#define HD    64
#define BB    2
#define SS    2048
#define LLL   2048
#define LOG2E 1.4426950408889634f

typedef __bf16 bf16x8 __attribute__((ext_vector_type(8)));
typedef __bf16 bf16x4v __attribute__((ext_vector_type(4)));
typedef float  f32x4  __attribute__((ext_vector_type(4)));
typedef short  s16x4  __attribute__((ext_vector_type(4)));
typedef unsigned short u16;

static __device__ __forceinline__ u16 f2b(float x) {
  unsigned u = __float_as_uint(x);
  u += 0x7fffu + ((u >> 16) & 1u);
  return (u16)(u >> 16);
}
static __device__ __forceinline__ float b2f(u16 u) {
  return __uint_as_float(((unsigned)u) << 16);
}
static __device__ __forceinline__ f32x4 mfma32(bf16x8 a, bf16x8 b, f32x4 c) {
  return __builtin_amdgcn_mfma_f32_16x16x32_bf16(a, b, c, 0, 0, 0);
}

// async global->LDS, 16B/lane. LDS base must be WAVE-UNIFORM (HW adds lane*16).
static __device__ __forceinline__ void gload_lds16(const void* g, void* lds_uniform_base) {
#if __has_builtin(__builtin_amdgcn_global_load_lds)
  __builtin_amdgcn_global_load_lds(
      (const __attribute__((address_space(1))) unsigned int*)g,
      (__attribute__((address_space(3))) unsigned int*)lds_uniform_base, 16, 0, 0);
#else
  const int l = threadIdx.x & 63;
  ((uint4*)lds_uniform_base)[l] = ((const uint4*)g)[0];
#endif
}

// ---------------- fused f32 -> bf16 convert for query/Wq/Wo ----------------
__global__ void cvt3(const float* __restrict__ a, const float* __restrict__ b,
                     const float* __restrict__ c, u16* __restrict__ da,
                     u16* __restrict__ db_, u16* __restrict__ dc, int na4, int nb4) {
  int i = blockIdx.x * blockDim.x + threadIdx.x;
  const float* s; u16* d; int j = i;
  if (j < na4) { s = a; d = da; }
  else if ((j -= na4) < nb4) { s = b; d = db_; }
  else { j -= nb4; s = c; d = dc; }
  float4 f = ((const float4*)s)[j];
  ushort4 o;
  o.x = f2b(f.x); o.y = f2b(f.y); o.z = f2b(f.z); o.w = f2b(f.w);
  ((ushort4*)d)[j] = o;
}

// ---------------- mask -> bitmask ----------------
__global__ void mask_pack(const int* __restrict__ mask, unsigned* __restrict__ mbits) {
  int i = blockIdx.x * blockDim.x + threadIdx.x;
  const int* src = mask + (size_t)i * 32;
  unsigned bm = 0;
#pragma unroll
  for (int j = 0; j < 8; ++j) {
    int4 m = ((const int4*)src)[j];
    bm |= (m.x != 0 ? 1u : 0u) << (j * 4 + 0);
    bm |= (m.y != 0 ? 1u : 0u) << (j * 4 + 1);
    bm |= (m.z != 0 ? 1u : 0u) << (j * 4 + 2);
    bm |= (m.w != 0 ? 1u : 0u) << (j * 4 + 3);
  }
  mbits[i] = bm;
}

// ---------------- K (f32) -> fragment-packed bf16 tiles, PRESCALED by 0.125*log2(e) ----------------
__global__ __launch_bounds__(256) void pack_k(const float* __restrict__ k0,
                                              const float* __restrict__ k1,
                                              u16* __restrict__ Kfrag) {
  const float SCK = 0.125f * LOG2E;
  const int w = threadIdx.x >> 6, l = threadIdx.x & 63, g = l >> 4, li = l & 15;
  const int lt = blockIdx.x * 4 + w, h = blockIdx.y, z = blockIdx.z;
  const int lay = z >> 1, b = z & 1;
  const float* src = (lay ? k1 : k0) + (size_t)b * LLL * DIM;
  u16* dst = Kfrag + ((((size_t)z * HEADS + h) * 32 + lt) * 8) * 512;
#pragma unroll
  for (int c = 0; c < 8; ++c) {
    int mt = c >> 1, kk = c & 1;
    const float* p = &src[(size_t)(lt * 64 + mt * 16 + li) * DIM + h * 64 + kk * 32 + g * 8];
    float4 f0 = *(const float4*)p;
    float4 f1 = *(const float4*)(p + 4);
    u16 u[8] = {f2b(f0.x * SCK), f2b(f0.y * SCK), f2b(f0.z * SCK), f2b(f0.w * SCK),
                f2b(f1.x * SCK), f2b(f1.y * SCK), f2b(f1.z * SCK), f2b(f1.w * SCK)};
    *(uint4*)&dst[c * 512 + l * 8] = *(uint4*)u;
  }
}

// ---------------- V (f32) -> K=32-PV fragment layout ----------------
// Vfrag[z][h][lt][c=pair*4+dt][lane(g,li)][8]:
//   j<4 : V^T[dt*16+li][lt*64 + pair*32 +      4g + j]
//   j>=4: V^T[dt*16+li][lt*64 + pair*32 + 16 + 4g + (j-4)]
// (permuted k-axis; matches wpk8 = concat(wpk_mt(2*pair), wpk_mt(2*pair+1)))
__global__ __launch_bounds__(256) void pack_v(const float* __restrict__ v0,
                                              const float* __restrict__ v1,
                                              u16* __restrict__ Vfrag) {
  __shared__ u16 T[64][72];  // T[l][d]
  const int lt = blockIdx.x, h = blockIdx.y, z = blockIdx.z;
  const int lay = z >> 1, b = z & 1;
  const float* v = (lay ? v1 : v0) + (size_t)b * LLL * DIM;
  const int t = threadIdx.x;
  {
    int r = t >> 2, c16 = (t & 3) * 16;
    const float* src = &v[(size_t)(lt * 64 + r) * DIM + h * 64 + c16];
#pragma unroll
    for (int i = 0; i < 4; ++i) {
      float4 f = *(const float4*)&src[i * 4];
      T[r][c16 + i * 4 + 0] = f2b(f.x);
      T[r][c16 + i * 4 + 1] = f2b(f.y);
      T[r][c16 + i * 4 + 2] = f2b(f.z);
      T[r][c16 + i * 4 + 3] = f2b(f.w);
    }
  }
  __syncthreads();
  u16* dst = Vfrag + ((((size_t)z * HEADS + h) * 32 + lt) * 8) * 512;
  {
    int lane = t & 63, g = lane >> 4, li = lane & 15;
#pragma unroll
    for (int cc = 0; cc < 2; ++cc) {
      int c = (t >> 6) + cc * 4;           // 0..7
      int pair = c >> 2, dt = c & 3;
      u16 u[8];
#pragma unroll
      for (int j = 0; j < 4; ++j) u[j]     = T[pair * 32 + 4 * g + j][dt * 16 + li];
#pragma unroll
      for (int j = 0; j < 4; ++j) u[4 + j] = T[pair * 32 + 16 + 4 * g + j][dt * 16 + li];
      *(uint4*)&dst[c * 512 + lane * 8] = *(uint4*)u;
    }
  }
}

// ---------------- bf16 NT GEMM, 128x64 tile, double-buffered global_load_lds staging ----------------
template<int MODE>
__global__ __launch_bounds__(256) void gemm_nt(const u16* __restrict__ A,
                                               const u16* __restrict__ Bt,
                                               const float* __restrict__ bias,
                                               void* __restrict__ Cv,
                                               int M, int N, int K) {
  __shared__ u16 As[2][128][64];
  __shared__ u16 Bs[2][64][64];
  const int t = threadIdx.x;
  const int w = t >> 6, l = t & 63, g = l >> 4, li = l & 15;
  const int m0 = blockIdx.y * 128, n0 = blockIdx.x * 64;
  const int slotL = w * 64 + l;
  const int rA = slotL >> 3, cA = ((slotL & 7) * 8) ^ ((rA & 7) * 8);

  auto stageAB = [&](int buf, int kt) {
#pragma unroll
    for (int s = 0; s < 4; ++s) {
      int r = rA + s * 32;
      gload_lds16(&A[(size_t)(m0 + r) * K + kt + cA], &As[buf][0][0] + (s * 256 + w * 64) * 8);
    }
#pragma unroll
    for (int s = 0; s < 2; ++s) {
      int r = rA + s * 32;
      gload_lds16(&Bt[(size_t)(n0 + r) * K + kt + cA], &Bs[buf][0][0] + (s * 256 + w * 64) * 8);
    }
  };

  f32x4 acc[2][4] = {};
  stageAB(0, 0);
  __syncthreads();
  int cur = 0;
  for (int kt = 0; kt < K; kt += 64) {
    if (kt + 64 < K) stageAB(cur ^ 1, kt + 64);
#pragma unroll
    for (int kk = 0; kk < 2; ++kk) {
      bf16x8 a[2], bfr[4];
#pragma unroll
      for (int mi = 0; mi < 2; ++mi) {
        int ra = w * 32 + mi * 16 + li;
        a[mi] = *(const bf16x8*)&As[cur][ra][(kk * 32 + g * 8) ^ ((ra & 7) << 3)];
      }
#pragma unroll
      for (int ni = 0; ni < 4; ++ni) {
        int rb = ni * 16 + li;
        bfr[ni] = *(const bf16x8*)&Bs[cur][rb][(kk * 32 + g * 8) ^ ((rb & 7) << 3)];
      }
#pragma unroll
      for (int mi = 0; mi < 2; ++mi)
#pragma unroll
        for (int ni = 0; ni < 4; ++ni)
          acc[mi][ni] = mfma32(a[mi], bfr[ni], acc[mi][ni]);
    }
    __syncthreads();
    cur ^= 1;
  }
#pragma unroll
  for (int mi = 0; mi < 2; ++mi)
#pragma unroll
    for (int ni = 0; ni < 4; ++ni)
#pragma unroll
      for (int v = 0; v < 4; ++v) {
        int rr = m0 + w * 32 + mi * 16 + g * 4 + v;
        int cc = n0 + ni * 16 + li;
        float val = acc[mi][ni][v] + bias[cc];
        if (MODE == 1) {
          ((float*)Cv)[(size_t)rr * N + cc] = val;
        } else {
          // Qfrag[b][h][qt][c=n*2+kk][lane(gp,liq)][8]
          int b = rr >> 11, q = rr & 2047;
          int qt = q >> 5, n = (q >> 4) & 1, liq = q & 15;
          int h = (cc >> 6) & 15, kk2 = (cc >> 5) & 1, gp = (cc >> 3) & 3, j = cc & 7;
          size_t base = ((((size_t)b * HEADS + h) * 64 + qt) * 4 + n * 2 + kk2) * 512;
          ((u16*)Cv)[base + (size_t)(gp * 16 + liq) * 8 + j] = f2b(val);
        }
      }
}

// ---------------- attn_pv: 32 q-rows/wave; all-K=32 MFMA (QK + PV + denominator) ----------------
// db layout: [z*HEADS+h][q] = -log2(denominator)  (consumed by amean as exp2 bias)
template<int MASKED>
static __device__ __forceinline__ void attn_pv_body(int z, int h, int qt, int w, int l,
                                                    const u16* __restrict__ Qfrag,
                                                    const u16* __restrict__ Kfrag,
                                                    const u16* __restrict__ Vfrag,
                                                    const unsigned* __restrict__ mbits,
                                                    u16* __restrict__ out01,
                                                    float* __restrict__ db,
                                                    u16* __restrict__ KV) {
  const int g = l >> 4, li = l & 15;
  const int b = z & 1;
  const u16* kfh = Kfrag + (size_t)(z * HEADS + h) * (32 * 8 * 512);
  const u16* vfh = Vfrag + (size_t)(z * HEADS + h) * (32 * 8 * 512);
  const u16* qfh = Qfrag + (((size_t)(b * HEADS + h) * 64 + qt) * 4) * 512;

  bf16x8 qf[2][2];
#pragma unroll
  for (int n = 0; n < 2; ++n)
#pragma unroll
    for (int kk = 0; kk < 2; ++kk)
      qf[n][kk] = *(const bf16x8*)&qfh[(n * 2 + kk) * 512 + l * 8];

  const unsigned* mrow0 = MASKED ? mbits + (size_t)(qt * 32 + li) * (LLL / 32) : nullptr;
  const unsigned* mrow1 = MASKED ? mrow0 + 16 * (LLL / 32) : nullptr;
  const int shb = 4 * g;
  bf16x8 ones8;
#pragma unroll
  for (int j = 0; j < 8; ++j) ones8[j] = __builtin_bit_cast(__bf16, (u16)0x3F80);

  auto stage = [&](int buf, int lt) {
    const u16* kfl = kfh + (size_t)lt * 4096;
    const u16* vfl = vfh + (size_t)lt * 4096;
#pragma unroll
    for (int i2 = 0; i2 < 2; ++i2) {
      int f = w * 2 + i2;
      const u16* gsrc = (f < 8 ? kfl + f * 512 : vfl + (f - 8) * 512) + l * 8;
      gload_lds16(gsrc, (char*)KV + buf * 16384 + f * 1024);
    }
  };

  f32x4 dacc[2] = {};     // denominator per n-half (matrix pipe, A = ones)
  f32x4 oacc[4][2] = {};  // [dt][n], unnormalized

  stage(0, 0);
  __syncthreads();
  int cur = 0;
  for (int lt = 0; lt < 32; ++lt) {
    if (lt + 1 < 32) stage(cur ^ 1, lt + 1);  // prefetch flies under compute
    unsigned mw[2][2];
    if (MASKED) {
      mw[0][0] = mrow0[lt * 2]; mw[0][1] = mrow0[lt * 2 + 1];
      mw[1][0] = mrow1[lt * 2]; mw[1][1] = mrow1[lt * 2 + 1];
    }
    const u16* Ks = KV + cur * 8192;
    const u16* Vs = Ks + 4096;

    auto qk = [&](f32x4 (&s)[2], int mt) {
      bf16x8 k0 = *(const bf16x8*)&Ks[(mt * 2 + 0) * 512 + l * 8];
      bf16x8 k1 = *(const bf16x8*)&Ks[(mt * 2 + 1) * 512 + l * 8];
      f32x4 zz = {};
      __builtin_amdgcn_s_setprio(1);
      s[0] = mfma32(k0, qf[0][0], zz);
      s[0] = mfma32(k1, qf[0][1], s[0]);
      s[1] = mfma32(k0, qf[1][0], zz);
      s[1] = mfma32(k1, qf[1][1], s[1]);
      __builtin_amdgcn_s_setprio(0);
    };
    auto sm = [&](f32x4 (&s)[2], int mt, s16x4 (&wpk)[2]) {
#pragma unroll
      for (int n = 0; n < 2; ++n) {
        unsigned mm = MASKED ? (mw[n][mt >> 1] >> ((mt & 1) * 16 + shb)) : 0u;
        f32x4 ev;
#pragma unroll
        for (int v = 0; v < 4; ++v) {
          float e = __builtin_amdgcn_exp2f(s[n][v]);    // K prescaled: zero prep
          if (MASKED) {
            int spread = ((int)(mm << (31 - v))) >> 31; // all-ones if keep
            e = __uint_as_float(__float_as_uint(e) & (unsigned)spread);
          }
          ev[v] = e;
        }
        bf16x4v wb = __builtin_convertvector(ev, bf16x4v);
        wpk[n] = __builtin_bit_cast(s16x4, wb);
      }
    };
    // PV + denominator for an mt pair, K=32 (permuted-k V layout)
    auto pv_pair = [&](s16x4 (&w0)[2], s16x4 (&w1)[2], int pair) {
      bf16x8 w8[2];
#pragma unroll
      for (int n = 0; n < 2; ++n) {
        bf16x4v a0 = __builtin_bit_cast(bf16x4v, w0[n]);
        bf16x4v a1 = __builtin_bit_cast(bf16x4v, w1[n]);
        w8[n] = __builtin_shufflevector(a0, a1, 0, 1, 2, 3, 4, 5, 6, 7);
      }
      __builtin_amdgcn_s_setprio(1);
      dacc[0] = mfma32(ones8, w8[0], dacc[0]);
      dacc[1] = mfma32(ones8, w8[1], dacc[1]);
#pragma unroll
      for (int dt = 0; dt < 4; ++dt) {
        bf16x8 vf = *(const bf16x8*)&Vs[(pair * 4 + dt) * 512 + l * 8];
#pragma unroll
        for (int n = 0; n < 2; ++n)
          oacc[dt][n] = mfma32(vf, w8[n], oacc[dt][n]);
      }
      __builtin_amdgcn_s_setprio(0);
    };

    f32x4 sA[2], sB[2];
    s16x4 wA[2], wB[2];
    qk(sA, 0); qk(sB, 1);
    sm(sA, 0, wA);
    qk(sA, 2);            // next pair's first QK overlaps sm/PV of pair 0
    sm(sB, 1, wB);
    pv_pair(wA, wB, 0);
    qk(sB, 3);
    sm(sA, 2, wA);
    sm(sB, 3, wB);
    pv_pair(wA, wB, 1);
    __syncthreads();
    cur ^= 1;
  }
  float dinv[2];
  dinv[0] = 1.0f / dacc[0][0];
  dinv[1] = 1.0f / dacc[1][0];
  if (l < 16) {
    db[(size_t)(z * HEADS + h) * SS + qt * 32 + li]      = -__log2f(dacc[0][0]);
    db[(size_t)(z * HEADS + h) * SS + qt * 32 + 16 + li] = -__log2f(dacc[1][0]);
  }
  u16* ob = out01 + (size_t)z * SS * DIM;
#pragma unroll
  for (int dt = 0; dt < 4; ++dt)
#pragma unroll
    for (int n = 0; n < 2; ++n) {
      f32x4 o = oacc[dt][n] * dinv[n];
      ushort4 us;
      us.x = f2b(o[0]); us.y = f2b(o[1]); us.z = f2b(o[2]); us.w = f2b(o[3]);
      *(ushort4*)&ob[((size_t)(qt * 32 + n * 16 + li)) * DIM + h * HD + dt * 16 + 4 * g] = us;
    }
}

__global__ __launch_bounds__(512, 4) void attn_pv(const u16* __restrict__ Qfrag,
                                                  const u16* __restrict__ Kfrag,
                                                  const u16* __restrict__ Vfrag,
                                                  const unsigned* __restrict__ mbits,
                                                  u16* __restrict__ out01,
                                                  float* __restrict__ db) {
  __shared__ u16 KV[2][8192];  // 32 KB double-buffered K+V tile
  // z-balanced XCD map (512 blocks): each XCD gets zh spanning all z
  const int flat = blockIdx.x;
  const int xcd = flat & 7, i = flat >> 3;     // i in [0,64)
  const int k = i >> 3, qg = i & 7;            // k in [0,8)
  const int zh = xcd + 8 * k;                  // [0,64)
  const int z = zh >> 4, h = zh & 15;
  const int w = threadIdx.x >> 6, l = threadIdx.x & 63;
  const int qt = qg * 8 + w;                   // [0,64)
  if (z < 2) attn_pv_body<1>(z, h, qt, w, l, Qfrag, Kfrag, Vfrag, mbits, out01, db, &KV[0][0]);
  else       attn_pv_body<0>(z, h, qt, w, l, Qfrag, Kfrag, Vfrag, mbits, out01, db, &KV[0][0]);
}

// ---------------- amean: 32 q-rows/wave, LDS-staged K (double-buffered per head) ----------------
template<int MASKED>
static __device__ __forceinline__ void amean_body(int z, int qt, int lt, int w, int l,
                                                  const u16* __restrict__ Qfrag,
                                                  const u16* __restrict__ Kfrag,
                                                  const unsigned* __restrict__ mbits,
                                                  const float* __restrict__ db,
                                                  float* __restrict__ aout,
                                                  u16* __restrict__ KS) {
  const int g = l >> 4, li = l & 15;
  const int b = z & 1;

  unsigned mw[2][2];
  if (MASKED) {
    const unsigned* m0 = mbits + (size_t)(qt * 32 + li) * (LLL / 32) + lt * 2;
    const unsigned* m1 = m0 + 16 * (LLL / 32);
    mw[0][0] = m0[0]; mw[0][1] = m0[1];
    mw[1][0] = m1[0]; mw[1][1] = m1[1];
  }
  const u16* qf_base = Qfrag + (((size_t)(b * HEADS) * 64 + qt) * 4) * 512 + l * 8;
  const float* dbb = db + (size_t)(z * HEADS) * SS + qt * 32 + li;

  auto stageK = [&](int buf, int h) {
    const u16* kfh = Kfrag + ((((size_t)(z * HEADS + h)) * 32 + lt) * 8) * 512;
#pragma unroll
    for (int i2 = 0; i2 < 2; ++i2) {
      int f = w * 2 + i2;
      gload_lds16(kfh + f * 512 + l * 8, (char*)KS + buf * 8192 + f * 1024);
    }
  };

  f32x4 asum[4][2] = {};
  stageK(0, 0);
  __syncthreads();
#pragma unroll 2
  for (int h = 0; h < HEADS; ++h) {
    if (h + 1 < HEADS) stageK((h + 1) & 1, h + 1);   // prefetch under compute
    float l2[2];
    l2[0] = dbb[(size_t)h * SS];                     // -log2(denom), precomputed
    l2[1] = dbb[(size_t)h * SS + 16];
    bf16x8 qf[2][2];
#pragma unroll
    for (int n = 0; n < 2; ++n)
#pragma unroll
      for (int kk = 0; kk < 2; ++kk)
        qf[n][kk] = *(const bf16x8*)&qf_base[(size_t)h * (64 * 4 * 512) + (n * 2 + kk) * 512];
    const u16* Ks = KS + (h & 1) * 4096;
#pragma unroll
    for (int mt = 0; mt < 4; ++mt) {
      bf16x8 k0 = *(const bf16x8*)&Ks[(mt * 2 + 0) * 512 + l * 8];
      bf16x8 k1 = *(const bf16x8*)&Ks[(mt * 2 + 1) * 512 + l * 8];
#pragma unroll
      for (int n = 0; n < 2; ++n) {
        f32x4 s = {};
        s = mfma32(k0, qf[n][0], s);
        s = mfma32(k1, qf[n][1], s);
        unsigned mm = MASKED ? (mw[n][mt >> 1] >> ((mt & 1) * 16 + 4 * g)) : 0u;
#pragma unroll
        for (int v = 0; v < 4; ++v) {
          float e = __builtin_amdgcn_exp2f(s[v] + l2[n]);
          if (MASKED) {
            int spread = ((int)(mm << (31 - v))) >> 31;  // all-ones if keep
            e = __uint_as_float(__float_as_uint(e) & (unsigned)spread);
          }
          asum[mt][n][v] += e;
        }
      }
    }
    __syncthreads();  // waves done reading Ks[h&1]; h+1 loads drained
  }
  float* ab = aout + (size_t)z * SS * LLL;
#pragma unroll
  for (int mt = 0; mt < 4; ++mt)
#pragma unroll
    for (int n = 0; n < 2; ++n) {
      f32x4 o = asum[mt][n] * 0.0625f;
      f32x4* dst = (f32x4*)&ab[(size_t)(qt * 32 + n * 16 + li) * LLL + lt * 64 + mt * 16 + 4 * g];
      __builtin_nontemporal_store(o, dst);
    }
}

__global__ __launch_bounds__(256, 4) void amean(const u16* __restrict__ Qfrag,
                                                const u16* __restrict__ Kfrag,
                                                const unsigned* __restrict__ mbits,
                                                const float* __restrict__ db,
                                                float* __restrict__ aout) {
  __shared__ u16 KS[2][4096];  // 16 KB double-buffered K tile
  // z-balanced XCD map over (z,lt) groups (2048 blocks)
  const int flat = blockIdx.x;
  const int xcd = flat & 7, i = flat >> 3;     // i in [0,256)
  const int k = i >> 4, qg = i & 15;           // k in [0,16)
  const int zlt = xcd + 8 * k;                 // [0,128)
  const int z = zlt >> 5, lt = zlt & 31;
  const int w = threadIdx.x >> 6, l = threadIdx.x & 63;
  const int qt = qg * 4 + w;                   // [0,64)
  if (z < 2) amean_body<1>(z, qt, lt, w, l, Qfrag, Kfrag, mbits, db, aout, &KS[0][0]);
  else       amean_body<0>(z, qt, lt, w, l, Qfrag, Kfrag, mbits, db, aout, &KS[0][0]);
}

// ---------------- gated merge ----------------
__global__ void merge_kernel(const u16* __restrict__ o01,
                             const float* __restrict__ gate,
                             u16* __restrict__ merged) {
  int i = blockIdx.x * blockDim.x + threadIdx.x;
  float gv = gate[0];
  float g = 1.0f / (1.0f + __builtin_amdgcn_exp2f(-gv * LOG2E));
  const size_t n = (size_t)BB * SS * DIM;
  ushort4 a = ((const ushort4*)o01)[i];
  ushort4 c = ((const ushort4*)(o01 + n))[i];
  ushort4 o;
  o.x = f2b(g * b2f(a.x) + (1.f - g) * b2f(c.x));
  o.y = f2b(g * b2f(a.y) + (1.f - g) * b2f(c.y));
  o.z = f2b(g * b2f(a.z) + (1.f - g) * b2f(c.z));
  o.w = f2b(g * b2f(a.w) + (1.f - g) * b2f(c.w));
  ((ushort4*)merged)[i] = o;
}

extern "C" void kernel_launch(void* const* d_in, const int* in_sizes, int n_in,
                              void* d_out, int out_size, void* d_ws, size_t ws_size,
                              hipStream_t stream) {
  const float* query = (const float*)d_in[0];
  const float* k0f   = (const float*)d_in[1];
  const float* v0f   = (const float*)d_in[2];
  const float* k1f   = (const float*)d_in[3];
  const float* v1f   = (const float*)d_in[4];
  const int*   mask  = (const int*)d_in[5];
  const float* Wqf   = (const float*)d_in[6];
  const float* bq    = (const float*)d_in[7];
  const float* Wof   = (const float*)d_in[8];
  const float* bo    = (const float*)d_in[9];
  const float* gate  = (const float*)d_in[10];
  float* out = (float*)d_out;

  const size_t nQ = (size_t)BB * SS * DIM;
  const size_t nW = (size_t)DIM * DIM;

  char* ws = (char*)d_ws;
  size_t off = 0;
  auto alloc = [&](size_t bytes) -> char* {
    char* p = ws + off;
    off += (bytes + 255) & ~(size_t)255;
    return p;
  };
  u16*      queryb  = (u16*)alloc(nQ * 2);             // reused as mergedb later
  u16*      wqb     = (u16*)alloc(nW * 2);
  u16*      wob     = (u16*)alloc(nW * 2);
  u16*      Qfrag   = (u16*)alloc(nQ * 2);             // [b][h][qt][c][lane][8]
  u16*      Kfrag   = (u16*)alloc((size_t)2 * nQ * 2); // [z][h][lt][c][lane][8] (prescaled)
  u16*      Vfrag   = (u16*)alloc((size_t)2 * nQ * 2); // K=32-PV layout
  unsigned* mbits   = (unsigned*)alloc((size_t)SS * (LLL / 32) * 4);
  float*    db      = (float*)alloc((size_t)4 * HEADS * SS * 4);  // -log2(denom) per [z][h][q]
  u16*      out01   = (u16*)alloc((size_t)2 * nQ * 2);
  u16*      mergedb = queryb;  // queryb dead after q-proj gemm

  {
    int na4 = (int)(nQ / 4), nb4 = (int)(nW / 4);
    int tot = na4 + 2 * nb4;
    cvt3<<<dim3(tot / 256), dim3(256), 0, stream>>>(query, Wqf, Wof, queryb, wqb, wob, na4, nb4);
  }

  mask_pack<<<dim3(SS * (LLL / 32) / 256), dim3(256), 0, stream>>>(mask, mbits);
  pack_k<<<dim3(LLL / 64 / 4, HEADS, 4), dim3(256), 0, stream>>>(k0f, k1f, Kfrag);
  pack_v<<<dim3(LLL / 64, HEADS, 4), dim3(256), 0, stream>>>(v0f, v1f, Vfrag);

  // q projection straight into fragment layout (128x64 tiles, double-buffered)
  gemm_nt<2><<<dim3(DIM / 64, (BB * SS) / 128), dim3(256), 0, stream>>>(
      queryb, wqb, bq, (void*)Qfrag, BB * SS, DIM, DIM);

  // fused single-pass attention: 32 rows/wave, all-K=32 MFMA, double-buffered LDS staging
  attn_pv<<<dim3(512), dim3(512), 0, stream>>>(Qfrag, Kfrag, Vfrag, mbits, out01, db);

  // head-mean attention maps straight into d_out (LDS-staged K, 32 rows/wave)
  amean<<<dim3(2048), dim3(256), 0, stream>>>(Qfrag, Kfrag, mbits, db, out + nQ);

  merge_kernel<<<dim3((int)(nQ / 4 / 256)), dim3(256), 0, stream>>>(out01, gate, mergedb);

  gemm_nt<1><<<dim3(DIM / 64, (BB * SS) / 128), dim3(256), 0, stream>>>(
      mergedb, wob, bo, (void*)out, BB * SS, DIM, DIM);
}